// Round 1
// baseline (2391.435 us; speedup 1.0000x reference)
//
#include <hip/hip_runtime.h>
#include <hip/hip_bf16.h>
#include <math.h>

#define NNODES 30000
#define NEDGES 480000
#define RROWS  8192
#define NCOLS  128
#define NIN    128
#define EIN    64
#define NHID   256
#define EHID   128
#define NOUTD  256
#define EOUTD  64
#define NCLS   10

__device__ __forceinline__ float lrelu(float v){ return v > 0.f ? v : 0.01f * v; }
__device__ __forceinline__ float4 ld4(const float* p){ return *(const float4*)p; }

// ---------------- mask dtype detector ----------------
// mask = (randint(0,2)==1): could arrive as bool (1B), int32, or float32.
// Inspect first 256 bytes: int32 0/1 words, f32 0/0x3F800000 words, else bytes.
__global__ void k_mask_detect(const unsigned int* __restrict__ m, int* __restrict__ mode){
    if (threadIdx.x == 0 && blockIdx.x == 0){
        bool allI32 = true, allF32 = true;
        for (int i = 0; i < 64; i++){
            unsigned int v = m[i];
            if (!(v == 0u || v == 1u)) allI32 = false;
            if (!(v == 0u || v == 0x3F800000u)) allF32 = false;
        }
        *mode = allI32 ? 0 : (allF32 ? 1 : 2);
    }
}

// ---------------- degree count ----------------
__global__ void k_count(const int* __restrict__ dst, float* __restrict__ cnt){
    int i = blockIdx.x * 256 + threadIdx.x;
    if (i < NEDGES) atomicAdd(&cnt[dst[i]], 1.0f);
}

// ---------------- edge layer 1: e1 = leaky([x[src], e] @ W1e + b1e), scatter-add to h1sum ----------------
// 64 edges x 128 cols per block, K=192. A staged transposed in LDS.
__global__ __launch_bounds__(256) void k_edge1(
    const float* __restrict__ x, const float* __restrict__ e,
    const int* __restrict__ src, const int* __restrict__ dst,
    const float* __restrict__ W, const float* __restrict__ bias,
    float* __restrict__ e1, float* __restrict__ hsum)
{
    __shared__ float At[192][68];
    const int t  = threadIdx.x;
    const int e0 = blockIdx.x * 64;
    {
        const int r = t >> 2, q = t & 3;
        const int eidx = e0 + r;
        const int s = src[eidx];
        const float* xrow = x + (size_t)s * NIN;
        const float* erow = e + (size_t)eidx * EIN;
        #pragma unroll
        for (int i = 0; i < 12; i++){
            int k = (q * 12 + i) * 4;
            float4 v = (k < NIN) ? ld4(xrow + k) : ld4(erow + (k - NIN));
            At[k][r] = v.x; At[k+1][r] = v.y; At[k+2][r] = v.z; At[k+3][r] = v.w;
        }
    }
    __syncthreads();
    const int tx = t & 31, ty = t >> 5;  // col group (4 cols), row group (8 rows)
    float acc[8][4];
    #pragma unroll
    for (int j = 0; j < 8; j++){ acc[j][0]=acc[j][1]=acc[j][2]=acc[j][3]=0.f; }
    #pragma unroll 2
    for (int k = 0; k < 192; k++){
        float4 w  = ld4(W + (size_t)k * 128 + tx * 4);
        float4 p0 = ld4(&At[k][ty * 8]);
        float4 p1 = ld4(&At[k][ty * 8 + 4]);
        float a[8] = {p0.x, p0.y, p0.z, p0.w, p1.x, p1.y, p1.z, p1.w};
        #pragma unroll
        for (int j = 0; j < 8; j++){
            acc[j][0] += a[j] * w.x; acc[j][1] += a[j] * w.y;
            acc[j][2] += a[j] * w.z; acc[j][3] += a[j] * w.w;
        }
    }
    float4 b4 = ld4(bias + tx * 4);
    #pragma unroll
    for (int j = 0; j < 8; j++){
        int er = e0 + ty * 8 + j;
        float o0 = lrelu(acc[j][0] + b4.x);
        float o1 = lrelu(acc[j][1] + b4.y);
        float o2 = lrelu(acc[j][2] + b4.z);
        float o3 = lrelu(acc[j][3] + b4.w);
        *(float4*)(e1 + (size_t)er * EHID + tx * 4) = make_float4(o0, o1, o2, o3);
        int d = dst[er];
        float* hp = hsum + (size_t)d * EHID + tx * 4;
        atomicAdd(hp + 0, o0); atomicAdd(hp + 1, o1);
        atomicAdd(hp + 2, o2); atomicAdd(hp + 3, o3);
    }
}

// ---------------- edge layer 2: e2 = leaky([x1[src], e1] @ W2e + b2e), scatter only ----------------
// 64 edges x 64 cols per block, K=384 staged in two chunks of 192.
__global__ __launch_bounds__(256) void k_edge2(
    const float* __restrict__ x1, const float* __restrict__ e1,
    const int* __restrict__ src, const int* __restrict__ dst,
    const float* __restrict__ W, const float* __restrict__ bias,
    float* __restrict__ hsum)
{
    __shared__ float At[192][68];
    const int t  = threadIdx.x;
    const int e0 = blockIdx.x * 64;
    const int r = t >> 2, q = t & 3;
    const int eidx = e0 + r;
    const int s = src[eidx];
    const float* arow = x1 + (size_t)s   * NHID;   // 256
    const float* brow = e1 + (size_t)eidx * EHID;  // 128
    const int tx = t & 15, ty = t >> 4;  // col group (4 cols of 64), row group (4 rows)
    float acc[4][4];
    #pragma unroll
    for (int j = 0; j < 4; j++){ acc[j][0]=acc[j][1]=acc[j][2]=acc[j][3]=0.f; }
    #pragma unroll
    for (int chunk = 0; chunk < 2; chunk++){
        if (chunk) __syncthreads();
        #pragma unroll
        for (int i = 0; i < 12; i++){
            int kk = (q * 12 + i) * 4;          // 0..191 within chunk
            int k  = chunk * 192 + kk;          // global K index
            float4 v = (k < NHID) ? ld4(arow + k) : ld4(brow + (k - NHID));
            At[kk][r] = v.x; At[kk+1][r] = v.y; At[kk+2][r] = v.z; At[kk+3][r] = v.w;
        }
        __syncthreads();
        #pragma unroll 2
        for (int kk = 0; kk < 192; kk++){
            float4 w = ld4(W + (size_t)(chunk * 192 + kk) * 64 + tx * 4);
            float4 a = ld4(&At[kk][ty * 4]);
            float av[4] = {a.x, a.y, a.z, a.w};
            #pragma unroll
            for (int j = 0; j < 4; j++){
                acc[j][0] += av[j] * w.x; acc[j][1] += av[j] * w.y;
                acc[j][2] += av[j] * w.z; acc[j][3] += av[j] * w.w;
            }
        }
    }
    float4 b4 = ld4(bias + tx * 4);
    #pragma unroll
    for (int j = 0; j < 4; j++){
        int er = e0 + ty * 4 + j;
        float o0 = lrelu(acc[j][0] + b4.x);
        float o1 = lrelu(acc[j][1] + b4.y);
        float o2 = lrelu(acc[j][2] + b4.z);
        float o3 = lrelu(acc[j][3] + b4.w);
        int d = dst[er];
        float* hp = hsum + (size_t)d * EOUTD + tx * 4;
        atomicAdd(hp + 0, o0); atomicAdd(hp + 1, o1);
        atomicAdd(hp + 2, o2); atomicAdd(hp + 3, o3);
    }
}

// ---------------- node update: out = leaky([A1, A2sum/cnt] @ W + b), N columns = 256 ----------------
template<int K1, int K2>
__global__ __launch_bounds__(256) void k_node(
    const float* __restrict__ A1, const float* __restrict__ A2sum,
    const float* __restrict__ cnt,
    const float* __restrict__ W, const float* __restrict__ bias,
    float* __restrict__ out, int M)
{
    constexpr int K = K1 + K2;
    __shared__ float At[K][36];
    const int t  = threadIdx.x;
    const int r0 = blockIdx.x * 32;
    {
        const int r = t >> 3, q = t & 7;
        const int row = r0 + r;
        const bool valid = row < M;
        float rinv = 1.f;
        const float* a1 = A1;
        const float* a2 = A2sum;
        if (valid){
            rinv = 1.f / fmaxf(cnt[row], 1.f);
            a1 = A1    + (size_t)row * K1;
            a2 = A2sum + (size_t)row * K2;
        }
        for (int i = q; i < K / 4; i += 8){
            int k = i * 4;
            float4 v;
            if (!valid) v = make_float4(0.f, 0.f, 0.f, 0.f);
            else if (k < K1) v = ld4(a1 + k);
            else { v = ld4(a2 + (k - K1)); v.x*=rinv; v.y*=rinv; v.z*=rinv; v.w*=rinv; }
            At[k][r] = v.x; At[k+1][r] = v.y; At[k+2][r] = v.z; At[k+3][r] = v.w;
        }
    }
    __syncthreads();
    const int tx = t & 63, ty = t >> 6;  // col group (4 of 256), row group (8 rows)
    float acc[8][4];
    #pragma unroll
    for (int j = 0; j < 8; j++){ acc[j][0]=acc[j][1]=acc[j][2]=acc[j][3]=0.f; }
    #pragma unroll 2
    for (int k = 0; k < K; k++){
        float4 w  = ld4(W + (size_t)k * 256 + tx * 4);
        float4 p0 = ld4(&At[k][ty * 8]);
        float4 p1 = ld4(&At[k][ty * 8 + 4]);
        float a[8] = {p0.x, p0.y, p0.z, p0.w, p1.x, p1.y, p1.z, p1.w};
        #pragma unroll
        for (int j = 0; j < 8; j++){
            acc[j][0] += a[j] * w.x; acc[j][1] += a[j] * w.y;
            acc[j][2] += a[j] * w.z; acc[j][3] += a[j] * w.w;
        }
    }
    float4 b4 = ld4(bias + tx * 4);
    #pragma unroll
    for (int j = 0; j < 8; j++){
        int rr = r0 + ty * 8 + j;
        if (rr < M){
            float4 o;
            o.x = lrelu(acc[j][0] + b4.x); o.y = lrelu(acc[j][1] + b4.y);
            o.z = lrelu(acc[j][2] + b4.z); o.w = lrelu(acc[j][3] + b4.w);
            *(float4*)(out + (size_t)rr * 256 + tx * 4) = o;
        }
    }
}

// ---------------- attention: q,k,v ----------------
__global__ __launch_bounds__(256) void k_attn_qkv(
    const float* __restrict__ x1, const int* __restrict__ col_idx,
    const float* __restrict__ pe,
    const float* __restrict__ Wq, const float* __restrict__ Wk, const float* __restrict__ Wv,
    float* __restrict__ qo, float* __restrict__ ko, float* __restrict__ vo)
{
    __shared__ float c[256];
    const int i = blockIdx.x, t = threadIdx.x;
    const int col = col_idx[i];
    c[t] = x1[(size_t)col * 256 + t] + pe[i * 256 + t];
    __syncthreads();
    float aq = 0.f, ak = 0.f, av = 0.f;
    #pragma unroll 4
    for (int kk = 0; kk < 256; kk++){
        float cv = c[kk];
        aq += cv * Wq[kk * 256 + t];
        ak += cv * Wk[kk * 256 + t];
        av += cv * Wv[kk * 256 + t];
    }
    qo[i * 256 + t] = aq; ko[i * 256 + t] = ak; vo[i * 256 + t] = av;
}

// ---------------- attention: dist = softmax(q @ k^T / 16) ----------------
__global__ __launch_bounds__(128) void k_attn_dist(
    const float* __restrict__ q, const float* __restrict__ k, float* __restrict__ dist)
{
    __shared__ float qr[256];
    __shared__ float red[128];
    const int i = blockIdx.x, t = threadIdx.x;  // 128 threads
    qr[t] = q[i * 256 + t]; qr[t + 128] = q[i * 256 + t + 128];
    __syncthreads();
    float s = 0.f;
    #pragma unroll 4
    for (int kk = 0; kk < 256; kk++) s += qr[kk] * k[t * 256 + kk];
    s *= 0.0625f;
    red[t] = s; __syncthreads();
    for (int off = 64; off; off >>= 1){ if (t < off) red[t] = fmaxf(red[t], red[t + off]); __syncthreads(); }
    float m = red[0]; __syncthreads();
    float ex = expf(s - m);
    red[t] = ex; __syncthreads();
    for (int off = 64; off; off >>= 1){ if (t < off) red[t] += red[t + off]; __syncthreads(); }
    dist[i * 128 + t] = ex / red[0];
}

// ---------------- attention tail: c2=2*(dist@v); nc=sigmoid(c2@Wref+bref); colWc=nc@Wc+bep ----------------
__global__ __launch_bounds__(256) void k_attn_out(
    const float* __restrict__ dist, const float* __restrict__ v,
    const float* __restrict__ Wref, const float* __restrict__ bref,
    const float* __restrict__ Wc, const float* __restrict__ bep,
    float* __restrict__ colWc)
{
    __shared__ float dr[128];
    __shared__ float c2[256];
    __shared__ float nc[256];
    const int i = blockIdx.x, t = threadIdx.x;
    if (t < 128) dr[t] = dist[i * 128 + t];
    __syncthreads();
    float s = 0.f;
    #pragma unroll 4
    for (int j = 0; j < 128; j++) s += dr[j] * v[j * 256 + t];
    c2[t] = 2.f * s;
    __syncthreads();
    float a = 0.f;
    #pragma unroll 4
    for (int kk = 0; kk < 256; kk++) a += c2[kk] * Wref[kk * 256 + t];
    a += bref[t];
    nc[t] = 1.f / (1.f + expf(-a));
    __syncthreads();
    if (t < 64){
        float o = 0.f;
        #pragma unroll 4
        for (int kk = 0; kk < 256; kk++) o += nc[kk] * Wc[kk * 64 + t];
        colWc[i * 64 + t] = o + bep[t];
    }
}

// ---------------- rowWr = x2[row_idx] @ Wr ----------------
__global__ __launch_bounds__(256) void k_rowwr(
    const float* __restrict__ x2, const int* __restrict__ row_idx,
    const float* __restrict__ Wr, float* __restrict__ rw)
{
    __shared__ float A[16][260];
    const int t = threadIdx.x;
    const int r0 = blockIdx.x * 16;
    const int rl = t >> 4, cg = t & 15;
    const int ridx = row_idx[r0 + rl];
    const float* ar = x2 + (size_t)ridx * 256;
    for (int i = cg; i < 64; i += 16) *(float4*)(&A[rl][i * 4]) = ld4(ar + i * 4);
    __syncthreads();
    float acc[4] = {0.f, 0.f, 0.f, 0.f};
    #pragma unroll 4
    for (int kk = 0; kk < 256; kk++){
        float4 w = ld4(Wr + (size_t)kk * 64 + cg * 4);
        float a = A[rl][kk];
        acc[0] += a * w.x; acc[1] += a * w.y; acc[2] += a * w.z; acc[3] += a * w.w;
    }
    *(float4*)(rw + (size_t)(r0 + rl) * 64 + cg * 4) = make_float4(acc[0], acc[1], acc[2], acc[3]);
}

// ---------------- fused: pred -> d_out, imputation, classifier, log_softmax -> d_out ----------------
__global__ __launch_bounds__(256) void k_pred(
    const float* __restrict__ rowWr, const float* __restrict__ colWc,
    const void* __restrict__ maskp, const int* __restrict__ modep,
    const float* __restrict__ real, const float* __restrict__ Wcls, const float* __restrict__ bcls,
    float* __restrict__ out)
{
    const int t  = threadIdx.x;
    const int r0 = blockIdx.x * 4;
    const int mode = *modep;
    float acc[4][10];
    #pragma unroll
    for (int g = 0; g < 4; g++)
        #pragma unroll
        for (int c = 0; c < 10; c++) acc[g][c] = 0.f;
    float* pred = out + RROWS * NCLS;
    #pragma unroll 2
    for (int i = 0; i < 8; i++){
        int e4   = i * 256 + t;      // float4 index within row (0..2047)
        int base = e4 * 4;           // element index (c*64+j)
        int c = base >> 6;
        int j = base & 63;
        float4 cw = ld4(colWc + c * 64 + j);
        float w40[40];
        #pragma unroll
        for (int u = 0; u < 10; u++){
            float4 wv = ld4(Wcls + (size_t)base * 10 + u * 4);
            w40[u*4+0] = wv.x; w40[u*4+1] = wv.y; w40[u*4+2] = wv.z; w40[u*4+3] = wv.w;
        }
        #pragma unroll
        for (int g = 0; g < 4; g++){
            int rr = r0 + g;
            float4 rwv = ld4(rowWr + (size_t)rr * 64 + j);
            float4 p;
            p.x = lrelu(rwv.x + cw.x); p.y = lrelu(rwv.y + cw.y);
            p.z = lrelu(rwv.z + cw.z); p.w = lrelu(rwv.w + cw.w);
            *(float4*)(pred + (size_t)rr * 8192 + base) = p;
            bool m;
            if (mode == 2)      m = ((const unsigned char*)maskp)[rr * NCOLS + c] != 0;
            else if (mode == 0) m = ((const int*)maskp)[rr * NCOLS + c] != 0;
            else                m = ((const float*)maskp)[rr * NCOLS + c] != 0.f;
            float4 im = p;
            if (m) im = ld4(real + (size_t)rr * 8192 + base);
            #pragma unroll
            for (int cls = 0; cls < 10; cls++){
                acc[g][cls] += im.x * w40[cls]      + im.y * w40[10 + cls]
                             + im.z * w40[20 + cls] + im.w * w40[30 + cls];
            }
        }
    }
    // wave reduce (64 lanes)
    #pragma unroll
    for (int g = 0; g < 4; g++)
        #pragma unroll
        for (int cls = 0; cls < 10; cls++){
            float v = acc[g][cls];
            for (int off = 32; off; off >>= 1) v += __shfl_down(v, off, 64);
            acc[g][cls] = v;
        }
    __shared__ float part[4][40];
    const int wid = t >> 6, lane = t & 63;
    if (lane == 0){
        #pragma unroll
        for (int g = 0; g < 4; g++)
            #pragma unroll
            for (int cls = 0; cls < 10; cls++) part[wid][g * 10 + cls] = acc[g][cls];
    }
    __syncthreads();
    __shared__ float logit[40];
    if (t < 40) logit[t] = part[0][t] + part[1][t] + part[2][t] + part[3][t] + bcls[t % 10];
    __syncthreads();
    if (t < 4){
        float m = -1e30f;
        #pragma unroll
        for (int cls = 0; cls < 10; cls++) m = fmaxf(m, logit[t * 10 + cls]);
        float se = 0.f;
        #pragma unroll
        for (int cls = 0; cls < 10; cls++) se += expf(logit[t * 10 + cls] - m);
        float ls = logf(se) + m;
        #pragma unroll
        for (int cls = 0; cls < 10; cls++) out[(r0 + t) * 10 + cls] = logit[t * 10 + cls] - ls;
    }
}

extern "C" void kernel_launch(void* const* d_in, const int* in_sizes, int n_in,
                              void* d_out, int out_size, void* d_ws, size_t ws_size,
                              hipStream_t stream)
{
    const float* x      = (const float*)d_in[0];
    const float* e      = (const float*)d_in[1];
    const int*   src    = (const int*)d_in[2];
    const int*   dst    = (const int*)d_in[3];
    const int*   row_idx= (const int*)d_in[4];
    const int*   col_idx= (const int*)d_in[5];
    const float* real   = (const float*)d_in[6];
    const void*  mask   = d_in[7];
    const float* W1e    = (const float*)d_in[8];
    const float* b1e    = (const float*)d_in[9];
    const float* W1n    = (const float*)d_in[10];
    const float* b1n    = (const float*)d_in[11];
    const float* W2e    = (const float*)d_in[12];
    const float* b2e    = (const float*)d_in[13];
    const float* W2n    = (const float*)d_in[14];
    const float* b2n    = (const float*)d_in[15];
    const float* pe     = (const float*)d_in[16];
    const float* Wq     = (const float*)d_in[17];
    const float* Wk     = (const float*)d_in[18];
    const float* Wv     = (const float*)d_in[19];
    const float* Wref   = (const float*)d_in[20];
    const float* bref   = (const float*)d_in[21];
    const float* Wr     = (const float*)d_in[22];
    const float* Wc     = (const float*)d_in[23];
    const float* bep    = (const float*)d_in[24];
    const float* Wcls   = (const float*)d_in[25];
    const float* bcls   = (const float*)d_in[26];

    float* ws = (float*)d_ws;
    size_t off = 0;
    float* h1sum = ws + off; off += (size_t)NNODES * EHID;   // 3.84M
    float* h2sum = ws + off; off += (size_t)NNODES * EOUTD;  // 1.92M
    float* cnt   = ws + off; off += NNODES;
    const size_t zero_floats = off;                           // zeroed each call
    float* x1    = ws + off; off += (size_t)NNODES * NHID;   // 7.68M
    float* x2    = ws + off; off += (size_t)NNODES * NOUTD;  // 7.68M
    float* qb    = ws + off; off += 128 * 256;
    float* kb    = ws + off; off += 128 * 256;
    float* vb    = ws + off; off += 128 * 256;
    float* distb = ws + off; off += 128 * 128;
    float* colWc = ws + off; off += 128 * 64;
    float* rowWrb= ws + off; off += (size_t)RROWS * EOUTD;   // 0.52M
    int*   modep = (int*)(ws + off); off += 1;
    // e1 is the big one (61.44M floats = 246MB). Use ws if it fits, else borrow
    // the pred region of d_out (written only after e1 is consumed by k_edge2).
    float* e1;
    size_t need = (off + (size_t)NEDGES * EHID) * sizeof(float);
    if (ws_size >= need) e1 = ws + off;
    else                 e1 = (float*)d_out + (size_t)RROWS * NCLS;

    hipMemsetAsync(d_ws, 0, zero_floats * sizeof(float), stream);
    k_mask_detect<<<1, 64, 0, stream>>>((const unsigned int*)mask, modep);
    k_count<<<(NEDGES + 255) / 256, 256, 0, stream>>>(dst, cnt);
    k_edge1<<<NEDGES / 64, 256, 0, stream>>>(x, e, src, dst, W1e, b1e, e1, h1sum);
    k_node<NIN, EHID><<<(NNODES + 31) / 32, 256, 0, stream>>>(x, h1sum, cnt, W1n, b1n, x1, NNODES);
    k_edge2<<<NEDGES / 64, 256, 0, stream>>>(x1, e1, src, dst, W2e, b2e, h2sum);
    k_node<NHID, EOUTD><<<(NNODES + 31) / 32, 256, 0, stream>>>(x1, h2sum, cnt, W2n, b2n, x2, NNODES);
    k_attn_qkv<<<128, 256, 0, stream>>>(x1, col_idx, pe, Wq, Wk, Wv, qb, kb, vb);
    k_attn_dist<<<128, 128, 0, stream>>>(qb, kb, distb);
    k_attn_out<<<128, 256, 0, stream>>>(distb, vb, Wref, bref, Wc, bep, colWc);
    k_rowwr<<<RROWS / 16, 256, 0, stream>>>(x2, row_idx, Wr, rowWrb);
    k_pred<<<RROWS / 4, 256, 0, stream>>>(rowWrb, colWc, mask, modep, real, Wcls, bcls, (float*)d_out);
}

// Round 2
// 1042.433 us; speedup vs baseline: 2.2941x; 2.2941x over previous
//
#include <hip/hip_runtime.h>
#include <hip/hip_bf16.h>
#include <math.h>

#define NNODES 30000
#define NEDGES 480000
#define RROWS  8192
#define NCOLS  128
#define NIN    128
#define EIN    64
#define NHID   256
#define EHID   128
#define NOUTD  256
#define EOUTD  64
#define NCLS   10

typedef __attribute__((ext_vector_type(8))) unsigned short ushort8;
typedef __attribute__((ext_vector_type(4))) unsigned short ushort4v;
typedef __attribute__((ext_vector_type(8))) short bhalf8;
typedef __attribute__((ext_vector_type(4))) float floatx4;

__device__ __forceinline__ float lrelu(float v){ return v > 0.f ? v : 0.01f * v; }
__device__ __forceinline__ float4 ld4(const float* p){ return *(const float4*)p; }
__device__ __forceinline__ unsigned short f2b(float f){
    unsigned int u = __builtin_bit_cast(unsigned int, f);
    u += 0x7fffu + ((u >> 16) & 1u);
    return (unsigned short)(u >> 16);
}

// ---------------- mask dtype detector ----------------
__global__ void k_mask_detect(const unsigned int* __restrict__ m, int* __restrict__ mode){
    if (threadIdx.x == 0 && blockIdx.x == 0){
        bool allI32 = true, allF32 = true;
        for (int i = 0; i < 64; i++){
            unsigned int v = m[i];
            if (!(v == 0u || v == 1u)) allI32 = false;
            if (!(v == 0u || v == 0x3F800000u)) allF32 = false;
        }
        *mode = allI32 ? 0 : (allF32 ? 1 : 2);
    }
}

// ---------------- degree count ----------------
__global__ void k_count(const int* __restrict__ dst, float* __restrict__ cnt){
    int i = blockIdx.x * 256 + threadIdx.x;
    if (i < NEDGES) atomicAdd(&cnt[dst[i]], 1.0f);
}

// ---------------- f32 -> bf16 bulk convert (n multiple of 8) ----------------
__global__ void k_cvt_bf16(const float* __restrict__ in, unsigned short* __restrict__ out, int n8){
    int i = blockIdx.x * 256 + threadIdx.x;
    if (i >= n8) return;
    float4 a = ld4(in + (size_t)i * 8), b = ld4(in + (size_t)i * 8 + 4);
    ushort8 o = {f2b(a.x), f2b(a.y), f2b(a.z), f2b(a.w), f2b(b.x), f2b(b.y), f2b(b.z), f2b(b.w)};
    *(ushort8*)(out + (size_t)i * 8) = o;
}

// ---------------- W[K][N] -> Wt[N][K] bf16 ----------------
template<int K, int N>
__global__ void k_wT(const float* __restrict__ W, unsigned short* __restrict__ Wt){
    int idx = blockIdx.x * 256 + threadIdx.x;
    if (idx >= K * N) return;
    int c = idx / K, k = idx % K;
    Wt[idx] = f2b(W[(size_t)k * N + c]);
}

// ---------------- edge layer 1 (MFMA): e1 = leaky([x[src],e]@W1e+b), scatter-add ----------------
// 64 edges x 128 cols, K=192. A tile bf16 in LDS [64][200]; B frags from W1eT (L2).
__global__ __launch_bounds__(256) void k_edge1_mfma(
    const unsigned short* __restrict__ xb, const float* __restrict__ e,
    const int* __restrict__ src, const int* __restrict__ dst,
    const unsigned short* __restrict__ Wt, const float* __restrict__ bias,
    unsigned short* __restrict__ e1b, float* __restrict__ hsum)
{
    __shared__ unsigned short At[64][200];
    __shared__ int dstS[64];
    const int t = threadIdx.x;
    const int e0 = blockIdx.x * 64;
    {
        const int r = t >> 2, q = t & 3;
        const int eidx = e0 + r;
        if (q == 0) dstS[r] = dst[eidx];
        const int srow = src[eidx];
        #pragma unroll
        for (int gi = 0; gi < 3; gi++){
            const int k = q * 48 + gi * 16;
            if (k < 128){
                const unsigned short* xp = xb + (size_t)srow * 128 + k;
                *(ushort8*)&At[r][k]     = *(const ushort8*)xp;
                *(ushort8*)&At[r][k + 8] = *(const ushort8*)(xp + 8);
            } else {
                const float* ep = e + (size_t)eidx * 64 + (k - 128);
                float4 f0 = ld4(ep), f1 = ld4(ep + 4), f2 = ld4(ep + 8), f3 = ld4(ep + 12);
                ushort8 u0 = {f2b(f0.x), f2b(f0.y), f2b(f0.z), f2b(f0.w), f2b(f1.x), f2b(f1.y), f2b(f1.z), f2b(f1.w)};
                ushort8 u1 = {f2b(f2.x), f2b(f2.y), f2b(f2.z), f2b(f2.w), f2b(f3.x), f2b(f3.y), f2b(f3.z), f2b(f3.w)};
                *(ushort8*)&At[r][k]     = u0;
                *(ushort8*)&At[r][k + 8] = u1;
            }
        }
    }
    __syncthreads();
    const int lane = t & 63, w = t >> 6;
    const int wm = w >> 1, wn = w & 1;
    const int fr = lane & 15, fq = lane >> 4;
    floatx4 acc[2][4] = {};
    #pragma unroll
    for (int ks = 0; ks < 6; ks++){
        const int k = ks * 32 + fq * 8;
        bhalf8 a0 = *(bhalf8*)&At[wm * 32 + fr][k];
        bhalf8 a1 = *(bhalf8*)&At[wm * 32 + 16 + fr][k];
        #pragma unroll
        for (int n = 0; n < 4; n++){
            const int col = wn * 64 + n * 16 + fr;
            bhalf8 b = *(const bhalf8*)(Wt + (size_t)col * 192 + k);
            acc[0][n] = __builtin_amdgcn_mfma_f32_16x16x32_bf16(a0, b, acc[0][n], 0, 0, 0);
            acc[1][n] = __builtin_amdgcn_mfma_f32_16x16x32_bf16(a1, b, acc[1][n], 0, 0, 0);
        }
    }
    __syncthreads();   // all frag reads done; reuse At as C staging
    unsigned short (*Ct)[136] = (unsigned short(*)[136])&At[0][0];
    #pragma unroll
    for (int m = 0; m < 2; m++){
        #pragma unroll
        for (int n = 0; n < 4; n++){
            const int col = wn * 64 + n * 16 + fr;
            const float bv = bias[col];
            #pragma unroll
            for (int r = 0; r < 4; r++){
                const int row = wm * 32 + m * 16 + fq * 4 + r;
                float o = lrelu(acc[m][n][r] + bv);
                Ct[row][col] = f2b(o);
                atomicAdd(&hsum[(size_t)dstS[row] * EHID + col], o);
            }
        }
    }
    __syncthreads();
    {
        const int r = t >> 2, q = t & 3;
        unsigned short* op = e1b + (size_t)(e0 + r) * EHID + q * 32;
        #pragma unroll
        for (int i = 0; i < 4; i++)
            *(ushort8*)(op + i * 8) = *(ushort8*)&Ct[r][q * 32 + i * 8];
    }
}

// ---------------- edge layer 2 (MFMA): scatter-add only. K=384 in two 192-chunks ----------------
__global__ __launch_bounds__(256) void k_edge2_mfma(
    const unsigned short* __restrict__ x1b, const unsigned short* __restrict__ e1b,
    const int* __restrict__ src, const int* __restrict__ dst,
    const unsigned short* __restrict__ Wt, const float* __restrict__ bias,
    float* __restrict__ hsum)
{
    __shared__ unsigned short At[64][200];
    __shared__ int dstS[64];
    const int t = threadIdx.x;
    const int e0 = blockIdx.x * 64;
    const int lane = t & 63, w = t >> 6;
    const int fr = lane & 15, fq = lane >> 4;
    const int r = t >> 2, q = t & 3;
    const int eidx = e0 + r;
    const int srow = src[eidx];
    if (q == 0) dstS[r] = dst[eidx];
    floatx4 acc[4] = {};
    #pragma unroll
    for (int chunk = 0; chunk < 2; chunk++){
        if (chunk) __syncthreads();
        #pragma unroll
        for (int gi = 0; gi < 3; gi++){
            const int kl = q * 48 + gi * 16;
            const int kg = chunk * 192 + kl;
            const unsigned short* sp = (kg < 256)
                ? (x1b + (size_t)srow * 256 + kg)
                : (e1b + (size_t)eidx * 128 + (kg - 256));
            *(ushort8*)&At[r][kl]     = *(const ushort8*)sp;
            *(ushort8*)&At[r][kl + 8] = *(const ushort8*)(sp + 8);
        }
        __syncthreads();
        #pragma unroll
        for (int ks = 0; ks < 6; ks++){
            const int kl = ks * 32 + fq * 8;
            bhalf8 a = *(bhalf8*)&At[w * 16 + fr][kl];
            #pragma unroll
            for (int n = 0; n < 4; n++){
                const int col = n * 16 + fr;
                bhalf8 b = *(const bhalf8*)(Wt + (size_t)col * 384 + chunk * 192 + kl);
                acc[n] = __builtin_amdgcn_mfma_f32_16x16x32_bf16(a, b, acc[n], 0, 0, 0);
            }
        }
    }
    #pragma unroll
    for (int n = 0; n < 4; n++){
        const int col = n * 16 + fr;
        const float bv = bias[col];
        #pragma unroll
        for (int rr = 0; rr < 4; rr++){
            const int row = w * 16 + fq * 4 + rr;
            float o = lrelu(acc[n][rr] + bv);
            atomicAdd(&hsum[(size_t)dstS[row] * EOUTD + col], o);
        }
    }
}

// ---------------- node update: out = leaky([A1, A2sum/cnt] @ W + b) ----------------
template<int K1, int K2>
__global__ __launch_bounds__(256) void k_node(
    const float* __restrict__ A1, const float* __restrict__ A2sum,
    const float* __restrict__ cnt,
    const float* __restrict__ W, const float* __restrict__ bias,
    float* __restrict__ out, unsigned short* __restrict__ out_b, int M)
{
    constexpr int K = K1 + K2;
    __shared__ float At[K][36];
    const int t  = threadIdx.x;
    const int r0 = blockIdx.x * 32;
    {
        const int r = t >> 3, q = t & 7;
        const int row = r0 + r;
        const bool valid = row < M;
        float rinv = 1.f;
        const float* a1 = A1;
        const float* a2 = A2sum;
        if (valid){
            rinv = 1.f / fmaxf(cnt[row], 1.f);
            a1 = A1    + (size_t)row * K1;
            a2 = A2sum + (size_t)row * K2;
        }
        for (int i = q; i < K / 4; i += 8){
            int k = i * 4;
            float4 v;
            if (!valid) v = make_float4(0.f, 0.f, 0.f, 0.f);
            else if (k < K1) v = ld4(a1 + k);
            else { v = ld4(a2 + (k - K1)); v.x*=rinv; v.y*=rinv; v.z*=rinv; v.w*=rinv; }
            At[k][r] = v.x; At[k+1][r] = v.y; At[k+2][r] = v.z; At[k+3][r] = v.w;
        }
    }
    __syncthreads();
    const int tx = t & 63, ty = t >> 6;
    float acc[8][4];
    #pragma unroll
    for (int j = 0; j < 8; j++){ acc[j][0]=acc[j][1]=acc[j][2]=acc[j][3]=0.f; }
    #pragma unroll 2
    for (int k = 0; k < K; k++){
        float4 w  = ld4(W + (size_t)k * 256 + tx * 4);
        float4 p0 = ld4(&At[k][ty * 8]);
        float4 p1 = ld4(&At[k][ty * 8 + 4]);
        float a[8] = {p0.x, p0.y, p0.z, p0.w, p1.x, p1.y, p1.z, p1.w};
        #pragma unroll
        for (int j = 0; j < 8; j++){
            acc[j][0] += a[j] * w.x; acc[j][1] += a[j] * w.y;
            acc[j][2] += a[j] * w.z; acc[j][3] += a[j] * w.w;
        }
    }
    float4 b4 = ld4(bias + tx * 4);
    #pragma unroll
    for (int j = 0; j < 8; j++){
        int rr = r0 + ty * 8 + j;
        if (rr < M){
            float4 o;
            o.x = lrelu(acc[j][0] + b4.x); o.y = lrelu(acc[j][1] + b4.y);
            o.z = lrelu(acc[j][2] + b4.z); o.w = lrelu(acc[j][3] + b4.w);
            *(float4*)(out + (size_t)rr * 256 + tx * 4) = o;
            if (out_b){
                ushort4v u = {f2b(o.x), f2b(o.y), f2b(o.z), f2b(o.w)};
                *(ushort4v*)(out_b + (size_t)rr * 256 + tx * 4) = u;
            }
        }
    }
}

// ---------------- attention: q,k,v ----------------
__global__ __launch_bounds__(256) void k_attn_qkv(
    const float* __restrict__ x1, const int* __restrict__ col_idx,
    const float* __restrict__ pe,
    const float* __restrict__ Wq, const float* __restrict__ Wk, const float* __restrict__ Wv,
    float* __restrict__ qo, float* __restrict__ ko, float* __restrict__ vo)
{
    __shared__ float c[256];
    const int i = blockIdx.x, t = threadIdx.x;
    const int col = col_idx[i];
    c[t] = x1[(size_t)col * 256 + t] + pe[i * 256 + t];
    __syncthreads();
    float aq = 0.f, ak = 0.f, av = 0.f;
    #pragma unroll 4
    for (int kk = 0; kk < 256; kk++){
        float cv = c[kk];
        aq += cv * Wq[kk * 256 + t];
        ak += cv * Wk[kk * 256 + t];
        av += cv * Wv[kk * 256 + t];
    }
    qo[i * 256 + t] = aq; ko[i * 256 + t] = ak; vo[i * 256 + t] = av;
}

// ---------------- attention: dist = softmax(q @ k^T / 16) ----------------
__global__ __launch_bounds__(128) void k_attn_dist(
    const float* __restrict__ q, const float* __restrict__ k, float* __restrict__ dist)
{
    __shared__ float qr[256];
    __shared__ float red[128];
    const int i = blockIdx.x, t = threadIdx.x;
    qr[t] = q[i * 256 + t]; qr[t + 128] = q[i * 256 + t + 128];
    __syncthreads();
    float s = 0.f;
    #pragma unroll 4
    for (int kk = 0; kk < 256; kk++) s += qr[kk] * k[t * 256 + kk];
    s *= 0.0625f;
    red[t] = s; __syncthreads();
    for (int off = 64; off; off >>= 1){ if (t < off) red[t] = fmaxf(red[t], red[t + off]); __syncthreads(); }
    float m = red[0]; __syncthreads();
    float ex = expf(s - m);
    red[t] = ex; __syncthreads();
    for (int off = 64; off; off >>= 1){ if (t < off) red[t] += red[t + off]; __syncthreads(); }
    dist[i * 128 + t] = ex / red[0];
}

// ---------------- attention tail ----------------
__global__ __launch_bounds__(256) void k_attn_out(
    const float* __restrict__ dist, const float* __restrict__ v,
    const float* __restrict__ Wref, const float* __restrict__ bref,
    const float* __restrict__ Wc, const float* __restrict__ bep,
    float* __restrict__ colWc)
{
    __shared__ float dr[128];
    __shared__ float c2[256];
    __shared__ float nc[256];
    const int i = blockIdx.x, t = threadIdx.x;
    if (t < 128) dr[t] = dist[i * 128 + t];
    __syncthreads();
    float s = 0.f;
    #pragma unroll 4
    for (int j = 0; j < 128; j++) s += dr[j] * v[j * 256 + t];
    c2[t] = 2.f * s;
    __syncthreads();
    float a = 0.f;
    #pragma unroll 4
    for (int kk = 0; kk < 256; kk++) a += c2[kk] * Wref[kk * 256 + t];
    a += bref[t];
    nc[t] = 1.f / (1.f + expf(-a));
    __syncthreads();
    if (t < 64){
        float o = 0.f;
        #pragma unroll 4
        for (int kk = 0; kk < 256; kk++) o += nc[kk] * Wc[kk * 64 + t];
        colWc[i * 64 + t] = o + bep[t];
    }
}

// ---------------- rowWr = x2[row_idx] @ Wr ----------------
__global__ __launch_bounds__(256) void k_rowwr(
    const float* __restrict__ x2, const int* __restrict__ row_idx,
    const float* __restrict__ Wr, float* __restrict__ rw)
{
    __shared__ float A[16][260];
    const int t = threadIdx.x;
    const int r0 = blockIdx.x * 16;
    const int rl = t >> 4, cg = t & 15;
    const int ridx = row_idx[r0 + rl];
    const float* ar = x2 + (size_t)ridx * 256;
    for (int i = cg; i < 64; i += 16) *(float4*)(&A[rl][i * 4]) = ld4(ar + i * 4);
    __syncthreads();
    float acc[4] = {0.f, 0.f, 0.f, 0.f};
    #pragma unroll 4
    for (int kk = 0; kk < 256; kk++){
        float4 w = ld4(Wr + (size_t)kk * 64 + cg * 4);
        float a = A[rl][kk];
        acc[0] += a * w.x; acc[1] += a * w.y; acc[2] += a * w.z; acc[3] += a * w.w;
    }
    *(float4*)(rw + (size_t)(r0 + rl) * 64 + cg * 4) = make_float4(acc[0], acc[1], acc[2], acc[3]);
}

// ---------------- fused: pred -> d_out, imputation, classifier, log_softmax ----------------
__global__ __launch_bounds__(256) void k_pred(
    const float* __restrict__ rowWr, const float* __restrict__ colWc,
    const void* __restrict__ maskp, const int* __restrict__ modep,
    const float* __restrict__ real, const float* __restrict__ Wcls, const float* __restrict__ bcls,
    float* __restrict__ out)
{
    const int t  = threadIdx.x;
    const int r0 = blockIdx.x * 4;
    const int mode = *modep;
    float acc[4][10];
    #pragma unroll
    for (int g = 0; g < 4; g++)
        #pragma unroll
        for (int c = 0; c < 10; c++) acc[g][c] = 0.f;
    float* pred = out + RROWS * NCLS;
    #pragma unroll 2
    for (int i = 0; i < 8; i++){
        int e4   = i * 256 + t;
        int base = e4 * 4;
        int c = base >> 6;
        int j = base & 63;
        float4 cw = ld4(colWc + c * 64 + j);
        float w40[40];
        #pragma unroll
        for (int u = 0; u < 10; u++){
            float4 wv = ld4(Wcls + (size_t)base * 10 + u * 4);
            w40[u*4+0] = wv.x; w40[u*4+1] = wv.y; w40[u*4+2] = wv.z; w40[u*4+3] = wv.w;
        }
        #pragma unroll
        for (int g = 0; g < 4; g++){
            int rr = r0 + g;
            float4 rwv = ld4(rowWr + (size_t)rr * 64 + j);
            float4 p;
            p.x = lrelu(rwv.x + cw.x); p.y = lrelu(rwv.y + cw.y);
            p.z = lrelu(rwv.z + cw.z); p.w = lrelu(rwv.w + cw.w);
            *(float4*)(pred + (size_t)rr * 8192 + base) = p;
            bool m;
            if (mode == 2)      m = ((const unsigned char*)maskp)[rr * NCOLS + c] != 0;
            else if (mode == 0) m = ((const int*)maskp)[rr * NCOLS + c] != 0;
            else                m = ((const float*)maskp)[rr * NCOLS + c] != 0.f;
            float4 im = p;
            if (m) im = ld4(real + (size_t)rr * 8192 + base);
            #pragma unroll
            for (int cls = 0; cls < 10; cls++){
                acc[g][cls] += im.x * w40[cls]      + im.y * w40[10 + cls]
                             + im.z * w40[20 + cls] + im.w * w40[30 + cls];
            }
        }
    }
    #pragma unroll
    for (int g = 0; g < 4; g++)
        #pragma unroll
        for (int cls = 0; cls < 10; cls++){
            float v = acc[g][cls];
            for (int off = 32; off; off >>= 1) v += __shfl_down(v, off, 64);
            acc[g][cls] = v;
        }
    __shared__ float part[4][40];
    const int wid = t >> 6, lane = t & 63;
    if (lane == 0){
        #pragma unroll
        for (int g = 0; g < 4; g++)
            #pragma unroll
            for (int cls = 0; cls < 10; cls++) part[wid][g * 10 + cls] = acc[g][cls];
    }
    __syncthreads();
    __shared__ float logit[40];
    if (t < 40) logit[t] = part[0][t] + part[1][t] + part[2][t] + part[3][t] + bcls[t % 10];
    __syncthreads();
    if (t < 4){
        float m = -1e30f;
        #pragma unroll
        for (int cls = 0; cls < 10; cls++) m = fmaxf(m, logit[t * 10 + cls]);
        float se = 0.f;
        #pragma unroll
        for (int cls = 0; cls < 10; cls++) se += expf(logit[t * 10 + cls] - m);
        float ls = logf(se) + m;
        #pragma unroll
        for (int cls = 0; cls < 10; cls++) out[(r0 + t) * 10 + cls] = logit[t * 10 + cls] - ls;
    }
}

extern "C" void kernel_launch(void* const* d_in, const int* in_sizes, int n_in,
                              void* d_out, int out_size, void* d_ws, size_t ws_size,
                              hipStream_t stream)
{
    const float* x      = (const float*)d_in[0];
    const float* e      = (const float*)d_in[1];
    const int*   src    = (const int*)d_in[2];
    const int*   dst    = (const int*)d_in[3];
    const int*   row_idx= (const int*)d_in[4];
    const int*   col_idx= (const int*)d_in[5];
    const float* real   = (const float*)d_in[6];
    const void*  mask   = d_in[7];
    const float* W1e    = (const float*)d_in[8];
    const float* b1e    = (const float*)d_in[9];
    const float* W1n    = (const float*)d_in[10];
    const float* b1n    = (const float*)d_in[11];
    const float* W2e    = (const float*)d_in[12];
    const float* b2e    = (const float*)d_in[13];
    const float* W2n    = (const float*)d_in[14];
    const float* b2n    = (const float*)d_in[15];
    const float* pe     = (const float*)d_in[16];
    const float* Wq     = (const float*)d_in[17];
    const float* Wk     = (const float*)d_in[18];
    const float* Wv     = (const float*)d_in[19];
    const float* Wref   = (const float*)d_in[20];
    const float* bref   = (const float*)d_in[21];
    const float* Wr     = (const float*)d_in[22];
    const float* Wc     = (const float*)d_in[23];
    const float* bep    = (const float*)d_in[24];
    const float* Wcls   = (const float*)d_in[25];
    const float* bcls   = (const float*)d_in[26];

    float* ws = (float*)d_ws;
    size_t off = 0;
    float* h1sum = ws + off; off += (size_t)NNODES * EHID;
    float* h2sum = ws + off; off += (size_t)NNODES * EOUTD;
    float* cnt   = ws + off; off += NNODES;
    const size_t zero_floats = off;
    float* x1    = ws + off; off += (size_t)NNODES * NHID;
    float* x2    = ws + off; off += (size_t)NNODES * NOUTD;
    unsigned short* xb    = (unsigned short*)(ws + off); off += (size_t)NNODES * NIN  / 2;
    unsigned short* x1b   = (unsigned short*)(ws + off); off += (size_t)NNODES * NHID / 2;
    unsigned short* W1eTb = (unsigned short*)(ws + off); off += 192 * 128 / 2;
    unsigned short* W2eTb = (unsigned short*)(ws + off); off += 384 * 64 / 2;
    float* qb    = ws + off; off += 128 * 256;
    float* kb    = ws + off; off += 128 * 256;
    float* vb    = ws + off; off += 128 * 256;
    float* distb = ws + off; off += 128 * 128;
    float* colWc = ws + off; off += 128 * 64;
    float* rowWrb= ws + off; off += (size_t)RROWS * EOUTD;
    int*   modep = (int*)(ws + off); off += 4;
    // e1 bf16 (480000x128 = 123MB). Use ws if it fits, else borrow pred region
    // of d_out (written only after e1b is consumed by k_edge2).
    unsigned short* e1b;
    size_t need = (off + (size_t)NEDGES * EHID / 2) * sizeof(float);
    if (ws_size >= need) e1b = (unsigned short*)(ws + off);
    else                 e1b = (unsigned short*)((float*)d_out + (size_t)RROWS * NCLS);

    hipMemsetAsync(d_ws, 0, zero_floats * sizeof(float), stream);
    k_mask_detect<<<1, 64, 0, stream>>>((const unsigned int*)mask, modep);
    k_count<<<(NEDGES + 255) / 256, 256, 0, stream>>>(dst, cnt);
    k_cvt_bf16<<<(NNODES * NIN / 8 + 255) / 256, 256, 0, stream>>>(x, xb, NNODES * NIN / 8);
    k_wT<192, 128><<<(192 * 128 + 255) / 256, 256, 0, stream>>>(W1e, W1eTb);
    k_wT<384, 64><<<(384 * 64 + 255) / 256, 256, 0, stream>>>(W2e, W2eTb);
    k_edge1_mfma<<<NEDGES / 64, 256, 0, stream>>>(xb, e, src, dst, W1eTb, b1e, e1b, h1sum);
    k_node<NIN, EHID><<<(NNODES + 31) / 32, 256, 0, stream>>>(x, h1sum, cnt, W1n, b1n, x1, x1b, NNODES);
    k_edge2_mfma<<<NEDGES / 64, 256, 0, stream>>>(x1b, e1b, src, dst, W2eTb, b2e, h2sum);
    k_node<NHID, EOUTD><<<(NNODES + 31) / 32, 256, 0, stream>>>(x1, h2sum, cnt, W2n, b2n, x2, (unsigned short*)nullptr, NNODES);
    k_attn_qkv<<<128, 256, 0, stream>>>(x1, col_idx, pe, Wq, Wk, Wv, qb, kb, vb);
    k_attn_dist<<<128, 128, 0, stream>>>(qb, kb, distb);
    k_attn_out<<<128, 256, 0, stream>>>(distb, vb, Wref, bref, Wc, bep, colWc);
    k_rowwr<<<RROWS / 16, 256, 0, stream>>>(x2, row_idx, Wr, rowWrb);
    k_pred<<<RROWS / 4, 256, 0, stream>>>(rowWrb, colWc, mask, modep, real, Wcls, bcls, (float*)d_out);
}

// Round 3
// 971.027 us; speedup vs baseline: 2.4628x; 1.0735x over previous
//
#include <hip/hip_runtime.h>
#include <hip/hip_bf16.h>
#include <math.h>

#define NNODES 30000
#define NEDGES 480000
#define RROWS  8192
#define NCOLS  128
#define NIN    128
#define EIN    64
#define NHID   256
#define EHID   128
#define NOUTD  256
#define EOUTD  64
#define NCLS   10

typedef __attribute__((ext_vector_type(8))) unsigned short ushort8;
typedef __attribute__((ext_vector_type(4))) unsigned short ushort4v;
typedef __attribute__((ext_vector_type(8))) short bhalf8;
typedef __attribute__((ext_vector_type(4))) float floatx4;

__device__ __forceinline__ float lrelu(float v){ return v > 0.f ? v : 0.01f * v; }
__device__ __forceinline__ float4 ld4(const float* p){ return *(const float4*)p; }
__device__ __forceinline__ unsigned short f2b(float f){
    unsigned int u = __builtin_bit_cast(unsigned int, f);
    u += 0x7fffu + ((u >> 16) & 1u);
    return (unsigned short)(u >> 16);
}

// ---------------- mask dtype detector ----------------
__global__ void k_mask_detect(const unsigned int* __restrict__ m, int* __restrict__ mode){
    if (threadIdx.x == 0 && blockIdx.x == 0){
        bool allI32 = true, allF32 = true;
        for (int i = 0; i < 64; i++){
            unsigned int v = m[i];
            if (!(v == 0u || v == 1u)) allI32 = false;
            if (!(v == 0u || v == 0x3F800000u)) allF32 = false;
        }
        *mode = allI32 ? 0 : (allF32 ? 1 : 2);
    }
}

// ---------------- histogram of dst ----------------
__global__ void k_hist(const int* __restrict__ dst, int* __restrict__ cnt_i){
    int i = blockIdx.x * 256 + threadIdx.x;
    if (i < NEDGES) atomicAdd(&cnt_i[dst[i]], 1);
}

// ---------------- exclusive prefix over 30000 bins; emit cursor + float counts ----------------
__global__ __launch_bounds__(256) void k_prefix(const int* __restrict__ cnt_i,
                                                int* __restrict__ cursor, float* __restrict__ cntf){
    __shared__ int part[256];
    const int t = threadIdx.x;
    const int CH = (NNODES + 255) / 256;
    const int lo = t * CH, hi = min(lo + CH, NNODES);
    int s = 0;
    for (int i = lo; i < hi; i++) s += cnt_i[i];
    part[t] = s;
    __syncthreads();
    if (t == 0){
        int acc = 0;
        for (int i = 0; i < 256; i++){ int v = part[i]; part[i] = acc; acc += v; }
    }
    __syncthreads();
    int run = part[t];
    for (int i = lo; i < hi; i++){
        cursor[i] = run;
        run += cnt_i[i];
        cntf[i] = (float)cnt_i[i];
    }
}

// ---------------- scatter: sorted-by-dst edge arrays ----------------
__global__ void k_scatter(const int* __restrict__ src, const int* __restrict__ dst,
                          int* __restrict__ cursor,
                          int* __restrict__ srcs, int* __restrict__ dsts, int* __restrict__ eidx){
    int i = blockIdx.x * 256 + threadIdx.x;
    if (i >= NEDGES) return;
    int d = dst[i];
    int pos = atomicAdd(&cursor[d], 1);
    srcs[pos] = src[i];
    dsts[pos] = d;
    eidx[pos] = i;
}

// ---------------- f32 -> bf16 bulk convert ----------------
__global__ void k_cvt_bf16(const float* __restrict__ in, unsigned short* __restrict__ out, int n8){
    int i = blockIdx.x * 256 + threadIdx.x;
    if (i >= n8) return;
    float4 a = ld4(in + (size_t)i * 8), b = ld4(in + (size_t)i * 8 + 4);
    ushort8 o = {f2b(a.x), f2b(a.y), f2b(a.z), f2b(a.w), f2b(b.x), f2b(b.y), f2b(b.z), f2b(b.w)};
    *(ushort8*)(out + (size_t)i * 8) = o;
}

// ---------------- W[K][N] -> Wt[N][K] bf16 ----------------
template<int K, int N>
__global__ void k_wT(const float* __restrict__ W, unsigned short* __restrict__ Wt){
    int idx = blockIdx.x * 256 + threadIdx.x;
    if (idx >= K * N) return;
    int c = idx / K, k = idx % K;
    Wt[idx] = f2b(W[(size_t)k * N + c]);
}

// ---------------- edge layer 1 (MFMA, dst-sorted): e1s + run-reduced scatter-add ----------------
__global__ __launch_bounds__(256) void k_edge1_mfma(
    const unsigned short* __restrict__ xb, const float* __restrict__ e,
    const int* __restrict__ srcs, const int* __restrict__ dsts, const int* __restrict__ eidx,
    const unsigned short* __restrict__ Wt, const float* __restrict__ bias,
    unsigned short* __restrict__ e1s, float* __restrict__ hsum)
{
    __shared__ __align__(16) char smem[64 * 132 * 4];   // union: At ushort[64][200] | Cf float[64][132]
    unsigned short (*At)[200] = (unsigned short(*)[200])smem;
    float (*Cf)[132] = (float(*)[132])smem;
    __shared__ int dstS[64];
    const int t = threadIdx.x;
    const int p0 = blockIdx.x * 64;
    {
        const int r = t >> 2, q = t & 3;
        const int p = p0 + r;
        if (q == 0) dstS[r] = dsts[p];
        const int srow = srcs[p];
        const int ei   = eidx[p];
        #pragma unroll
        for (int gi = 0; gi < 3; gi++){
            const int k = q * 48 + gi * 16;
            if (k < 128){
                const unsigned short* xp = xb + (size_t)srow * 128 + k;
                *(ushort8*)&At[r][k]     = *(const ushort8*)xp;
                *(ushort8*)&At[r][k + 8] = *(const ushort8*)(xp + 8);
            } else {
                const float* ep = e + (size_t)ei * 64 + (k - 128);
                float4 f0 = ld4(ep), f1 = ld4(ep + 4), f2 = ld4(ep + 8), f3 = ld4(ep + 12);
                ushort8 u0 = {f2b(f0.x), f2b(f0.y), f2b(f0.z), f2b(f0.w), f2b(f1.x), f2b(f1.y), f2b(f1.z), f2b(f1.w)};
                ushort8 u1 = {f2b(f2.x), f2b(f2.y), f2b(f2.z), f2b(f2.w), f2b(f3.x), f2b(f3.y), f2b(f3.z), f2b(f3.w)};
                *(ushort8*)&At[r][k]     = u0;
                *(ushort8*)&At[r][k + 8] = u1;
            }
        }
    }
    __syncthreads();
    const int lane = t & 63, w = t >> 6;
    const int wm = w >> 1, wn = w & 1;
    const int fr = lane & 15, fq = lane >> 4;
    floatx4 acc[2][4] = {};
    #pragma unroll
    for (int ks = 0; ks < 6; ks++){
        const int k = ks * 32 + fq * 8;
        bhalf8 a0 = *(bhalf8*)&At[wm * 32 + fr][k];
        bhalf8 a1 = *(bhalf8*)&At[wm * 32 + 16 + fr][k];
        #pragma unroll
        for (int n = 0; n < 4; n++){
            const int col = wn * 64 + n * 16 + fr;
            bhalf8 b = *(const bhalf8*)(Wt + (size_t)col * 192 + k);
            acc[0][n] = __builtin_amdgcn_mfma_f32_16x16x32_bf16(a0, b, acc[0][n], 0, 0, 0);
            acc[1][n] = __builtin_amdgcn_mfma_f32_16x16x32_bf16(a1, b, acc[1][n], 0, 0, 0);
        }
    }
    __syncthreads();   // At reads done; reuse as Cf
    #pragma unroll
    for (int m = 0; m < 2; m++){
        #pragma unroll
        for (int n = 0; n < 4; n++){
            const int col = wn * 64 + n * 16 + fr;
            const float bv = bias[col];
            #pragma unroll
            for (int r = 0; r < 4; r++){
                const int row = wm * 32 + m * 16 + fq * 4 + r;
                Cf[row][col] = lrelu(acc[m][n][r] + bv);
            }
        }
    }
    __syncthreads();
    // e1s store (sorted layout, bf16, coalesced)
    {
        const int r = t >> 2, q = t & 3;
        unsigned short* op = e1s + (size_t)(p0 + r) * EHID + q * 32;
        #pragma unroll
        for (int i = 0; i < 4; i++){
            float4 f0 = ld4(&Cf[r][q * 32 + i * 8]);
            float4 f1 = ld4(&Cf[r][q * 32 + i * 8 + 4]);
            ushort8 u = {f2b(f0.x), f2b(f0.y), f2b(f0.z), f2b(f0.w), f2b(f1.x), f2b(f1.y), f2b(f1.z), f2b(f1.w)};
            *(ushort8*)(op + i * 8) = u;
        }
    }
    // run-length reduced scatter-add: 128 col-threads x 2 row-halves
    {
        const int col = t & 127, half = t >> 7;
        const int rbase = half * 32;
        float s = 0.f;
        int prev = dstS[rbase];
        #pragma unroll 4
        for (int rr = 0; rr < 32; rr++){
            const int r = rbase + rr;
            const int d = dstS[r];
            if (d != prev){
                atomicAdd(&hsum[(size_t)prev * EHID + col], s);
                s = 0.f; prev = d;
            }
            s += Cf[r][col];
        }
        atomicAdd(&hsum[(size_t)prev * EHID + col], s);
    }
}

// ---------------- edge layer 2 (MFMA, dst-sorted): run-reduced scatter-add only ----------------
__global__ __launch_bounds__(256) void k_edge2_mfma(
    const unsigned short* __restrict__ x1b, const unsigned short* __restrict__ e1s,
    const int* __restrict__ srcs, const int* __restrict__ dsts,
    const unsigned short* __restrict__ Wt, const float* __restrict__ bias,
    float* __restrict__ hsum)
{
    __shared__ __align__(16) char smem[64 * 200 * 2];   // union: At ushort[64][200] | Cf float[64][68]
    unsigned short (*At)[200] = (unsigned short(*)[200])smem;
    float (*Cf)[68] = (float(*)[68])smem;
    __shared__ int dstS[64];
    const int t = threadIdx.x;
    const int p0 = blockIdx.x * 64;
    const int lane = t & 63, w = t >> 6;
    const int fr = lane & 15, fq = lane >> 4;
    const int r = t >> 2, q = t & 3;
    const int p = p0 + r;
    const int srow = srcs[p];
    if (q == 0) dstS[r] = dsts[p];
    floatx4 acc[4] = {};
    #pragma unroll
    for (int chunk = 0; chunk < 2; chunk++){
        if (chunk) __syncthreads();
        #pragma unroll
        for (int gi = 0; gi < 3; gi++){
            const int kl = q * 48 + gi * 16;
            const int kg = chunk * 192 + kl;
            const unsigned short* sp = (kg < 256)
                ? (x1b + (size_t)srow * 256 + kg)
                : (e1s + (size_t)p * 128 + (kg - 256));
            *(ushort8*)&At[r][kl]     = *(const ushort8*)sp;
            *(ushort8*)&At[r][kl + 8] = *(const ushort8*)(sp + 8);
        }
        __syncthreads();
        #pragma unroll
        for (int ks = 0; ks < 6; ks++){
            const int kl = ks * 32 + fq * 8;
            bhalf8 a = *(bhalf8*)&At[w * 16 + fr][kl];
            #pragma unroll
            for (int n = 0; n < 4; n++){
                const int col = n * 16 + fr;
                bhalf8 b = *(const bhalf8*)(Wt + (size_t)col * 384 + chunk * 192 + kl);
                acc[n] = __builtin_amdgcn_mfma_f32_16x16x32_bf16(a, b, acc[n], 0, 0, 0);
            }
        }
    }
    __syncthreads();   // At reads done; reuse as Cf
    #pragma unroll
    for (int n = 0; n < 4; n++){
        const int col = n * 16 + fr;
        const float bv = bias[col];
        #pragma unroll
        for (int rr = 0; rr < 4; rr++){
            const int row = w * 16 + fq * 4 + rr;
            Cf[row][col] = lrelu(acc[n][rr] + bv);
        }
    }
    __syncthreads();
    {
        const int col = t & 63, quarter = t >> 6;
        const int rbase = quarter * 16;
        float s = 0.f;
        int prev = dstS[rbase];
        #pragma unroll 4
        for (int rr = 0; rr < 16; rr++){
            const int rw = rbase + rr;
            const int d = dstS[rw];
            if (d != prev){
                atomicAdd(&hsum[(size_t)prev * EOUTD + col], s);
                s = 0.f; prev = d;
            }
            s += Cf[rw][col];
        }
        atomicAdd(&hsum[(size_t)prev * EOUTD + col], s);
    }
}

// ---------------- node update (MFMA): out = leaky([A1, hsum/cnt] @ W + b) ----------------
template<int K1, int K2, bool WRITE_BF16>
__global__ __launch_bounds__(256) void k_node_mfma(
    const unsigned short* __restrict__ A1b, const float* __restrict__ hsum,
    const float* __restrict__ cntf,
    const unsigned short* __restrict__ Wt, const float* __restrict__ bias,
    float* __restrict__ outf, unsigned short* __restrict__ outb, int M)
{
    constexpr int K = K1 + K2;
    __shared__ unsigned short At[64][K + 8];
    const int t = threadIdx.x;
    const int r0 = blockIdx.x * 64;
    {
        const int r = t >> 2, q = t & 3;
        const int row = r0 + r;
        const bool valid = row < M;
        float rinv = 0.f;
        const unsigned short* a1 = A1b;
        const float* a2 = hsum;
        if (valid){
            rinv = 1.f / fmaxf(cntf[row], 1.f);
            a1 = A1b  + (size_t)row * K1;
            a2 = hsum + (size_t)row * K2;
        }
        for (int kk = q * (K / 4); kk < (q + 1) * (K / 4); kk += 8){
            ushort8 u;
            if (!valid){
                u = (ushort8){0,0,0,0,0,0,0,0};
            } else if (kk < K1){
                u = *(const ushort8*)(a1 + kk);
            } else {
                float4 f0 = ld4(a2 + (kk - K1)), f1 = ld4(a2 + (kk - K1) + 4);
                u = (ushort8){f2b(f0.x*rinv), f2b(f0.y*rinv), f2b(f0.z*rinv), f2b(f0.w*rinv),
                              f2b(f1.x*rinv), f2b(f1.y*rinv), f2b(f1.z*rinv), f2b(f1.w*rinv)};
            }
            *(ushort8*)&At[r][kk] = u;
        }
    }
    __syncthreads();
    const int lane = t & 63, w = t >> 6;
    const int fr = lane & 15, fq = lane >> 4;
    floatx4 acc[16] = {};
    #pragma unroll
    for (int ks = 0; ks < K / 32; ks++){
        const int k = ks * 32 + fq * 8;
        bhalf8 a = *(bhalf8*)&At[w * 16 + fr][k];
        #pragma unroll
        for (int n = 0; n < 16; n++){
            bhalf8 b = *(const bhalf8*)(Wt + (size_t)(n * 16 + fr) * K + k);
            acc[n] = __builtin_amdgcn_mfma_f32_16x16x32_bf16(a, b, acc[n], 0, 0, 0);
        }
    }
    #pragma unroll
    for (int n = 0; n < 16; n++){
        const int col = n * 16 + fr;
        const float bv = bias[col];
        #pragma unroll
        for (int rr = 0; rr < 4; rr++){
            const int row = r0 + w * 16 + fq * 4 + rr;
            if (row < M){
                float o = lrelu(acc[n][rr] + bv);
                outf[(size_t)row * 256 + col] = o;
                if (WRITE_BF16) outb[(size_t)row * 256 + col] = f2b(o);
            }
        }
    }
}

// ---------------- attention: q,k,v ----------------
__global__ __launch_bounds__(256) void k_attn_qkv(
    const float* __restrict__ x1, const int* __restrict__ col_idx,
    const float* __restrict__ pe,
    const float* __restrict__ Wq, const float* __restrict__ Wk, const float* __restrict__ Wv,
    float* __restrict__ qo, float* __restrict__ ko, float* __restrict__ vo)
{
    __shared__ float c[256];
    const int i = blockIdx.x, t = threadIdx.x;
    const int col = col_idx[i];
    c[t] = x1[(size_t)col * 256 + t] + pe[i * 256 + t];
    __syncthreads();
    float aq = 0.f, ak = 0.f, av = 0.f;
    #pragma unroll 4
    for (int kk = 0; kk < 256; kk++){
        float cv = c[kk];
        aq += cv * Wq[kk * 256 + t];
        ak += cv * Wk[kk * 256 + t];
        av += cv * Wv[kk * 256 + t];
    }
    qo[i * 256 + t] = aq; ko[i * 256 + t] = ak; vo[i * 256 + t] = av;
}

// ---------------- attention: dist = softmax(q @ k^T / 16) ----------------
__global__ __launch_bounds__(128) void k_attn_dist(
    const float* __restrict__ q, const float* __restrict__ k, float* __restrict__ dist)
{
    __shared__ float qr[256];
    __shared__ float red[128];
    const int i = blockIdx.x, t = threadIdx.x;
    qr[t] = q[i * 256 + t]; qr[t + 128] = q[i * 256 + t + 128];
    __syncthreads();
    float s = 0.f;
    #pragma unroll 4
    for (int kk = 0; kk < 256; kk++) s += qr[kk] * k[t * 256 + kk];
    s *= 0.0625f;
    red[t] = s; __syncthreads();
    for (int off = 64; off; off >>= 1){ if (t < off) red[t] = fmaxf(red[t], red[t + off]); __syncthreads(); }
    float m = red[0]; __syncthreads();
    float ex = expf(s - m);
    red[t] = ex; __syncthreads();
    for (int off = 64; off; off >>= 1){ if (t < off) red[t] += red[t + off]; __syncthreads(); }
    dist[i * 128 + t] = ex / red[0];
}

// ---------------- attention tail ----------------
__global__ __launch_bounds__(256) void k_attn_out(
    const float* __restrict__ dist, const float* __restrict__ v,
    const float* __restrict__ Wref, const float* __restrict__ bref,
    const float* __restrict__ Wc, const float* __restrict__ bep,
    float* __restrict__ colWc)
{
    __shared__ float dr[128];
    __shared__ float c2[256];
    __shared__ float nc[256];
    const int i = blockIdx.x, t = threadIdx.x;
    if (t < 128) dr[t] = dist[i * 128 + t];
    __syncthreads();
    float s = 0.f;
    #pragma unroll 4
    for (int j = 0; j < 128; j++) s += dr[j] * v[j * 256 + t];
    c2[t] = 2.f * s;
    __syncthreads();
    float a = 0.f;
    #pragma unroll 4
    for (int kk = 0; kk < 256; kk++) a += c2[kk] * Wref[kk * 256 + t];
    a += bref[t];
    nc[t] = 1.f / (1.f + expf(-a));
    __syncthreads();
    if (t < 64){
        float o = 0.f;
        #pragma unroll 4
        for (int kk = 0; kk < 256; kk++) o += nc[kk] * Wc[kk * 64 + t];
        colWc[i * 64 + t] = o + bep[t];
    }
}

// ---------------- rowWr = x2[row_idx] @ Wr ----------------
__global__ __launch_bounds__(256) void k_rowwr(
    const float* __restrict__ x2, const int* __restrict__ row_idx,
    const float* __restrict__ Wr, float* __restrict__ rw)
{
    __shared__ float A[16][260];
    const int t = threadIdx.x;
    const int r0 = blockIdx.x * 16;
    const int rl = t >> 4, cg = t & 15;
    const int ridx = row_idx[r0 + rl];
    const float* ar = x2 + (size_t)ridx * 256;
    for (int i = cg; i < 64; i += 16) *(float4*)(&A[rl][i * 4]) = ld4(ar + i * 4);
    __syncthreads();
    float acc[4] = {0.f, 0.f, 0.f, 0.f};
    #pragma unroll 4
    for (int kk = 0; kk < 256; kk++){
        float4 w = ld4(Wr + (size_t)kk * 64 + cg * 4);
        float a = A[rl][kk];
        acc[0] += a * w.x; acc[1] += a * w.y; acc[2] += a * w.z; acc[3] += a * w.w;
    }
    *(float4*)(rw + (size_t)(r0 + rl) * 64 + cg * 4) = make_float4(acc[0], acc[1], acc[2], acc[3]);
}

// ---------------- fused: pred -> d_out, imputation, classifier, log_softmax ----------------
__global__ __launch_bounds__(256) void k_pred(
    const float* __restrict__ rowWr, const float* __restrict__ colWc,
    const void* __restrict__ maskp, const int* __restrict__ modep,
    const float* __restrict__ real, const float* __restrict__ Wcls, const float* __restrict__ bcls,
    float* __restrict__ out)
{
    const int t  = threadIdx.x;
    const int r0 = blockIdx.x * 4;
    const int mode = *modep;
    float acc[4][10];
    #pragma unroll
    for (int g = 0; g < 4; g++)
        #pragma unroll
        for (int c = 0; c < 10; c++) acc[g][c] = 0.f;
    float* pred = out + RROWS * NCLS;
    #pragma unroll 2
    for (int i = 0; i < 8; i++){
        int e4   = i * 256 + t;
        int base = e4 * 4;
        int c = base >> 6;
        int j = base & 63;
        float4 cw = ld4(colWc + c * 64 + j);
        float w40[40];
        #pragma unroll
        for (int u = 0; u < 10; u++){
            float4 wv = ld4(Wcls + (size_t)base * 10 + u * 4);
            w40[u*4+0] = wv.x; w40[u*4+1] = wv.y; w40[u*4+2] = wv.z; w40[u*4+3] = wv.w;
        }
        #pragma unroll
        for (int g = 0; g < 4; g++){
            int rr = r0 + g;
            float4 rwv = ld4(rowWr + (size_t)rr * 64 + j);
            float4 p;
            p.x = lrelu(rwv.x + cw.x); p.y = lrelu(rwv.y + cw.y);
            p.z = lrelu(rwv.z + cw.z); p.w = lrelu(rwv.w + cw.w);
            *(float4*)(pred + (size_t)rr * 8192 + base) = p;
            bool m;
            if (mode == 2)      m = ((const unsigned char*)maskp)[rr * NCOLS + c] != 0;
            else if (mode == 0) m = ((const int*)maskp)[rr * NCOLS + c] != 0;
            else                m = ((const float*)maskp)[rr * NCOLS + c] != 0.f;
            float4 im = p;
            if (m) im = ld4(real + (size_t)rr * 8192 + base);
            #pragma unroll
            for (int cls = 0; cls < 10; cls++){
                acc[g][cls] += im.x * w40[cls]      + im.y * w40[10 + cls]
                             + im.z * w40[20 + cls] + im.w * w40[30 + cls];
            }
        }
    }
    #pragma unroll
    for (int g = 0; g < 4; g++)
        #pragma unroll
        for (int cls = 0; cls < 10; cls++){
            float v = acc[g][cls];
            for (int off = 32; off; off >>= 1) v += __shfl_down(v, off, 64);
            acc[g][cls] = v;
        }
    __shared__ float part[4][40];
    const int wid = t >> 6, lane = t & 63;
    if (lane == 0){
        #pragma unroll
        for (int g = 0; g < 4; g++)
            #pragma unroll
            for (int cls = 0; cls < 10; cls++) part[wid][g * 10 + cls] = acc[g][cls];
    }
    __syncthreads();
    __shared__ float logit[40];
    if (t < 40) logit[t] = part[0][t] + part[1][t] + part[2][t] + part[3][t] + bcls[t % 10];
    __syncthreads();
    if (t < 4){
        float m = -1e30f;
        #pragma unroll
        for (int cls = 0; cls < 10; cls++) m = fmaxf(m, logit[t * 10 + cls]);
        float se = 0.f;
        #pragma unroll
        for (int cls = 0; cls < 10; cls++) se += expf(logit[t * 10 + cls] - m);
        float ls = logf(se) + m;
        #pragma unroll
        for (int cls = 0; cls < 10; cls++) out[(r0 + t) * 10 + cls] = logit[t * 10 + cls] - ls;
    }
}

extern "C" void kernel_launch(void* const* d_in, const int* in_sizes, int n_in,
                              void* d_out, int out_size, void* d_ws, size_t ws_size,
                              hipStream_t stream)
{
    const float* x      = (const float*)d_in[0];
    const float* e      = (const float*)d_in[1];
    const int*   src    = (const int*)d_in[2];
    const int*   dst    = (const int*)d_in[3];
    const int*   row_idx= (const int*)d_in[4];
    const int*   col_idx= (const int*)d_in[5];
    const float* real   = (const float*)d_in[6];
    const void*  mask   = d_in[7];
    const float* W1e    = (const float*)d_in[8];
    const float* b1e    = (const float*)d_in[9];
    const float* W1n    = (const float*)d_in[10];
    const float* b1n    = (const float*)d_in[11];
    const float* W2e    = (const float*)d_in[12];
    const float* b2e    = (const float*)d_in[13];
    const float* W2n    = (const float*)d_in[14];
    const float* b2n    = (const float*)d_in[15];
    const float* pe     = (const float*)d_in[16];
    const float* Wq     = (const float*)d_in[17];
    const float* Wk     = (const float*)d_in[18];
    const float* Wv     = (const float*)d_in[19];
    const float* Wref   = (const float*)d_in[20];
    const float* bref   = (const float*)d_in[21];
    const float* Wr     = (const float*)d_in[22];
    const float* Wc     = (const float*)d_in[23];
    const float* bep    = (const float*)d_in[24];
    const float* Wcls   = (const float*)d_in[25];
    const float* bcls   = (const float*)d_in[26];

    float* ws = (float*)d_ws;
    size_t off = 0;
    float* h1sum = ws + off; off += (size_t)NNODES * EHID;   // 3.84M
    float* h2sum = ws + off; off += (size_t)NNODES * EOUTD;  // 1.92M
    int*   cnt_i = (int*)(ws + off); off += NNODES;
    const size_t zero_floats = off;                           // zeroed each call
    float* cntf  = ws + off; off += NNODES;
    int*   cursor= (int*)(ws + off); off += NNODES;
    int*   srcs  = (int*)(ws + off); off += NEDGES;
    int*   dsts  = (int*)(ws + off); off += NEDGES;
    int*   eidx  = (int*)(ws + off); off += NEDGES;
    float* x1    = ws + off; off += (size_t)NNODES * NHID;   // 7.68M
    float* x2    = ws + off; off += (size_t)NNODES * NOUTD;  // 7.68M
    unsigned short* xb    = (unsigned short*)(ws + off); off += (size_t)NNODES * NIN  / 2;
    unsigned short* x1b   = (unsigned short*)(ws + off); off += (size_t)NNODES * NHID / 2;
    unsigned short* W1eTb = (unsigned short*)(ws + off); off += 192 * 128 / 2;
    unsigned short* W2eTb = (unsigned short*)(ws + off); off += 384 * 64 / 2;
    unsigned short* W1nTb = (unsigned short*)(ws + off); off += 256 * 256 / 2;
    unsigned short* W2nTb = (unsigned short*)(ws + off); off += 320 * 256 / 2;
    float* qb    = ws + off; off += 128 * 256;
    float* kb    = ws + off; off += 128 * 256;
    float* vb    = ws + off; off += 128 * 256;
    float* distb = ws + off; off += 128 * 128;
    float* colWc = ws + off; off += 128 * 64;
    float* rowWrb= ws + off; off += (size_t)RROWS * EOUTD;
    int*   modep = (int*)(ws + off); off += 4;
    // e1s bf16 (sorted layout, 480000x128 = 123MB). ws if it fits, else borrow
    // pred region of d_out (written only after e1s is consumed by k_edge2).
    unsigned short* e1s;
    size_t need = (off + (size_t)NEDGES * EHID / 2) * sizeof(float);
    if (ws_size >= need) e1s = (unsigned short*)(ws + off);
    else                 e1s = (unsigned short*)((float*)d_out + (size_t)RROWS * NCLS);

    hipMemsetAsync(d_ws, 0, zero_floats * sizeof(float), stream);
    k_mask_detect<<<1, 64, 0, stream>>>((const unsigned int*)mask, modep);
    k_hist<<<(NEDGES + 255) / 256, 256, 0, stream>>>(dst, cnt_i);
    k_prefix<<<1, 256, 0, stream>>>(cnt_i, cursor, cntf);
    k_scatter<<<(NEDGES + 255) / 256, 256, 0, stream>>>(src, dst, cursor, srcs, dsts, eidx);
    k_cvt_bf16<<<(NNODES * NIN / 8 + 255) / 256, 256, 0, stream>>>(x, xb, NNODES * NIN / 8);
    k_wT<192, 128><<<(192 * 128 + 255) / 256, 256, 0, stream>>>(W1e, W1eTb);
    k_wT<384, 64><<<(384 * 64 + 255) / 256, 256, 0, stream>>>(W2e, W2eTb);
    k_wT<256, 256><<<(256 * 256 + 255) / 256, 256, 0, stream>>>(W1n, W1nTb);
    k_wT<320, 256><<<(320 * 256 + 255) / 256, 256, 0, stream>>>(W2n, W2nTb);
    k_edge1_mfma<<<NEDGES / 64, 256, 0, stream>>>(xb, e, srcs, dsts, eidx, W1eTb, b1e, e1s, h1sum);
    k_node_mfma<NIN, EHID, true><<<(NNODES + 63) / 64, 256, 0, stream>>>(xb, h1sum, cntf, W1nTb, b1n, x1, x1b, NNODES);
    k_edge2_mfma<<<NEDGES / 64, 256, 0, stream>>>(x1b, e1s, srcs, dsts, W2eTb, b2e, h2sum);
    k_node_mfma<NHID, EOUTD, false><<<(NNODES + 63) / 64, 256, 0, stream>>>(x1b, h2sum, cntf, W2nTb, b2n, x2, (unsigned short*)nullptr, NNODES);
    k_attn_qkv<<<128, 256, 0, stream>>>(x1, col_idx, pe, Wq, Wk, Wv, qb, kb, vb);
    k_attn_dist<<<128, 128, 0, stream>>>(qb, kb, distb);
    k_attn_out<<<128, 256, 0, stream>>>(distb, vb, Wref, bref, Wc, bep, colWc);
    k_rowwr<<<RROWS / 16, 256, 0, stream>>>(x2, row_idx, Wr, rowWrb);
    k_pred<<<RROWS / 4, 256, 0, stream>>>(rowWrb, colWc, mask, modep, real, Wcls, bcls, (float*)d_out);
}

// Round 4
// 846.165 us; speedup vs baseline: 2.8262x; 1.1476x over previous
//
#include <hip/hip_runtime.h>
#include <hip/hip_bf16.h>
#include <math.h>

#define NNODES 30000
#define NEDGES 480000
#define RROWS  8192
#define NCOLS  128
#define NIN    128
#define EIN    64
#define NHID   256
#define EHID   128
#define NOUTD  256
#define EOUTD  64
#define NCLS   10

typedef __attribute__((ext_vector_type(8))) unsigned short ushort8;
typedef __attribute__((ext_vector_type(4))) unsigned short ushort4v;
typedef __attribute__((ext_vector_type(8))) short bhalf8;
typedef __attribute__((ext_vector_type(4))) float floatx4;

__device__ __forceinline__ float lrelu(float v){ return v > 0.f ? v : 0.01f * v; }
__device__ __forceinline__ float4 ld4(const float* p){ return *(const float4*)p; }
__device__ __forceinline__ unsigned short f2b(float f){
    unsigned int u = __builtin_bit_cast(unsigned int, f);
    u += 0x7fffu + ((u >> 16) & 1u);
    return (unsigned short)(u >> 16);
}
__device__ __forceinline__ float b2f(unsigned short b){
    unsigned int u = ((unsigned int)b) << 16;
    return __builtin_bit_cast(float, u);
}

// ---------------- mask dtype detector ----------------
__global__ void k_mask_detect(const unsigned int* __restrict__ m, int* __restrict__ mode){
    if (threadIdx.x == 0 && blockIdx.x == 0){
        bool allI32 = true, allF32 = true;
        for (int i = 0; i < 64; i++){
            unsigned int v = m[i];
            if (!(v == 0u || v == 1u)) allI32 = false;
            if (!(v == 0u || v == 0x3F800000u)) allF32 = false;
        }
        *mode = allI32 ? 0 : (allF32 ? 1 : 2);
    }
}

// ---------------- histogram of dst ----------------
__global__ void k_hist(const int* __restrict__ dst, int* __restrict__ cnt_i){
    int i = blockIdx.x * 256 + threadIdx.x;
    if (i < NEDGES) atomicAdd(&cnt_i[dst[i]], 1);
}

// ---------------- exclusive prefix over 30000 bins ----------------
__global__ __launch_bounds__(256) void k_prefix(const int* __restrict__ cnt_i,
                                                int* __restrict__ cursor, float* __restrict__ cntf){
    __shared__ int part[256];
    const int t = threadIdx.x;
    const int CH = (NNODES + 255) / 256;
    const int lo = t * CH, hi = min(lo + CH, NNODES);
    int s = 0;
    for (int i = lo; i < hi; i++) s += cnt_i[i];
    part[t] = s;
    __syncthreads();
    if (t == 0){
        int acc = 0;
        for (int i = 0; i < 256; i++){ int v = part[i]; part[i] = acc; acc += v; }
    }
    __syncthreads();
    int run = part[t];
    for (int i = lo; i < hi; i++){
        cursor[i] = run;
        run += cnt_i[i];
        cntf[i] = (float)cnt_i[i];
    }
}

// ---------------- scatter: sorted-by-dst edge arrays ----------------
__global__ void k_scatter(const int* __restrict__ src, const int* __restrict__ dst,
                          int* __restrict__ cursor,
                          int* __restrict__ srcs, int* __restrict__ dsts, int* __restrict__ eidx){
    int i = blockIdx.x * 256 + threadIdx.x;
    if (i >= NEDGES) return;
    int d = dst[i];
    int pos = atomicAdd(&cursor[d], 1);
    srcs[pos] = src[i];
    dsts[pos] = d;
    eidx[pos] = i;
}

// ---------------- f32 -> bf16 bulk convert ----------------
__global__ void k_cvt_bf16(const float* __restrict__ in, unsigned short* __restrict__ out, int n8){
    int i = blockIdx.x * 256 + threadIdx.x;
    if (i >= n8) return;
    float4 a = ld4(in + (size_t)i * 8), b = ld4(in + (size_t)i * 8 + 4);
    ushort8 o = {f2b(a.x), f2b(a.y), f2b(a.z), f2b(a.w), f2b(b.x), f2b(b.y), f2b(b.z), f2b(b.w)};
    *(ushort8*)(out + (size_t)i * 8) = o;
}

// ---------------- W[KTOT][N] rows [KOFF, KOFF+KSUB) -> Wt[N][KSUB] bf16 ----------------
template<int KOFF, int KSUB, int N>
__global__ void k_wT_part(const float* __restrict__ W, unsigned short* __restrict__ Wt){
    int idx = blockIdx.x * 256 + threadIdx.x;
    if (idx >= N * KSUB) return;
    int n = idx / KSUB, k = idx % KSUB;
    Wt[idx] = f2b(W[(size_t)(KOFF + k) * N + n]);
}

// ---------------- small GEMM: out_f32[M,N] = Ab[M,K] @ Wt[N,K] ----------------
template<int K, int N>
__global__ __launch_bounds__(256) void k_gemm_f32(
    const unsigned short* __restrict__ Ab, const unsigned short* __restrict__ Wt,
    float* __restrict__ outf, int M)
{
    __shared__ unsigned short At[64][K + 8];
    const int t = threadIdx.x;
    const int r0 = blockIdx.x * 64;
    {
        const int r = t >> 2, q = t & 3;
        const int row = r0 + r;
        const bool valid = row < M;
        const unsigned short* a = Ab + (size_t)(valid ? row : 0) * K;
        for (int kk = q * (K / 4); kk < (q + 1) * (K / 4); kk += 8){
            ushort8 u;
            if (valid) u = *(const ushort8*)(a + kk);
            else       u = (ushort8){0,0,0,0,0,0,0,0};
            *(ushort8*)&At[r][kk] = u;
        }
    }
    __syncthreads();
    const int lane = t & 63, w = t >> 6;
    const int fr = lane & 15, fq = lane >> 4;
    constexpr int NF = N / 16;
    floatx4 acc[NF] = {};
    #pragma unroll
    for (int ks = 0; ks < K / 32; ks++){
        const int k = ks * 32 + fq * 8;
        bhalf8 a = *(bhalf8*)&At[w * 16 + fr][k];
        #pragma unroll
        for (int n = 0; n < NF; n++){
            bhalf8 b = *(const bhalf8*)(Wt + (size_t)(n * 16 + fr) * K + k);
            acc[n] = __builtin_amdgcn_mfma_f32_16x16x32_bf16(a, b, acc[n], 0, 0, 0);
        }
    }
    #pragma unroll
    for (int n = 0; n < NF; n++){
        const int col = n * 16 + fr;
        #pragma unroll
        for (int rr = 0; rr < 4; rr++){
            const int row = r0 + w * 16 + fq * 4 + rr;
            if (row < M) outf[(size_t)row * N + col] = acc[n][rr];
        }
    }
}

// ---------------- fused edge layer 1 ----------------
// per 64-edge tile (dst-sorted):
//   e1 = leaky(P1[src] + e@W1bT + b1e)   (kept in LDS, f32)
//   Q  = e1 @ W2bT                        (written f32, sorted/coalesced)
//   h1sum += run-reduced column sums of e1
__global__ __launch_bounds__(256) void k_edge1_fused(
    const float* __restrict__ e,
    const int* __restrict__ srcs, const int* __restrict__ dsts, const int* __restrict__ eidx,
    const unsigned short* __restrict__ W1bT, const float* __restrict__ b1e,
    const float* __restrict__ P1f, const unsigned short* __restrict__ W2bT,
    float* __restrict__ Qf, float* __restrict__ hsum)
{
    __shared__ __align__(16) char smem[64 * 132 * 4];   // Cf f32[64][132]; Et ushort[64][72] overlays
    unsigned short (*Et)[72] = (unsigned short(*)[72])smem;
    float (*Cf)[132] = (float(*)[132])smem;
    __shared__ int dstS[64];
    __shared__ int srcS[64];
    const int t = threadIdx.x;
    const int p0 = blockIdx.x * 64;
    // phase A: stage e rows (f32 -> bf16), load src/dst
    {
        const int r = t >> 2, q = t & 3;
        const int p = p0 + r;
        if (q == 0){ dstS[r] = dsts[p]; srcS[r] = srcs[p]; }
        const int ei = eidx[p];
        const float* ep = e + (size_t)ei * 64 + q * 16;
        float4 f0 = ld4(ep), f1 = ld4(ep + 4), f2 = ld4(ep + 8), f3 = ld4(ep + 12);
        ushort8 u0 = {f2b(f0.x), f2b(f0.y), f2b(f0.z), f2b(f0.w), f2b(f1.x), f2b(f1.y), f2b(f1.z), f2b(f1.w)};
        ushort8 u1 = {f2b(f2.x), f2b(f2.y), f2b(f2.z), f2b(f2.w), f2b(f3.x), f2b(f3.y), f2b(f3.z), f2b(f3.w)};
        *(ushort8*)&Et[r][q * 16]     = u0;
        *(ushort8*)&Et[r][q * 16 + 8] = u1;
    }
    __syncthreads();
    const int lane = t & 63, w = t >> 6;
    const int wm = w >> 1, wn = w & 1;
    const int fr = lane & 15, fq = lane >> 4;
    // phase B: MFMA1  (64x128) = e_tile(64xK64) @ W1bT
    floatx4 acc1[2][4] = {};
    #pragma unroll
    for (int ks = 0; ks < 2; ks++){
        const int k = ks * 32 + fq * 8;
        bhalf8 a0 = *(bhalf8*)&Et[wm * 32 + fr][k];
        bhalf8 a1 = *(bhalf8*)&Et[wm * 32 + 16 + fr][k];
        #pragma unroll
        for (int n = 0; n < 4; n++){
            const int col = wn * 64 + n * 16 + fr;
            bhalf8 b = *(const bhalf8*)(W1bT + (size_t)col * 64 + k);
            acc1[0][n] = __builtin_amdgcn_mfma_f32_16x16x32_bf16(a0, b, acc1[0][n], 0, 0, 0);
            acc1[1][n] = __builtin_amdgcn_mfma_f32_16x16x32_bf16(a1, b, acc1[1][n], 0, 0, 0);
        }
    }
    __syncthreads();   // Et reads done; Cf may overlay
    // phase C: e1 = leaky(acc + P1[src] + b1e) -> Cf
    #pragma unroll
    for (int m = 0; m < 2; m++){
        #pragma unroll
        for (int n = 0; n < 4; n++){
            const int col = wn * 64 + n * 16 + fr;
            const float bv = b1e[col];
            #pragma unroll
            for (int r = 0; r < 4; r++){
                const int row = wm * 32 + m * 16 + fq * 4 + r;
                const float pv = P1f[(size_t)srcS[row] * 128 + col];
                Cf[row][col] = lrelu(acc1[m][n][r] + pv + bv);
            }
        }
    }
    __syncthreads();
    // phase D: Q = e1 @ W2bT  (64x64, K=128), direct store f32
    {
        floatx4 acc2[4] = {};
        #pragma unroll
        for (int ks = 0; ks < 4; ks++){
            const int k = ks * 32 + fq * 8;
            float4 f0 = ld4(&Cf[w * 16 + fr][k]);
            float4 f1 = ld4(&Cf[w * 16 + fr][k + 4]);
            ushort8 u = {f2b(f0.x), f2b(f0.y), f2b(f0.z), f2b(f0.w), f2b(f1.x), f2b(f1.y), f2b(f1.z), f2b(f1.w)};
            bhalf8 a = *(bhalf8*)&u;
            #pragma unroll
            for (int n = 0; n < 4; n++){
                bhalf8 b = *(const bhalf8*)(W2bT + (size_t)(n * 16 + fr) * 128 + k);
                acc2[n] = __builtin_amdgcn_mfma_f32_16x16x32_bf16(a, b, acc2[n], 0, 0, 0);
            }
        }
        #pragma unroll
        for (int n = 0; n < 4; n++){
            const int col = n * 16 + fr;
            #pragma unroll
            for (int r = 0; r < 4; r++){
                const int row = w * 16 + fq * 4 + r;
                Qf[(size_t)(p0 + row) * 64 + col] = acc2[n][r];
            }
        }
    }
    // phase F: run-reduced scatter-add of e1 (Cf) to h1sum
    {
        const int col = t & 127, half = t >> 7;
        const int rbase = half * 32;
        float s = 0.f;
        int prev = dstS[rbase];
        #pragma unroll 4
        for (int rr = 0; rr < 32; rr++){
            const int r = rbase + rr;
            const int d = dstS[r];
            if (d != prev){
                atomicAdd(&hsum[(size_t)prev * EHID + col], s);
                s = 0.f; prev = d;
            }
            s += Cf[r][col];
        }
        atomicAdd(&hsum[(size_t)prev * EHID + col], s);
    }
}

// ---------------- edge layer 2 (lite): e2 = leaky(P2[src] + Q + b2e), scatter ----------------
// one wave = 64 sorted edges x 64 cols; dst/src loads are wave-uniform.
__global__ __launch_bounds__(256) void k_edge2_lite(
    const float* __restrict__ P2f, const float* __restrict__ Qf,
    const int* __restrict__ srcs, const int* __restrict__ dsts,
    const float* __restrict__ b2e, float* __restrict__ hsum)
{
    const int t = threadIdx.x;
    const int lane = t & 63, w = t >> 6;
    const int p0 = blockIdx.x * 256 + w * 64;
    const float bias = b2e[lane];
    float s = 0.f;
    int prev = dsts[p0];
    #pragma unroll 4
    for (int i = 0; i < 64; i++){
        const int p = p0 + i;
        const int d = dsts[p];
        if (d != prev){
            atomicAdd(&hsum[(size_t)prev * EOUTD + lane], s);
            s = 0.f; prev = d;
        }
        const float q  = Qf[(size_t)p * 64 + lane];
        const float pv = P2f[(size_t)srcs[p] * 64 + lane];
        s += lrelu(pv + q + bias);
    }
    atomicAdd(&hsum[(size_t)prev * EOUTD + lane], s);
}

// ---------------- node update (MFMA): out = leaky([A1, hsum/cnt] @ W + b) ----------------
template<int K1, int K2, bool WRITE_BF16>
__global__ __launch_bounds__(256) void k_node_mfma(
    const unsigned short* __restrict__ A1b, const float* __restrict__ hsum,
    const float* __restrict__ cntf,
    const unsigned short* __restrict__ Wt, const float* __restrict__ bias,
    float* __restrict__ outf, unsigned short* __restrict__ outb, int M)
{
    constexpr int K = K1 + K2;
    __shared__ unsigned short At[64][K + 8];
    const int t = threadIdx.x;
    const int r0 = blockIdx.x * 64;
    {
        const int r = t >> 2, q = t & 3;
        const int row = r0 + r;
        const bool valid = row < M;
        float rinv = 0.f;
        const unsigned short* a1 = A1b;
        const float* a2 = hsum;
        if (valid){
            rinv = 1.f / fmaxf(cntf[row], 1.f);
            a1 = A1b  + (size_t)row * K1;
            a2 = hsum + (size_t)row * K2;
        }
        for (int kk = q * (K / 4); kk < (q + 1) * (K / 4); kk += 8){
            ushort8 u;
            if (!valid){
                u = (ushort8){0,0,0,0,0,0,0,0};
            } else if (kk < K1){
                u = *(const ushort8*)(a1 + kk);
            } else {
                float4 f0 = ld4(a2 + (kk - K1)), f1 = ld4(a2 + (kk - K1) + 4);
                u = (ushort8){f2b(f0.x*rinv), f2b(f0.y*rinv), f2b(f0.z*rinv), f2b(f0.w*rinv),
                              f2b(f1.x*rinv), f2b(f1.y*rinv), f2b(f1.z*rinv), f2b(f1.w*rinv)};
            }
            *(ushort8*)&At[r][kk] = u;
        }
    }
    __syncthreads();
    const int lane = t & 63, w = t >> 6;
    const int fr = lane & 15, fq = lane >> 4;
    floatx4 acc[16] = {};
    #pragma unroll
    for (int ks = 0; ks < K / 32; ks++){
        const int k = ks * 32 + fq * 8;
        bhalf8 a = *(bhalf8*)&At[w * 16 + fr][k];
        #pragma unroll
        for (int n = 0; n < 16; n++){
            bhalf8 b = *(const bhalf8*)(Wt + (size_t)(n * 16 + fr) * K + k);
            acc[n] = __builtin_amdgcn_mfma_f32_16x16x32_bf16(a, b, acc[n], 0, 0, 0);
        }
    }
    #pragma unroll
    for (int n = 0; n < 16; n++){
        const int col = n * 16 + fr;
        const float bv = bias[col];
        #pragma unroll
        for (int rr = 0; rr < 4; rr++){
            const int row = r0 + w * 16 + fq * 4 + rr;
            if (row < M){
                float o = lrelu(acc[n][rr] + bv);
                outf[(size_t)row * 256 + col] = o;
                if (WRITE_BF16) outb[(size_t)row * 256 + col] = f2b(o);
            }
        }
    }
}

// ---------------- attention: q,k,v ----------------
__global__ __launch_bounds__(256) void k_attn_qkv(
    const float* __restrict__ x1, const int* __restrict__ col_idx,
    const float* __restrict__ pe,
    const float* __restrict__ Wq, const float* __restrict__ Wk, const float* __restrict__ Wv,
    float* __restrict__ qo, float* __restrict__ ko, float* __restrict__ vo)
{
    __shared__ float c[256];
    const int i = blockIdx.x, t = threadIdx.x;
    const int col = col_idx[i];
    c[t] = x1[(size_t)col * 256 + t] + pe[i * 256 + t];
    __syncthreads();
    float aq = 0.f, ak = 0.f, av = 0.f;
    #pragma unroll 4
    for (int kk = 0; kk < 256; kk++){
        float cv = c[kk];
        aq += cv * Wq[kk * 256 + t];
        ak += cv * Wk[kk * 256 + t];
        av += cv * Wv[kk * 256 + t];
    }
    qo[i * 256 + t] = aq; ko[i * 256 + t] = ak; vo[i * 256 + t] = av;
}

// ---------------- attention: dist = softmax(q @ k^T / 16) ----------------
__global__ __launch_bounds__(128) void k_attn_dist(
    const float* __restrict__ q, const float* __restrict__ k, float* __restrict__ dist)
{
    __shared__ float qr[256];
    __shared__ float red[128];
    const int i = blockIdx.x, t = threadIdx.x;
    qr[t] = q[i * 256 + t]; qr[t + 128] = q[i * 256 + t + 128];
    __syncthreads();
    float s = 0.f;
    #pragma unroll 4
    for (int kk = 0; kk < 256; kk++) s += qr[kk] * k[t * 256 + kk];
    s *= 0.0625f;
    red[t] = s; __syncthreads();
    for (int off = 64; off; off >>= 1){ if (t < off) red[t] = fmaxf(red[t], red[t + off]); __syncthreads(); }
    float m = red[0]; __syncthreads();
    float ex = expf(s - m);
    red[t] = ex; __syncthreads();
    for (int off = 64; off; off >>= 1){ if (t < off) red[t] += red[t + off]; __syncthreads(); }
    dist[i * 128 + t] = ex / red[0];
}

// ---------------- attention tail ----------------
__global__ __launch_bounds__(256) void k_attn_out(
    const float* __restrict__ dist, const float* __restrict__ v,
    const float* __restrict__ Wref, const float* __restrict__ bref,
    const float* __restrict__ Wc, const float* __restrict__ bep,
    float* __restrict__ colWc)
{
    __shared__ float dr[128];
    __shared__ float c2[256];
    __shared__ float nc[256];
    const int i = blockIdx.x, t = threadIdx.x;
    if (t < 128) dr[t] = dist[i * 128 + t];
    __syncthreads();
    float s = 0.f;
    #pragma unroll 4
    for (int j = 0; j < 128; j++) s += dr[j] * v[j * 256 + t];
    c2[t] = 2.f * s;
    __syncthreads();
    float a = 0.f;
    #pragma unroll 4
    for (int kk = 0; kk < 256; kk++) a += c2[kk] * Wref[kk * 256 + t];
    a += bref[t];
    nc[t] = 1.f / (1.f + expf(-a));
    __syncthreads();
    if (t < 64){
        float o = 0.f;
        #pragma unroll 4
        for (int kk = 0; kk < 256; kk++) o += nc[kk] * Wc[kk * 64 + t];
        colWc[i * 64 + t] = o + bep[t];
    }
}

// ---------------- rowWr = x2[row_idx] @ Wr ----------------
__global__ __launch_bounds__(256) void k_rowwr(
    const float* __restrict__ x2, const int* __restrict__ row_idx,
    const float* __restrict__ Wr, float* __restrict__ rw)
{
    __shared__ float A[16][260];
    const int t = threadIdx.x;
    const int r0 = blockIdx.x * 16;
    const int rl = t >> 4, cg = t & 15;
    const int ridx = row_idx[r0 + rl];
    const float* ar = x2 + (size_t)ridx * 256;
    for (int i = cg; i < 64; i += 16) *(float4*)(&A[rl][i * 4]) = ld4(ar + i * 4);
    __syncthreads();
    float acc[4] = {0.f, 0.f, 0.f, 0.f};
    #pragma unroll 4
    for (int kk = 0; kk < 256; kk++){
        float4 w = ld4(Wr + (size_t)kk * 64 + cg * 4);
        float a = A[rl][kk];
        acc[0] += a * w.x; acc[1] += a * w.y; acc[2] += a * w.z; acc[3] += a * w.w;
    }
    *(float4*)(rw + (size_t)(r0 + rl) * 64 + cg * 4) = make_float4(acc[0], acc[1], acc[2], acc[3]);
}

// ---------------- fused: pred -> d_out, imputation, classifier, log_softmax ----------------
__global__ __launch_bounds__(256) void k_pred(
    const float* __restrict__ rowWr, const float* __restrict__ colWc,
    const void* __restrict__ maskp, const int* __restrict__ modep,
    const float* __restrict__ real, const float* __restrict__ Wcls, const float* __restrict__ bcls,
    float* __restrict__ out)
{
    const int t  = threadIdx.x;
    const int r0 = blockIdx.x * 4;
    const int mode = *modep;
    float acc[4][10];
    #pragma unroll
    for (int g = 0; g < 4; g++)
        #pragma unroll
        for (int c = 0; c < 10; c++) acc[g][c] = 0.f;
    float* pred = out + RROWS * NCLS;
    #pragma unroll 2
    for (int i = 0; i < 8; i++){
        int e4   = i * 256 + t;
        int base = e4 * 4;
        int c = base >> 6;
        int j = base & 63;
        float4 cw = ld4(colWc + c * 64 + j);
        float w40[40];
        #pragma unroll
        for (int u = 0; u < 10; u++){
            float4 wv = ld4(Wcls + (size_t)base * 10 + u * 4);
            w40[u*4+0] = wv.x; w40[u*4+1] = wv.y; w40[u*4+2] = wv.z; w40[u*4+3] = wv.w;
        }
        #pragma unroll
        for (int g = 0; g < 4; g++){
            int rr = r0 + g;
            float4 rwv = ld4(rowWr + (size_t)rr * 64 + j);
            float4 p;
            p.x = lrelu(rwv.x + cw.x); p.y = lrelu(rwv.y + cw.y);
            p.z = lrelu(rwv.z + cw.z); p.w = lrelu(rwv.w + cw.w);
            *(float4*)(pred + (size_t)rr * 8192 + base) = p;
            bool m;
            if (mode == 2)      m = ((const unsigned char*)maskp)[rr * NCOLS + c] != 0;
            else if (mode == 0) m = ((const int*)maskp)[rr * NCOLS + c] != 0;
            else                m = ((const float*)maskp)[rr * NCOLS + c] != 0.f;
            float4 im = p;
            if (m) im = ld4(real + (size_t)rr * 8192 + base);
            #pragma unroll
            for (int cls = 0; cls < 10; cls++){
                acc[g][cls] += im.x * w40[cls]      + im.y * w40[10 + cls]
                             + im.z * w40[20 + cls] + im.w * w40[30 + cls];
            }
        }
    }
    #pragma unroll
    for (int g = 0; g < 4; g++)
        #pragma unroll
        for (int cls = 0; cls < 10; cls++){
            float v = acc[g][cls];
            for (int off = 32; off; off >>= 1) v += __shfl_down(v, off, 64);
            acc[g][cls] = v;
        }
    __shared__ float part[4][40];
    const int wid = t >> 6, lane = t & 63;
    if (lane == 0){
        #pragma unroll
        for (int g = 0; g < 4; g++)
            #pragma unroll
            for (int cls = 0; cls < 10; cls++) part[wid][g * 10 + cls] = acc[g][cls];
    }
    __syncthreads();
    __shared__ float logit[40];
    if (t < 40) logit[t] = part[0][t] + part[1][t] + part[2][t] + part[3][t] + bcls[t % 10];
    __syncthreads();
    if (t < 4){
        float m = -1e30f;
        #pragma unroll
        for (int cls = 0; cls < 10; cls++) m = fmaxf(m, logit[t * 10 + cls]);
        float se = 0.f;
        #pragma unroll
        for (int cls = 0; cls < 10; cls++) se += expf(logit[t * 10 + cls] - m);
        float ls = logf(se) + m;
        #pragma unroll
        for (int cls = 0; cls < 10; cls++) out[(r0 + t) * 10 + cls] = logit[t * 10 + cls] - ls;
    }
}

extern "C" void kernel_launch(void* const* d_in, const int* in_sizes, int n_in,
                              void* d_out, int out_size, void* d_ws, size_t ws_size,
                              hipStream_t stream)
{
    const float* x      = (const float*)d_in[0];
    const float* e      = (const float*)d_in[1];
    const int*   src    = (const int*)d_in[2];
    const int*   dst    = (const int*)d_in[3];
    const int*   row_idx= (const int*)d_in[4];
    const int*   col_idx= (const int*)d_in[5];
    const float* real   = (const float*)d_in[6];
    const void*  mask   = d_in[7];
    const float* W1e    = (const float*)d_in[8];
    const float* b1e    = (const float*)d_in[9];
    const float* W1n    = (const float*)d_in[10];
    const float* b1n    = (const float*)d_in[11];
    const float* W2e    = (const float*)d_in[12];
    const float* b2e    = (const float*)d_in[13];
    const float* W2n    = (const float*)d_in[14];
    const float* b2n    = (const float*)d_in[15];
    const float* pe     = (const float*)d_in[16];
    const float* Wq     = (const float*)d_in[17];
    const float* Wk     = (const float*)d_in[18];
    const float* Wv     = (const float*)d_in[19];
    const float* Wref   = (const float*)d_in[20];
    const float* bref   = (const float*)d_in[21];
    const float* Wr     = (const float*)d_in[22];
    const float* Wc     = (const float*)d_in[23];
    const float* bep    = (const float*)d_in[24];
    const float* Wcls   = (const float*)d_in[25];
    const float* bcls   = (const float*)d_in[26];

    float* ws = (float*)d_ws;
    size_t off = 0;
    float* h1sum = ws + off; off += (size_t)NNODES * EHID;   // 3.84M
    float* h2sum = ws + off; off += (size_t)NNODES * EOUTD;  // 1.92M
    int*   cnt_i = (int*)(ws + off); off += NNODES;
    const size_t zero_floats = off;                           // zeroed each call
    float* cntf  = ws + off; off += NNODES;
    int*   cursor= (int*)(ws + off); off += NNODES;
    int*   srcs  = (int*)(ws + off); off += NEDGES;
    int*   dsts  = (int*)(ws + off); off += NEDGES;
    int*   eidx  = (int*)(ws + off); off += NEDGES;
    float* x1    = ws + off; off += (size_t)NNODES * NHID;
    float* x2    = ws + off; off += (size_t)NNODES * NOUTD;
    unsigned short* xb    = (unsigned short*)(ws + off); off += (size_t)NNODES * NIN  / 2;
    unsigned short* x1b   = (unsigned short*)(ws + off); off += (size_t)NNODES * NHID / 2;
    unsigned short* W1tT  = (unsigned short*)(ws + off); off += 128 * 128 / 2;
    unsigned short* W1bT  = (unsigned short*)(ws + off); off += 128 * 64 / 2;
    unsigned short* W2tT  = (unsigned short*)(ws + off); off += 64 * 256 / 2;
    unsigned short* W2bT  = (unsigned short*)(ws + off); off += 64 * 128 / 2;
    unsigned short* W1nTb = (unsigned short*)(ws + off); off += 256 * 256 / 2;
    unsigned short* W2nTb = (unsigned short*)(ws + off); off += 256 * 320 / 2;
    float* P1f   = ws + off; off += (size_t)NNODES * 128;    // 3.84M
    float* P2f   = ws + off; off += (size_t)NNODES * 64;     // 1.92M
    float* qb    = ws + off; off += 128 * 256;
    float* kb    = ws + off; off += 128 * 256;
    float* vb    = ws + off; off += 128 * 256;
    float* distb = ws + off; off += 128 * 128;
    float* colWc = ws + off; off += 128 * 64;
    float* rowWrb= ws + off; off += (size_t)RROWS * EOUTD;
    int*   modep = (int*)(ws + off); off += 4;
    // Q f32 (sorted layout, 480000x64 = 123MB). ws if it fits, else borrow the
    // pred region of d_out (Q fully consumed by k_edge2_lite before k_pred writes).
    float* Qf;
    size_t need = (off + (size_t)NEDGES * 64) * sizeof(float);
    if (ws_size >= need) Qf = ws + off;
    else                 Qf = (float*)d_out + (size_t)RROWS * NCLS;

    hipMemsetAsync(d_ws, 0, zero_floats * sizeof(float), stream);
    k_mask_detect<<<1, 64, 0, stream>>>((const unsigned int*)mask, modep);
    k_hist<<<(NEDGES + 255) / 256, 256, 0, stream>>>(dst, cnt_i);
    k_prefix<<<1, 256, 0, stream>>>(cnt_i, cursor, cntf);
    k_scatter<<<(NEDGES + 255) / 256, 256, 0, stream>>>(src, dst, cursor, srcs, dsts, eidx);
    k_cvt_bf16<<<(NNODES * NIN / 8 + 255) / 256, 256, 0, stream>>>(x, xb, NNODES * NIN / 8);
    k_wT_part<0,   128, 128><<<(128 * 128 + 255) / 256, 256, 0, stream>>>(W1e, W1tT);
    k_wT_part<128, 64,  128><<<(128 * 64  + 255) / 256, 256, 0, stream>>>(W1e, W1bT);
    k_wT_part<0,   256, 64 ><<<(64 * 256 + 255) / 256, 256, 0, stream>>>(W2e, W2tT);
    k_wT_part<256, 128, 64 ><<<(64 * 128 + 255) / 256, 256, 0, stream>>>(W2e, W2bT);
    k_wT_part<0,   256, 256><<<(256 * 256 + 255) / 256, 256, 0, stream>>>(W1n, W1nTb);
    k_wT_part<0,   320, 256><<<(256 * 320 + 255) / 256, 256, 0, stream>>>(W2n, W2nTb);
    k_gemm_f32<128, 128><<<(NNODES + 63) / 64, 256, 0, stream>>>(xb, W1tT, P1f, NNODES);
    k_edge1_fused<<<NEDGES / 64, 256, 0, stream>>>(e, srcs, dsts, eidx, W1bT, b1e, P1f, W2bT, Qf, h1sum);
    k_node_mfma<NIN, EHID, true><<<(NNODES + 63) / 64, 256, 0, stream>>>(xb, h1sum, cntf, W1nTb, b1n, x1, x1b, NNODES);
    k_gemm_f32<256, 64><<<(NNODES + 63) / 64, 256, 0, stream>>>(x1b, W2tT, P2f, NNODES);
    k_edge2_lite<<<NEDGES / 256, 256, 0, stream>>>(P2f, Qf, srcs, dsts, b2e, h2sum);
    k_node_mfma<NHID, EOUTD, false><<<(NNODES + 63) / 64, 256, 0, stream>>>(x1b, h2sum, cntf, W2nTb, b2n, x2, (unsigned short*)nullptr, NNODES);
    k_attn_qkv<<<128, 256, 0, stream>>>(x1, col_idx, pe, Wq, Wk, Wv, qb, kb, vb);
    k_attn_dist<<<128, 128, 0, stream>>>(qb, kb, distb);
    k_attn_out<<<128, 256, 0, stream>>>(distb, vb, Wref, bref, Wc, bep, colWc);
    k_rowwr<<<RROWS / 16, 256, 0, stream>>>(x2, row_idx, Wr, rowWrb);
    k_pred<<<RROWS / 4, 256, 0, stream>>>(rowWrb, colWc, mask, modep, real, Wcls, bcls, (float*)d_out);
}

// Round 5
// 734.692 us; speedup vs baseline: 3.2550x; 1.1517x over previous
//
#include <hip/hip_runtime.h>
#include <hip/hip_bf16.h>
#include <math.h>

#define NNODES 30000
#define NEDGES 480000
#define RROWS  8192
#define NCOLS  128
#define NIN    128
#define EIN    64
#define NHID   256
#define EHID   128
#define NOUTD  256
#define EOUTD  64
#define NCLS   10

typedef __attribute__((ext_vector_type(8))) unsigned short ushort8;
typedef __attribute__((ext_vector_type(4))) unsigned short ushort4v;
typedef __attribute__((ext_vector_type(8))) short bhalf8;
typedef __attribute__((ext_vector_type(4))) float floatx4;

__device__ __forceinline__ float lrelu(float v){ return v > 0.f ? v : 0.01f * v; }
__device__ __forceinline__ float4 ld4(const float* p){ return *(const float4*)p; }
__device__ __forceinline__ unsigned short f2b(float f){
    unsigned int u = __builtin_bit_cast(unsigned int, f);
    u += 0x7fffu + ((u >> 16) & 1u);
    return (unsigned short)(u >> 16);
}
__device__ __forceinline__ float b2f(unsigned short b){
    unsigned int u = ((unsigned int)b) << 16;
    return __builtin_bit_cast(float, u);
}

// ---------------- mask dtype detector ----------------
__global__ void k_mask_detect(const unsigned int* __restrict__ m, int* __restrict__ mode){
    if (threadIdx.x == 0 && blockIdx.x == 0){
        bool allI32 = true, allF32 = true;
        for (int i = 0; i < 64; i++){
            unsigned int v = m[i];
            if (!(v == 0u || v == 1u)) allI32 = false;
            if (!(v == 0u || v == 0x3F800000u)) allF32 = false;
        }
        *mode = allI32 ? 0 : (allF32 ? 1 : 2);
    }
}

// ---------------- histogram of dst ----------------
__global__ void k_hist(const int* __restrict__ dst, int* __restrict__ cnt_i){
    int i = blockIdx.x * 256 + threadIdx.x;
    if (i < NEDGES) atomicAdd(&cnt_i[dst[i]], 1);
}

// ---------------- exclusive prefix over 30000 bins ----------------
__global__ __launch_bounds__(256) void k_prefix(const int* __restrict__ cnt_i,
                                                int* __restrict__ cursor, float* __restrict__ cntf){
    __shared__ int part[256];
    const int t = threadIdx.x;
    const int CH = (NNODES + 255) / 256;
    const int lo = t * CH, hi = min(lo + CH, NNODES);
    int s = 0;
    for (int i = lo; i < hi; i++) s += cnt_i[i];
    part[t] = s;
    __syncthreads();
    if (t == 0){
        int acc = 0;
        for (int i = 0; i < 256; i++){ int v = part[i]; part[i] = acc; acc += v; }
    }
    __syncthreads();
    int run = part[t];
    for (int i = lo; i < hi; i++){
        cursor[i] = run;
        run += cnt_i[i];
        cntf[i] = (float)cnt_i[i];
    }
}

// ---------------- scatter: sorted-by-dst edge arrays ----------------
__global__ void k_scatter(const int* __restrict__ src, const int* __restrict__ dst,
                          int* __restrict__ cursor,
                          int* __restrict__ srcs, int* __restrict__ dsts, int* __restrict__ eidx){
    int i = blockIdx.x * 256 + threadIdx.x;
    if (i >= NEDGES) return;
    int d = dst[i];
    int pos = atomicAdd(&cursor[d], 1);
    srcs[pos] = src[i];
    dsts[pos] = d;
    eidx[pos] = i;
}

// ---------------- f32 -> bf16 bulk convert ----------------
__global__ void k_cvt_bf16(const float* __restrict__ in, unsigned short* __restrict__ out, int n8){
    int i = blockIdx.x * 256 + threadIdx.x;
    if (i >= n8) return;
    float4 a = ld4(in + (size_t)i * 8), b = ld4(in + (size_t)i * 8 + 4);
    ushort8 o = {f2b(a.x), f2b(a.y), f2b(a.z), f2b(a.w), f2b(b.x), f2b(b.y), f2b(b.z), f2b(b.w)};
    *(ushort8*)(out + (size_t)i * 8) = o;
}

// ---------------- W[KTOT][N] rows [KOFF, KOFF+KSUB) -> Wt[N][KSUB] bf16 ----------------
template<int KOFF, int KSUB, int N>
__global__ void k_wT_part(const float* __restrict__ W, unsigned short* __restrict__ Wt){
    int idx = blockIdx.x * 256 + threadIdx.x;
    if (idx >= N * KSUB) return;
    int n = idx / KSUB, k = idx % KSUB;
    Wt[idx] = f2b(W[(size_t)(KOFF + k) * N + n]);
}

// ---------------- small GEMM: out_bf16[M,N] = Ab[M,K] @ Wt[N,K] ----------------
template<int K, int N>
__global__ __launch_bounds__(256) void k_gemm_b16(
    const unsigned short* __restrict__ Ab, const unsigned short* __restrict__ Wt,
    unsigned short* __restrict__ outb, int M)
{
    __shared__ unsigned short At[64][K + 8];
    const int t = threadIdx.x;
    const int r0 = blockIdx.x * 64;
    {
        const int r = t >> 2, q = t & 3;
        const int row = r0 + r;
        const bool valid = row < M;
        const unsigned short* a = Ab + (size_t)(valid ? row : 0) * K;
        for (int kk = q * (K / 4); kk < (q + 1) * (K / 4); kk += 8){
            ushort8 u;
            if (valid) u = *(const ushort8*)(a + kk);
            else       u = (ushort8){0,0,0,0,0,0,0,0};
            *(ushort8*)&At[r][kk] = u;
        }
    }
    __syncthreads();
    const int lane = t & 63, w = t >> 6;
    const int fr = lane & 15, fq = lane >> 4;
    constexpr int NF = N / 16;
    floatx4 acc[NF] = {};
    #pragma unroll
    for (int ks = 0; ks < K / 32; ks++){
        const int k = ks * 32 + fq * 8;
        bhalf8 a = *(bhalf8*)&At[w * 16 + fr][k];
        #pragma unroll
        for (int n = 0; n < NF; n++){
            bhalf8 b = *(const bhalf8*)(Wt + (size_t)(n * 16 + fr) * K + k);
            acc[n] = __builtin_amdgcn_mfma_f32_16x16x32_bf16(a, b, acc[n], 0, 0, 0);
        }
    }
    #pragma unroll
    for (int n = 0; n < NF; n++){
        const int col = n * 16 + fr;
        #pragma unroll
        for (int rr = 0; rr < 4; rr++){
            const int row = r0 + w * 16 + fq * 4 + rr;
            if (row < M) outb[(size_t)row * N + col] = f2b(acc[n][rr]);
        }
    }
}

// ---------------- fused edge layer 1 ----------------
// per 64-edge tile (dst-sorted):
//   e1 = leaky(P1[src] + e@W1bT + b1e)   (kept in LDS, f32)
//   Q  = e1 @ W2bT                        (written bf16, sorted/coalesced)
//   h1sum += run-reduced column sums of e1
__global__ __launch_bounds__(256) void k_edge1_fused(
    const float* __restrict__ e,
    const int* __restrict__ srcs, const int* __restrict__ dsts, const int* __restrict__ eidx,
    const unsigned short* __restrict__ W1bT, const float* __restrict__ b1e,
    const unsigned short* __restrict__ P1b, const unsigned short* __restrict__ W2bT,
    unsigned short* __restrict__ Qb, float* __restrict__ hsum)
{
    __shared__ __align__(16) char smem[64 * 132 * 4];   // Cf f32[64][132]; Et ushort[64][72] overlays
    unsigned short (*Et)[72] = (unsigned short(*)[72])smem;
    float (*Cf)[132] = (float(*)[132])smem;
    __shared__ int dstS[64];
    __shared__ int srcS[64];
    const int t = threadIdx.x;
    const int p0 = blockIdx.x * 64;
    // phase A: stage e rows (f32 -> bf16), load src/dst
    {
        const int r = t >> 2, q = t & 3;
        const int p = p0 + r;
        if (q == 0){ dstS[r] = dsts[p]; srcS[r] = srcs[p]; }
        const int ei = eidx[p];
        const float* ep = e + (size_t)ei * 64 + q * 16;
        float4 f0 = ld4(ep), f1 = ld4(ep + 4), f2 = ld4(ep + 8), f3 = ld4(ep + 12);
        ushort8 u0 = {f2b(f0.x), f2b(f0.y), f2b(f0.z), f2b(f0.w), f2b(f1.x), f2b(f1.y), f2b(f1.z), f2b(f1.w)};
        ushort8 u1 = {f2b(f2.x), f2b(f2.y), f2b(f2.z), f2b(f2.w), f2b(f3.x), f2b(f3.y), f2b(f3.z), f2b(f3.w)};
        *(ushort8*)&Et[r][q * 16]     = u0;
        *(ushort8*)&Et[r][q * 16 + 8] = u1;
    }
    __syncthreads();
    const int lane = t & 63, w = t >> 6;
    const int wm = w >> 1, wn = w & 1;
    const int fr = lane & 15, fq = lane >> 4;
    // phase B: MFMA1  (64x128) = e_tile(64xK64) @ W1bT
    floatx4 acc1[2][4] = {};
    #pragma unroll
    for (int ks = 0; ks < 2; ks++){
        const int k = ks * 32 + fq * 8;
        bhalf8 a0 = *(bhalf8*)&Et[wm * 32 + fr][k];
        bhalf8 a1 = *(bhalf8*)&Et[wm * 32 + 16 + fr][k];
        #pragma unroll
        for (int n = 0; n < 4; n++){
            const int col = wn * 64 + n * 16 + fr;
            bhalf8 b = *(const bhalf8*)(W1bT + (size_t)col * 64 + k);
            acc1[0][n] = __builtin_amdgcn_mfma_f32_16x16x32_bf16(a0, b, acc1[0][n], 0, 0, 0);
            acc1[1][n] = __builtin_amdgcn_mfma_f32_16x16x32_bf16(a1, b, acc1[1][n], 0, 0, 0);
        }
    }
    __syncthreads();   // Et reads done; Cf may overlay
    // phase C: e1 = leaky(acc + P1[src] + b1e) -> Cf
    #pragma unroll
    for (int m = 0; m < 2; m++){
        #pragma unroll
        for (int n = 0; n < 4; n++){
            const int col = wn * 64 + n * 16 + fr;
            const float bv = b1e[col];
            #pragma unroll
            for (int r = 0; r < 4; r++){
                const int row = wm * 32 + m * 16 + fq * 4 + r;
                const float pv = b2f(P1b[(size_t)srcS[row] * 128 + col]);
                Cf[row][col] = lrelu(acc1[m][n][r] + pv + bv);
            }
        }
    }
    __syncthreads();
    // phase D: Q = e1 @ W2bT  (64x64, K=128), store bf16
    {
        floatx4 acc2[4] = {};
        #pragma unroll
        for (int ks = 0; ks < 4; ks++){
            const int k = ks * 32 + fq * 8;
            float4 f0 = ld4(&Cf[w * 16 + fr][k]);
            float4 f1 = ld4(&Cf[w * 16 + fr][k + 4]);
            ushort8 u = {f2b(f0.x), f2b(f0.y), f2b(f0.z), f2b(f0.w), f2b(f1.x), f2b(f1.y), f2b(f1.z), f2b(f1.w)};
            bhalf8 a = *(bhalf8*)&u;
            #pragma unroll
            for (int n = 0; n < 4; n++){
                bhalf8 b = *(const bhalf8*)(W2bT + (size_t)(n * 16 + fr) * 128 + k);
                acc2[n] = __builtin_amdgcn_mfma_f32_16x16x32_bf16(a, b, acc2[n], 0, 0, 0);
            }
        }
        #pragma unroll
        for (int n = 0; n < 4; n++){
            const int col = n * 16 + fr;
            #pragma unroll
            for (int r = 0; r < 4; r++){
                const int row = w * 16 + fq * 4 + r;
                Qb[(size_t)(p0 + row) * 64 + col] = f2b(acc2[n][r]);
            }
        }
    }
    // phase F: run-reduced scatter-add of e1 (Cf) to h1sum
    {
        const int col = t & 127, half = t >> 7;
        const int rbase = half * 32;
        float s = 0.f;
        int prev = dstS[rbase];
        #pragma unroll 4
        for (int rr = 0; rr < 32; rr++){
            const int r = rbase + rr;
            const int d = dstS[r];
            if (d != prev){
                atomicAdd(&hsum[(size_t)prev * EHID + col], s);
                s = 0.f; prev = d;
            }
            s += Cf[r][col];
        }
        atomicAdd(&hsum[(size_t)prev * EHID + col], s);
    }
}

// ---------------- edge layer 2 (lite): e2 = leaky(P2[src] + Q + b2e), scatter ----------------
__global__ __launch_bounds__(256) void k_edge2_lite(
    const unsigned short* __restrict__ P2b, const unsigned short* __restrict__ Qb,
    const int* __restrict__ srcs, const int* __restrict__ dsts,
    const float* __restrict__ b2e, float* __restrict__ hsum)
{
    const int t = threadIdx.x;
    const int lane = t & 63, w = t >> 6;
    const int p0 = blockIdx.x * 256 + w * 64;
    const float bias = b2e[lane];
    float s = 0.f;
    int prev = dsts[p0];
    #pragma unroll 4
    for (int i = 0; i < 64; i++){
        const int p = p0 + i;
        const int d = dsts[p];
        if (d != prev){
            atomicAdd(&hsum[(size_t)prev * EOUTD + lane], s);
            s = 0.f; prev = d;
        }
        const float q  = b2f(Qb[(size_t)p * 64 + lane]);
        const float pv = b2f(P2b[(size_t)srcs[p] * 64 + lane]);
        s += lrelu(pv + q + bias);
    }
    atomicAdd(&hsum[(size_t)prev * EOUTD + lane], s);
}

// ---------------- node update (MFMA): out = leaky([A1, hsum/cnt] @ W + b) ----------------
template<int K1, int K2, bool WRITE_BF16>
__global__ __launch_bounds__(256) void k_node_mfma(
    const unsigned short* __restrict__ A1b, const float* __restrict__ hsum,
    const float* __restrict__ cntf,
    const unsigned short* __restrict__ Wt, const float* __restrict__ bias,
    float* __restrict__ outf, unsigned short* __restrict__ outb, int M)
{
    constexpr int K = K1 + K2;
    __shared__ unsigned short At[64][K + 8];
    const int t = threadIdx.x;
    const int r0 = blockIdx.x * 64;
    {
        const int r = t >> 2, q = t & 3;
        const int row = r0 + r;
        const bool valid = row < M;
        float rinv = 0.f;
        const unsigned short* a1 = A1b;
        const float* a2 = hsum;
        if (valid){
            rinv = 1.f / fmaxf(cntf[row], 1.f);
            a1 = A1b  + (size_t)row * K1;
            a2 = hsum + (size_t)row * K2;
        }
        for (int kk = q * (K / 4); kk < (q + 1) * (K / 4); kk += 8){
            ushort8 u;
            if (!valid){
                u = (ushort8){0,0,0,0,0,0,0,0};
            } else if (kk < K1){
                u = *(const ushort8*)(a1 + kk);
            } else {
                float4 f0 = ld4(a2 + (kk - K1)), f1 = ld4(a2 + (kk - K1) + 4);
                u = (ushort8){f2b(f0.x*rinv), f2b(f0.y*rinv), f2b(f0.z*rinv), f2b(f0.w*rinv),
                              f2b(f1.x*rinv), f2b(f1.y*rinv), f2b(f1.z*rinv), f2b(f1.w*rinv)};
            }
            *(ushort8*)&At[r][kk] = u;
        }
    }
    __syncthreads();
    const int lane = t & 63, w = t >> 6;
    const int fr = lane & 15, fq = lane >> 4;
    floatx4 acc[16] = {};
    #pragma unroll
    for (int ks = 0; ks < K / 32; ks++){
        const int k = ks * 32 + fq * 8;
        bhalf8 a = *(bhalf8*)&At[w * 16 + fr][k];
        #pragma unroll
        for (int n = 0; n < 16; n++){
            bhalf8 b = *(const bhalf8*)(Wt + (size_t)(n * 16 + fr) * K + k);
            acc[n] = __builtin_amdgcn_mfma_f32_16x16x32_bf16(a, b, acc[n], 0, 0, 0);
        }
    }
    #pragma unroll
    for (int n = 0; n < 16; n++){
        const int col = n * 16 + fr;
        const float bv = bias[col];
        #pragma unroll
        for (int rr = 0; rr < 4; rr++){
            const int row = r0 + w * 16 + fq * 4 + rr;
            if (row < M){
                float o = lrelu(acc[n][rr] + bv);
                outf[(size_t)row * 256 + col] = o;
                if (WRITE_BF16) outb[(size_t)row * 256 + col] = f2b(o);
            }
        }
    }
}

// ---------------- attention: q,k,v ----------------
__global__ __launch_bounds__(256) void k_attn_qkv(
    const float* __restrict__ x1, const int* __restrict__ col_idx,
    const float* __restrict__ pe,
    const float* __restrict__ Wq, const float* __restrict__ Wk, const float* __restrict__ Wv,
    float* __restrict__ qo, float* __restrict__ ko, float* __restrict__ vo)
{
    __shared__ float c[256];
    const int i = blockIdx.x, t = threadIdx.x;
    const int col = col_idx[i];
    c[t] = x1[(size_t)col * 256 + t] + pe[i * 256 + t];
    __syncthreads();
    float aq = 0.f, ak = 0.f, av = 0.f;
    #pragma unroll 4
    for (int kk = 0; kk < 256; kk++){
        float cv = c[kk];
        aq += cv * Wq[kk * 256 + t];
        ak += cv * Wk[kk * 256 + t];
        av += cv * Wv[kk * 256 + t];
    }
    qo[i * 256 + t] = aq; ko[i * 256 + t] = ak; vo[i * 256 + t] = av;
}

// ---------------- attention: dist = softmax(q @ k^T / 16) ----------------
__global__ __launch_bounds__(128) void k_attn_dist(
    const float* __restrict__ q, const float* __restrict__ k, float* __restrict__ dist)
{
    __shared__ float qr[256];
    __shared__ float red[128];
    const int i = blockIdx.x, t = threadIdx.x;
    qr[t] = q[i * 256 + t]; qr[t + 128] = q[i * 256 + t + 128];
    __syncthreads();
    float s = 0.f;
    #pragma unroll 4
    for (int kk = 0; kk < 256; kk++) s += qr[kk] * k[t * 256 + kk];
    s *= 0.0625f;
    red[t] = s; __syncthreads();
    for (int off = 64; off; off >>= 1){ if (t < off) red[t] = fmaxf(red[t], red[t + off]); __syncthreads(); }
    float m = red[0]; __syncthreads();
    float ex = expf(s - m);
    red[t] = ex; __syncthreads();
    for (int off = 64; off; off >>= 1){ if (t < off) red[t] += red[t + off]; __syncthreads(); }
    dist[i * 128 + t] = ex / red[0];
}

// ---------------- attention tail ----------------
__global__ __launch_bounds__(256) void k_attn_out(
    const float* __restrict__ dist, const float* __restrict__ v,
    const float* __restrict__ Wref, const float* __restrict__ bref,
    const float* __restrict__ Wc, const float* __restrict__ bep,
    float* __restrict__ colWc)
{
    __shared__ float dr[128];
    __shared__ float c2[256];
    __shared__ float nc[256];
    const int i = blockIdx.x, t = threadIdx.x;
    if (t < 128) dr[t] = dist[i * 128 + t];
    __syncthreads();
    float s = 0.f;
    #pragma unroll 4
    for (int j = 0; j < 128; j++) s += dr[j] * v[j * 256 + t];
    c2[t] = 2.f * s;
    __syncthreads();
    float a = 0.f;
    #pragma unroll 4
    for (int kk = 0; kk < 256; kk++) a += c2[kk] * Wref[kk * 256 + t];
    a += bref[t];
    nc[t] = 1.f / (1.f + expf(-a));
    __syncthreads();
    if (t < 64){
        float o = 0.f;
        #pragma unroll 4
        for (int kk = 0; kk < 256; kk++) o += nc[kk] * Wc[kk * 64 + t];
        colWc[i * 64 + t] = o + bep[t];
    }
}

// ---------------- rowWr = x2[row_idx] @ Wr ----------------
__global__ __launch_bounds__(256) void k_rowwr(
    const float* __restrict__ x2, const int* __restrict__ row_idx,
    const float* __restrict__ Wr, float* __restrict__ rw)
{
    __shared__ float A[16][260];
    const int t = threadIdx.x;
    const int r0 = blockIdx.x * 16;
    const int rl = t >> 4, cg = t & 15;
    const int ridx = row_idx[r0 + rl];
    const float* ar = x2 + (size_t)ridx * 256;
    for (int i = cg; i < 64; i += 16) *(float4*)(&A[rl][i * 4]) = ld4(ar + i * 4);
    __syncthreads();
    float acc[4] = {0.f, 0.f, 0.f, 0.f};
    #pragma unroll 4
    for (int kk = 0; kk < 256; kk++){
        float4 w = ld4(Wr + (size_t)kk * 64 + cg * 4);
        float a = A[rl][kk];
        acc[0] += a * w.x; acc[1] += a * w.y; acc[2] += a * w.z; acc[3] += a * w.w;
    }
    *(float4*)(rw + (size_t)(r0 + rl) * 64 + cg * 4) = make_float4(acc[0], acc[1], acc[2], acc[3]);
}

// ---------------- fused: pred -> d_out, imputation, classifier, log_softmax ----------------
// 8 rows per block; colWc/rowWr/mask staged in LDS; Wcls streamed from L2.
__global__ __launch_bounds__(256) void k_pred8(
    const float* __restrict__ rowWr, const float* __restrict__ colWc,
    const void* __restrict__ maskp, const int* __restrict__ modep,
    const float* __restrict__ real, const float* __restrict__ Wcls, const float* __restrict__ bcls,
    float* __restrict__ out)
{
    __shared__ float colWc_s[8192];          // 32 KB
    __shared__ float rowWr_s[8 * 64];        // 2 KB
    __shared__ unsigned char mask_s[8 * 128];
    __shared__ float part[4][80];
    __shared__ float logits_s[80];
    const int t  = threadIdx.x;
    const int r0 = blockIdx.x * 8;
    const int mode = *modep;
    // stage colWc (entire 128x64)
    for (int idx = t; idx < 2048; idx += 256)
        *(float4*)&colWc_s[idx * 4] = ld4(colWc + idx * 4);
    // stage rowWr rows
    for (int idx = t; idx < 128; idx += 256)
        *(float4*)&rowWr_s[idx * 4] = ld4(rowWr + (size_t)r0 * 64 + idx * 4);
    // stage + decode mask tile
    for (int idx = t; idx < 1024; idx += 256){
        const int g = idx >> 7, c = idx & 127;
        const int gi = (r0 + g) * 128 + c;
        bool m;
        if (mode == 2)      m = ((const unsigned char*)maskp)[gi] != 0;
        else if (mode == 0) m = ((const int*)maskp)[gi] != 0;
        else                m = ((const float*)maskp)[gi] != 0.f;
        mask_s[idx] = m ? 1 : 0;
    }
    __syncthreads();

    float acc[8][10];
    #pragma unroll
    for (int g = 0; g < 8; g++)
        #pragma unroll
        for (int c = 0; c < 10; c++) acc[g][c] = 0.f;
    float* pred = out + RROWS * NCLS;

    #pragma unroll 1
    for (int i = 0; i < 8; i++){
        const int e4   = i * 256 + t;      // float4 index within row
        const int base = e4 * 4;           // flat element index (c*64+j)
        const int c = base >> 6;
        const int j = base & 63;
        float4 cw = ld4(&colWc_s[c * 64 + j]);
        float w40[40];
        #pragma unroll
        for (int u = 0; u < 10; u++){
            float4 wv = ld4(Wcls + (size_t)base * 10 + u * 4);
            w40[u*4+0] = wv.x; w40[u*4+1] = wv.y; w40[u*4+2] = wv.z; w40[u*4+3] = wv.w;
        }
        #pragma unroll
        for (int g = 0; g < 8; g++){
            const int rr = r0 + g;
            float4 rwv = ld4(&rowWr_s[g * 64 + j]);
            float4 p;
            p.x = lrelu(rwv.x + cw.x); p.y = lrelu(rwv.y + cw.y);
            p.z = lrelu(rwv.z + cw.z); p.w = lrelu(rwv.w + cw.w);
            *(float4*)(pred + (size_t)rr * 8192 + base) = p;
            float4 im = p;
            if (mask_s[g * 128 + c]) im = ld4(real + (size_t)rr * 8192 + base);
            #pragma unroll
            for (int cls = 0; cls < 10; cls++){
                acc[g][cls] += im.x * w40[cls]      + im.y * w40[10 + cls]
                             + im.z * w40[20 + cls] + im.w * w40[30 + cls];
            }
        }
    }
    // wave reduce (64 lanes)
    #pragma unroll
    for (int g = 0; g < 8; g++)
        #pragma unroll
        for (int cls = 0; cls < 10; cls++){
            float v = acc[g][cls];
            for (int off = 32; off; off >>= 1) v += __shfl_down(v, off, 64);
            acc[g][cls] = v;
        }
    const int wid = t >> 6, lane = t & 63;
    if (lane == 0){
        #pragma unroll
        for (int g = 0; g < 8; g++)
            #pragma unroll
            for (int cls = 0; cls < 10; cls++) part[wid][g * 10 + cls] = acc[g][cls];
    }
    __syncthreads();
    if (t < 80) logits_s[t] = part[0][t] + part[1][t] + part[2][t] + part[3][t] + bcls[t % 10];
    __syncthreads();
    if (t < 8){
        float m = -1e30f;
        #pragma unroll
        for (int cls = 0; cls < 10; cls++) m = fmaxf(m, logits_s[t * 10 + cls]);
        float se = 0.f;
        #pragma unroll
        for (int cls = 0; cls < 10; cls++) se += expf(logits_s[t * 10 + cls] - m);
        float ls = logf(se) + m;
        #pragma unroll
        for (int cls = 0; cls < 10; cls++) out[(r0 + t) * 10 + cls] = logits_s[t * 10 + cls] - ls;
    }
}

extern "C" void kernel_launch(void* const* d_in, const int* in_sizes, int n_in,
                              void* d_out, int out_size, void* d_ws, size_t ws_size,
                              hipStream_t stream)
{
    const float* x      = (const float*)d_in[0];
    const float* e      = (const float*)d_in[1];
    const int*   src    = (const int*)d_in[2];
    const int*   dst    = (const int*)d_in[3];
    const int*   row_idx= (const int*)d_in[4];
    const int*   col_idx= (const int*)d_in[5];
    const float* real   = (const float*)d_in[6];
    const void*  mask   = d_in[7];
    const float* W1e    = (const float*)d_in[8];
    const float* b1e    = (const float*)d_in[9];
    const float* W1n    = (const float*)d_in[10];
    const float* b1n    = (const float*)d_in[11];
    const float* W2e    = (const float*)d_in[12];
    const float* b2e    = (const float*)d_in[13];
    const float* W2n    = (const float*)d_in[14];
    const float* b2n    = (const float*)d_in[15];
    const float* pe     = (const float*)d_in[16];
    const float* Wq     = (const float*)d_in[17];
    const float* Wk     = (const float*)d_in[18];
    const float* Wv     = (const float*)d_in[19];
    const float* Wref   = (const float*)d_in[20];
    const float* bref   = (const float*)d_in[21];
    const float* Wr     = (const float*)d_in[22];
    const float* Wc     = (const float*)d_in[23];
    const float* bep    = (const float*)d_in[24];
    const float* Wcls   = (const float*)d_in[25];
    const float* bcls   = (const float*)d_in[26];

    float* ws = (float*)d_ws;
    size_t off = 0;
    float* h1sum = ws + off; off += (size_t)NNODES * EHID;
    float* h2sum = ws + off; off += (size_t)NNODES * EOUTD;
    int*   cnt_i = (int*)(ws + off); off += NNODES;
    const size_t zero_floats = off;
    float* cntf  = ws + off; off += NNODES;
    int*   cursor= (int*)(ws + off); off += NNODES;
    int*   srcs  = (int*)(ws + off); off += NEDGES;
    int*   dsts  = (int*)(ws + off); off += NEDGES;
    int*   eidx  = (int*)(ws + off); off += NEDGES;
    float* x1    = ws + off; off += (size_t)NNODES * NHID;
    float* x2    = ws + off; off += (size_t)NNODES * NOUTD;
    unsigned short* xb    = (unsigned short*)(ws + off); off += (size_t)NNODES * NIN  / 2;
    unsigned short* x1b   = (unsigned short*)(ws + off); off += (size_t)NNODES * NHID / 2;
    unsigned short* W1tT  = (unsigned short*)(ws + off); off += 128 * 128 / 2;
    unsigned short* W1bT  = (unsigned short*)(ws + off); off += 128 * 64 / 2;
    unsigned short* W2tT  = (unsigned short*)(ws + off); off += 64 * 256 / 2;
    unsigned short* W2bT  = (unsigned short*)(ws + off); off += 64 * 128 / 2;
    unsigned short* W1nTb = (unsigned short*)(ws + off); off += 256 * 256 / 2;
    unsigned short* W2nTb = (unsigned short*)(ws + off); off += 256 * 320 / 2;
    unsigned short* P1b   = (unsigned short*)(ws + off); off += (size_t)NNODES * 128 / 2;
    unsigned short* P2b   = (unsigned short*)(ws + off); off += (size_t)NNODES * 64 / 2;
    float* qb    = ws + off; off += 128 * 256;
    float* kb    = ws + off; off += 128 * 256;
    float* vb    = ws + off; off += 128 * 256;
    float* distb = ws + off; off += 128 * 128;
    float* colWc = ws + off; off += 128 * 64;
    float* rowWrb= ws + off; off += (size_t)RROWS * EOUTD;
    int*   modep = (int*)(ws + off); off += 4;
    // Q bf16 (sorted layout, 480000x64x2B = 61MB). ws if it fits, else borrow the
    // pred region of d_out (Q fully consumed by k_edge2_lite before k_pred8 writes).
    unsigned short* Qb;
    size_t need = (off + (size_t)NEDGES * 32) * sizeof(float);
    if (ws_size >= need) Qb = (unsigned short*)(ws + off);
    else                 Qb = (unsigned short*)((float*)d_out + (size_t)RROWS * NCLS);

    hipMemsetAsync(d_ws, 0, zero_floats * sizeof(float), stream);
    k_mask_detect<<<1, 64, 0, stream>>>((const unsigned int*)mask, modep);
    k_hist<<<(NEDGES + 255) / 256, 256, 0, stream>>>(dst, cnt_i);
    k_prefix<<<1, 256, 0, stream>>>(cnt_i, cursor, cntf);
    k_scatter<<<(NEDGES + 255) / 256, 256, 0, stream>>>(src, dst, cursor, srcs, dsts, eidx);
    k_cvt_bf16<<<(NNODES * NIN / 8 + 255) / 256, 256, 0, stream>>>(x, xb, NNODES * NIN / 8);
    k_wT_part<0,   128, 128><<<(128 * 128 + 255) / 256, 256, 0, stream>>>(W1e, W1tT);
    k_wT_part<128, 64,  128><<<(128 * 64  + 255) / 256, 256, 0, stream>>>(W1e, W1bT);
    k_wT_part<0,   256, 64 ><<<(64 * 256 + 255) / 256, 256, 0, stream>>>(W2e, W2tT);
    k_wT_part<256, 128, 64 ><<<(64 * 128 + 255) / 256, 256, 0, stream>>>(W2e, W2bT);
    k_wT_part<0,   256, 256><<<(256 * 256 + 255) / 256, 256, 0, stream>>>(W1n, W1nTb);
    k_wT_part<0,   320, 256><<<(256 * 320 + 255) / 256, 256, 0, stream>>>(W2n, W2nTb);
    k_gemm_b16<128, 128><<<(NNODES + 63) / 64, 256, 0, stream>>>(xb, W1tT, P1b, NNODES);
    k_edge1_fused<<<NEDGES / 64, 256, 0, stream>>>(e, srcs, dsts, eidx, W1bT, b1e, P1b, W2bT, Qb, h1sum);
    k_node_mfma<NIN, EHID, true><<<(NNODES + 63) / 64, 256, 0, stream>>>(xb, h1sum, cntf, W1nTb, b1n, x1, x1b, NNODES);
    k_gemm_b16<256, 64><<<(NNODES + 63) / 64, 256, 0, stream>>>(x1b, W2tT, P2b, NNODES);
    k_edge2_lite<<<NEDGES / 256, 256, 0, stream>>>(P2b, Qb, srcs, dsts, b2e, h2sum);
    k_node_mfma<NHID, EOUTD, false><<<(NNODES + 63) / 64, 256, 0, stream>>>(x1b, h2sum, cntf, W2nTb, b2n, x2, (unsigned short*)nullptr, NNODES);
    k_attn_qkv<<<128, 256, 0, stream>>>(x1, col_idx, pe, Wq, Wk, Wv, qb, kb, vb);
    k_attn_dist<<<128, 128, 0, stream>>>(qb, kb, distb);
    k_attn_out<<<128, 256, 0, stream>>>(distb, vb, Wref, bref, Wc, bep, colWc);
    k_rowwr<<<RROWS / 16, 256, 0, stream>>>(x2, row_idx, Wr, rowWrb);
    k_pred8<<<RROWS / 8, 256, 0, stream>>>(rowWrb, colWc, mask, modep, real, Wcls, bcls, (float*)d_out);
}

// Round 7
// 619.554 us; speedup vs baseline: 3.8599x; 1.1858x over previous
//
#include <hip/hip_runtime.h>
#include <hip/hip_bf16.h>
#include <math.h>

#define NNODES 30000
#define NEDGES 480000
#define RROWS  8192
#define NCOLS  128
#define NIN    128
#define EIN    64
#define NHID   256
#define EHID   128
#define NOUTD  256
#define EOUTD  64
#define NCLS   10
#define NB_PFX 118   // ceil(30000/256)

typedef __attribute__((ext_vector_type(8))) unsigned short ushort8;
typedef __attribute__((ext_vector_type(8))) short bhalf8;
typedef __attribute__((ext_vector_type(4))) float floatx4;

__device__ __forceinline__ float lrelu(float v){ return v > 0.f ? v : 0.01f * v; }
__device__ __forceinline__ float4 ld4(const float* p){ return *(const float4*)p; }
__device__ __forceinline__ float4 ntld4(const float* p){
    floatx4 v = __builtin_nontemporal_load((const floatx4*)p);
    return make_float4(v.x, v.y, v.z, v.w);
}
__device__ __forceinline__ void ntst4(float* p, float4 v){
    floatx4 n = {v.x, v.y, v.z, v.w};
    __builtin_nontemporal_store(n, (floatx4*)p);
}
__device__ __forceinline__ unsigned short f2b(float f){
    unsigned int u = __builtin_bit_cast(unsigned int, f);
    u += 0x7fffu + ((u >> 16) & 1u);
    return (unsigned short)(u >> 16);
}
__device__ __forceinline__ float b2f(unsigned short b){
    unsigned int u = ((unsigned int)b) << 16;
    return __builtin_bit_cast(float, u);
}

// ---------------- fused prep: cvt_bf16(x) + 6 weight transposes + dst-hist + mask-detect ----------------
#define PREP_CVT_N   1875                       // 480000/256
#define PREP_W1T_B   (PREP_CVT_N)               // 64 blocks
#define PREP_W1B_B   (PREP_W1T_B + 64)          // 32
#define PREP_W2T_B   (PREP_W1B_B + 32)          // 64
#define PREP_W2B_B   (PREP_W2T_B + 64)          // 32
#define PREP_W1N_B   (PREP_W2B_B + 32)          // 256
#define PREP_W2N_B   (PREP_W1N_B + 256)         // 320
#define PREP_HIST_B  (PREP_W2N_B + 320)         // 1875
#define PREP_DET_B   (PREP_HIST_B + 1875)       // 1
#define PREP_TOTAL   (PREP_DET_B + 1)

__device__ __forceinline__ void wT_region(const float* __restrict__ W, unsigned short* __restrict__ Wt,
                                          int KOFF, int KSUB, int N, int idx){
    if (idx >= N * KSUB) return;
    int n = idx / KSUB, k = idx % KSUB;
    Wt[idx] = f2b(W[(size_t)(KOFF + k) * N + n]);
}

__global__ __launch_bounds__(256) void k_prep(
    const float* __restrict__ x, unsigned short* __restrict__ xb,
    const float* __restrict__ W1e, unsigned short* __restrict__ W1tT, unsigned short* __restrict__ W1bT,
    const float* __restrict__ W2e, unsigned short* __restrict__ W2tT, unsigned short* __restrict__ W2bT,
    const float* __restrict__ W1n, unsigned short* __restrict__ W1nTb,
    const float* __restrict__ W2n, unsigned short* __restrict__ W2nTb,
    const int* __restrict__ dst, int* __restrict__ cnt_i,
    const unsigned int* __restrict__ mask, int* __restrict__ mode)
{
    const int bid = blockIdx.x, t = threadIdx.x;
    if (bid < PREP_CVT_N){
        int i = bid * 256 + t;   // < 480000
        float4 a = ntld4(x + (size_t)i * 8), b = ntld4(x + (size_t)i * 8 + 4);
        ushort8 o = {f2b(a.x), f2b(a.y), f2b(a.z), f2b(a.w), f2b(b.x), f2b(b.y), f2b(b.z), f2b(b.w)};
        *(ushort8*)(xb + (size_t)i * 8) = o;
    } else if (bid < PREP_W1B_B){
        wT_region(W1e, W1tT, 0, 128, 128, (bid - PREP_W1T_B) * 256 + t);
    } else if (bid < PREP_W2T_B){
        wT_region(W1e, W1bT, 128, 64, 128, (bid - PREP_W1B_B) * 256 + t);
    } else if (bid < PREP_W2B_B){
        wT_region(W2e, W2tT, 0, 256, 64, (bid - PREP_W2T_B) * 256 + t);
    } else if (bid < PREP_W1N_B){
        wT_region(W2e, W2bT, 256, 128, 64, (bid - PREP_W2B_B) * 256 + t);
    } else if (bid < PREP_W2N_B){
        wT_region(W1n, W1nTb, 0, 256, 256, (bid - PREP_W1N_B) * 256 + t);
    } else if (bid < PREP_HIST_B){
        wT_region(W2n, W2nTb, 0, 320, 256, (bid - PREP_W2N_B) * 256 + t);
    } else if (bid < PREP_DET_B){
        int i = (bid - PREP_HIST_B) * 256 + t;
        if (i < NEDGES) atomicAdd(&cnt_i[dst[i]], 1);
    } else if (t == 0){
        bool allI32 = true, allF32 = true;
        for (int i = 0; i < 64; i++){
            unsigned int v = mask[i];
            if (!(v == 0u || v == 1u)) allI32 = false;
            if (!(v == 0u || v == 0x3F800000u)) allF32 = false;
        }
        *mode = allI32 ? 0 : (allF32 ? 1 : 2);
    }
}

// ---------------- 3-stage exclusive prefix over 30000 bins ----------------
__global__ __launch_bounds__(256) void k_pfx1(const int* __restrict__ cnt_i, int* __restrict__ blocksum){
    __shared__ int red[256];
    const int t = threadIdx.x;
    const int i = blockIdx.x * 256 + t;
    red[t] = (i < NNODES) ? cnt_i[i] : 0;
    __syncthreads();
    for (int o = 128; o; o >>= 1){ if (t < o) red[t] += red[t + o]; __syncthreads(); }
    if (t == 0) blocksum[blockIdx.x] = red[0];
}
__global__ __launch_bounds__(128) void k_pfx2(const int* __restrict__ blocksum, int* __restrict__ blockoff){
    __shared__ int s[128];
    const int t = threadIdx.x;
    int v = (t < NB_PFX) ? blocksum[t] : 0;
    s[t] = v;
    __syncthreads();
    for (int o = 1; o < 128; o <<= 1){
        int add = (t >= o) ? s[t - o] : 0;
        __syncthreads();
        s[t] += add;
        __syncthreads();
    }
    if (t < NB_PFX) blockoff[t] = s[t] - v;   // exclusive
}
__global__ __launch_bounds__(256) void k_pfx3(const int* __restrict__ cnt_i, const int* __restrict__ blockoff,
                                              int* __restrict__ cursor, float* __restrict__ cntf){
    __shared__ int s[256];
    const int t = threadIdx.x;
    const int i = blockIdx.x * 256 + t;
    int v = (i < NNODES) ? cnt_i[i] : 0;
    s[t] = v;
    __syncthreads();
    for (int o = 1; o < 256; o <<= 1){
        int add = (t >= o) ? s[t - o] : 0;
        __syncthreads();
        s[t] += add;
        __syncthreads();
    }
    if (i < NNODES){
        cursor[i] = s[t] - v + blockoff[blockIdx.x];
        cntf[i] = (float)v;
    }
}

// ---------------- scatter: sorted position -> original edge index ----------------
__global__ void k_scatter(const int* __restrict__ dst, int* __restrict__ cursor, int* __restrict__ eidx){
    int i = blockIdx.x * 256 + threadIdx.x;
    if (i >= NEDGES) return;
    int pos = atomicAdd(&cursor[dst[i]], 1);
    eidx[pos] = i;
}
// ---------------- gather sorted src/dst (coalesced writes) ----------------
__global__ void k_sgather(const int* __restrict__ src, const int* __restrict__ dst,
                          const int* __restrict__ eidx,
                          int* __restrict__ srcs, int* __restrict__ dsts){
    int p = blockIdx.x * 256 + threadIdx.x;
    if (p >= NEDGES) return;
    int i = eidx[p];
    srcs[p] = src[i];
    dsts[p] = dst[i];
}

// ---------------- small GEMM: out_bf16[M,N] = Ab[M,K] @ Wt[N,K] ----------------
template<int K, int N>
__global__ __launch_bounds__(256) void k_gemm_b16(
    const unsigned short* __restrict__ Ab, const unsigned short* __restrict__ Wt,
    unsigned short* __restrict__ outb, int M)
{
    __shared__ unsigned short At[64][K + 8];
    const int t = threadIdx.x;
    const int r0 = blockIdx.x * 64;
    {
        const int r = t >> 2, q = t & 3;
        const int row = r0 + r;
        const bool valid = row < M;
        const unsigned short* a = Ab + (size_t)(valid ? row : 0) * K;
        for (int kk = q * (K / 4); kk < (q + 1) * (K / 4); kk += 8){
            ushort8 u;
            if (valid) u = *(const ushort8*)(a + kk);
            else       u = (ushort8){0,0,0,0,0,0,0,0};
            *(ushort8*)&At[r][kk] = u;
        }
    }
    __syncthreads();
    const int lane = t & 63, w = t >> 6;
    const int fr = lane & 15, fq = lane >> 4;
    constexpr int NF = N / 16;
    floatx4 acc[NF] = {};
    #pragma unroll
    for (int ks = 0; ks < K / 32; ks++){
        const int k = ks * 32 + fq * 8;
        bhalf8 a = *(bhalf8*)&At[w * 16 + fr][k];
        #pragma unroll
        for (int n = 0; n < NF; n++){
            bhalf8 b = *(const bhalf8*)(Wt + (size_t)(n * 16 + fr) * K + k);
            acc[n] = __builtin_amdgcn_mfma_f32_16x16x32_bf16(a, b, acc[n], 0, 0, 0);
        }
    }
    #pragma unroll
    for (int n = 0; n < NF; n++){
        const int col = n * 16 + fr;
        #pragma unroll
        for (int rr = 0; rr < 4; rr++){
            const int row = r0 + w * 16 + fq * 4 + rr;
            if (row < M) outb[(size_t)row * N + col] = f2b(acc[n][rr]);
        }
    }
}

// ---------------- fused edge layer 1 (bf16 LDS tile, 17.4 KB) ----------------
// e1 = leaky(P1[src] + e@W1bT + b1e) -> LDS bf16; Q = e1@W2bT (nt store);
// h1sum += run-reduced col sums of e1.
__global__ __launch_bounds__(256) void k_edge1_fused(
    const float* __restrict__ e,
    const int* __restrict__ srcs, const int* __restrict__ dsts, const int* __restrict__ eidx,
    const unsigned short* __restrict__ W1bT, const float* __restrict__ b1e,
    const unsigned short* __restrict__ P1b, const unsigned short* __restrict__ W2bT,
    unsigned short* __restrict__ Qb, float* __restrict__ hsum)
{
    __shared__ unsigned short Cb[64][136];   // phase A: e stage (cols 0..63); phase C+: e1 bf16 (cols 0..127)
    __shared__ int dstS[64];
    __shared__ int srcS[64];
    const int t = threadIdx.x;
    const int p0 = blockIdx.x * 64;
    // phase A: stage e rows (f32 -> bf16, nt), load src/dst
    {
        const int r = t >> 2, q = t & 3;
        const int p = p0 + r;
        if (q == 0){ dstS[r] = dsts[p]; srcS[r] = srcs[p]; }
        const int ei = eidx[p];
        const float* ep = e + (size_t)ei * 64 + q * 16;
        float4 f0 = ntld4(ep), f1 = ntld4(ep + 4), f2 = ntld4(ep + 8), f3 = ntld4(ep + 12);
        ushort8 u0 = {f2b(f0.x), f2b(f0.y), f2b(f0.z), f2b(f0.w), f2b(f1.x), f2b(f1.y), f2b(f1.z), f2b(f1.w)};
        ushort8 u1 = {f2b(f2.x), f2b(f2.y), f2b(f2.z), f2b(f2.w), f2b(f3.x), f2b(f3.y), f2b(f3.z), f2b(f3.w)};
        *(ushort8*)&Cb[r][q * 16]     = u0;
        *(ushort8*)&Cb[r][q * 16 + 8] = u1;
    }
    __syncthreads();
    const int lane = t & 63, w = t >> 6;
    const int wm = w >> 1, wn = w & 1;
    const int fr = lane & 15, fq = lane >> 4;
    // phase B: acc1 = e_tile(64xK64) @ W1bT  (64x128)
    floatx4 acc1[2][4] = {};
    #pragma unroll
    for (int ks = 0; ks < 2; ks++){
        const int k = ks * 32 + fq * 8;
        bhalf8 a0 = *(bhalf8*)&Cb[wm * 32 + fr][k];
        bhalf8 a1 = *(bhalf8*)&Cb[wm * 32 + 16 + fr][k];
        #pragma unroll
        for (int n = 0; n < 4; n++){
            const int col = wn * 64 + n * 16 + fr;
            bhalf8 b = *(const bhalf8*)(W1bT + (size_t)col * 64 + k);
            acc1[0][n] = __builtin_amdgcn_mfma_f32_16x16x32_bf16(a0, b, acc1[0][n], 0, 0, 0);
            acc1[1][n] = __builtin_amdgcn_mfma_f32_16x16x32_bf16(a1, b, acc1[1][n], 0, 0, 0);
        }
    }
    __syncthreads();   // e-stage reads done; overwrite Cb with e1 (bf16)
    // phase C: e1 = leaky(acc + P1[src] + b1e) -> Cb bf16
    #pragma unroll
    for (int m = 0; m < 2; m++){
        #pragma unroll
        for (int n = 0; n < 4; n++){
            const int col = wn * 64 + n * 16 + fr;
            const float bv = b1e[col];
            #pragma unroll
            for (int r = 0; r < 4; r++){
                const int row = wm * 32 + m * 16 + fq * 4 + r;
                const float pv = b2f(P1b[(size_t)srcS[row] * 128 + col]);
                Cb[row][col] = f2b(lrelu(acc1[m][n][r] + pv + bv));
            }
        }
    }
    __syncthreads();
    // phase D: Q = e1 @ W2bT  (64x64, K=128), nt store bf16
    {
        floatx4 acc2[4] = {};
        #pragma unroll
        for (int ks = 0; ks < 4; ks++){
            const int k = ks * 32 + fq * 8;
            bhalf8 a = *(bhalf8*)&Cb[w * 16 + fr][k];
            #pragma unroll
            for (int n = 0; n < 4; n++){
                bhalf8 b = *(const bhalf8*)(W2bT + (size_t)(n * 16 + fr) * 128 + k);
                acc2[n] = __builtin_amdgcn_mfma_f32_16x16x32_bf16(a, b, acc2[n], 0, 0, 0);
            }
        }
        #pragma unroll
        for (int n = 0; n < 4; n++){
            const int col = n * 16 + fr;
            #pragma unroll
            for (int r = 0; r < 4; r++){
                const int row = w * 16 + fq * 4 + r;
                __builtin_nontemporal_store(f2b(acc2[n][r]), &Qb[(size_t)(p0 + row) * 64 + col]);
            }
        }
    }
    // phase E: run-reduced scatter-add of e1 to h1sum
    {
        const int col = t & 127, half = t >> 7;
        const int rbase = half * 32;
        float s = 0.f;
        int prev = dstS[rbase];
        #pragma unroll 4
        for (int rr = 0; rr < 32; rr++){
            const int r = rbase + rr;
            const int d = dstS[r];
            if (d != prev){
                atomicAdd(&hsum[(size_t)prev * EHID + col], s);
                s = 0.f; prev = d;
            }
            s += b2f(Cb[r][col]);
        }
        atomicAdd(&hsum[(size_t)prev * EHID + col], s);
    }
}

// ---------------- edge layer 2 (lite): e2 = leaky(P2[src] + Q + b2e), run-reduced scatter ----------------
__global__ __launch_bounds__(256) void k_edge2_lite(
    const unsigned short* __restrict__ P2b, const unsigned short* __restrict__ Qb,
    const int* __restrict__ srcs, const int* __restrict__ dsts,
    const float* __restrict__ b2e, float* __restrict__ hsum)
{
    const int t = threadIdx.x;
    const int lane = t & 63, w = t >> 6;
    const int p0 = blockIdx.x * 256 + w * 64;
    const float bias = b2e[lane];
    float s = 0.f;
    int prev = dsts[p0];
    #pragma unroll 4
    for (int i = 0; i < 64; i++){
        const int p = p0 + i;
        const int d = dsts[p];
        if (d != prev){
            atomicAdd(&hsum[(size_t)prev * EOUTD + lane], s);
            s = 0.f; prev = d;
        }
        const float q  = b2f(__builtin_nontemporal_load(&Qb[(size_t)p * 64 + lane]));
        const float pv = b2f(P2b[(size_t)srcs[p] * 64 + lane]);
        s += lrelu(pv + q + bias);
    }
    atomicAdd(&hsum[(size_t)prev * EOUTD + lane], s);
}

// ---------------- node update (MFMA, 32-row tiles): out = leaky([A1, hsum/cnt] @ W + b) ----------------
template<int K1, int K2, bool WRITE_BF16>
__global__ __launch_bounds__(256) void k_node_mfma(
    const unsigned short* __restrict__ A1b, const float* __restrict__ hsum,
    const float* __restrict__ cntf,
    const unsigned short* __restrict__ Wt, const float* __restrict__ bias,
    float* __restrict__ outf, unsigned short* __restrict__ outb, int M)
{
    constexpr int K = K1 + K2;
    __shared__ unsigned short At[32][K + 8];
    const int t = threadIdx.x;
    const int r0 = blockIdx.x * 32;
    {
        const int r = t >> 3, q = t & 7;
        const int row = r0 + r;
        const bool valid = row < M;
        float rinv = 0.f;
        const unsigned short* a1 = A1b;
        const float* a2 = hsum;
        if (valid){
            rinv = 1.f / fmaxf(cntf[row], 1.f);
            a1 = A1b  + (size_t)row * K1;
            a2 = hsum + (size_t)row * K2;
        }
        for (int kk = q * (K / 8); kk < (q + 1) * (K / 8); kk += 8){
            ushort8 u;
            if (!valid){
                u = (ushort8){0,0,0,0,0,0,0,0};
            } else if (kk < K1){
                u = *(const ushort8*)(a1 + kk);
            } else {
                float4 f0 = ld4(a2 + (kk - K1)), f1 = ld4(a2 + (kk - K1) + 4);
                u = (ushort8){f2b(f0.x*rinv), f2b(f0.y*rinv), f2b(f0.z*rinv), f2b(f0.w*rinv),
                              f2b(f1.x*rinv), f2b(f1.y*rinv), f2b(f1.z*rinv), f2b(f1.w*rinv)};
            }
            *(ushort8*)&At[r][kk] = u;
        }
    }
    __syncthreads();
    const int lane = t & 63, w = t >> 6;
    const int wm = w >> 1, wn = w & 1;
    const int fr = lane & 15, fq = lane >> 4;
    floatx4 acc[8] = {};
    #pragma unroll
    for (int ks = 0; ks < K / 32; ks++){
        const int k = ks * 32 + fq * 8;
        bhalf8 a = *(bhalf8*)&At[wm * 16 + fr][k];
        #pragma unroll
        for (int n = 0; n < 8; n++){
            const int col = wn * 128 + n * 16 + fr;
            bhalf8 b = *(const bhalf8*)(Wt + (size_t)col * K + k);
            acc[n] = __builtin_amdgcn_mfma_f32_16x16x32_bf16(a, b, acc[n], 0, 0, 0);
        }
    }
    #pragma unroll
    for (int n = 0; n < 8; n++){
        const int col = wn * 128 + n * 16 + fr;
        const float bv = bias[col];
        #pragma unroll
        for (int rr = 0; rr < 4; rr++){
            const int row = r0 + wm * 16 + fq * 4 + rr;
            if (row < M){
                float o = lrelu(acc[n][rr] + bv);
                outf[(size_t)row * 256 + col] = o;
                if (WRITE_BF16) outb[(size_t)row * 256 + col] = f2b(o);
            }
        }
    }
}

// ---------------- attention: q,k,v ----------------
__global__ __launch_bounds__(256) void k_attn_qkv(
    const float* __restrict__ x1, const int* __restrict__ col_idx,
    const float* __restrict__ pe,
    const float* __restrict__ Wq, const float* __restrict__ Wk, const float* __restrict__ Wv,
    float* __restrict__ qo, float* __restrict__ ko, float* __restrict__ vo)
{
    __shared__ float c[256];
    const int i = blockIdx.x, t = threadIdx.x;
    const int col = col_idx[i];
    c[t] = x1[(size_t)col * 256 + t] + pe[i * 256 + t];
    __syncthreads();
    float aq = 0.f, ak = 0.f, av = 0.f;
    #pragma unroll 4
    for (int kk = 0; kk < 256; kk++){
        float cv = c[kk];
        aq += cv * Wq[kk * 256 + t];
        ak += cv * Wk[kk * 256 + t];
        av += cv * Wv[kk * 256 + t];
    }
    qo[i * 256 + t] = aq; ko[i * 256 + t] = ak; vo[i * 256 + t] = av;
}

// ---------------- attention: dist = softmax(q @ k^T / 16) ----------------
__global__ __launch_bounds__(128) void k_attn_dist(
    const float* __restrict__ q, const float* __restrict__ k, float* __restrict__ dist)
{
    __shared__ float qr[256];
    __shared__ float red[128];
    const int i = blockIdx.x, t = threadIdx.x;
    qr[t] = q[i * 256 + t]; qr[t + 128] = q[i * 256 + t + 128];
    __syncthreads();
    float s = 0.f;
    #pragma unroll 4
    for (int kk = 0; kk < 256; kk++) s += qr[kk] * k[t * 256 + kk];
    s *= 0.0625f;
    red[t] = s; __syncthreads();
    for (int off = 64; off; off >>= 1){ if (t < off) red[t] = fmaxf(red[t], red[t + off]); __syncthreads(); }
    float m = red[0]; __syncthreads();
    float ex = expf(s - m);
    red[t] = ex; __syncthreads();
    for (int off = 64; off; off >>= 1){ if (t < off) red[t] += red[t + off]; __syncthreads(); }
    dist[i * 128 + t] = ex / red[0];
}

// ---------------- attention tail ----------------
__global__ __launch_bounds__(256) void k_attn_out(
    const float* __restrict__ dist, const float* __restrict__ v,
    const float* __restrict__ Wref, const float* __restrict__ bref,
    const float* __restrict__ Wc, const float* __restrict__ bep,
    float* __restrict__ colWc)
{
    __shared__ float dr[128];
    __shared__ float c2[256];
    __shared__ float nc[256];
    const int i = blockIdx.x, t = threadIdx.x;
    if (t < 128) dr[t] = dist[i * 128 + t];
    __syncthreads();
    float s = 0.f;
    #pragma unroll 4
    for (int j = 0; j < 128; j++) s += dr[j] * v[j * 256 + t];
    c2[t] = 2.f * s;
    __syncthreads();
    float a = 0.f;
    #pragma unroll 4
    for (int kk = 0; kk < 256; kk++) a += c2[kk] * Wref[kk * 256 + t];
    a += bref[t];
    nc[t] = 1.f / (1.f + expf(-a));
    __syncthreads();
    if (t < 64){
        float o = 0.f;
        #pragma unroll 4
        for (int kk = 0; kk < 256; kk++) o += nc[kk] * Wc[kk * 64 + t];
        colWc[i * 64 + t] = o + bep[t];
    }
}

// ---------------- rowWr = x2[row_idx] @ Wr ----------------
__global__ __launch_bounds__(256) void k_rowwr(
    const float* __restrict__ x2, const int* __restrict__ row_idx,
    const float* __restrict__ Wr, float* __restrict__ rw)
{
    __shared__ float A[16][260];
    const int t = threadIdx.x;
    const int r0 = blockIdx.x * 16;
    const int rl = t >> 4, cg = t & 15;
    const int ridx = row_idx[r0 + rl];
    const float* ar = x2 + (size_t)ridx * 256;
    for (int i = cg; i < 64; i += 16) *(float4*)(&A[rl][i * 4]) = ld4(ar + i * 4);
    __syncthreads();
    float acc[4] = {0.f, 0.f, 0.f, 0.f};
    #pragma unroll 4
    for (int kk = 0; kk < 256; kk++){
        float4 w = ld4(Wr + (size_t)kk * 64 + cg * 4);
        float a = A[rl][kk];
        acc[0] += a * w.x; acc[1] += a * w.y; acc[2] += a * w.z; acc[3] += a * w.w;
    }
    *(float4*)(rw + (size_t)(r0 + rl) * 64 + cg * 4) = make_float4(acc[0], acc[1], acc[2], acc[3]);
}

// ---------------- fused: pred -> d_out (nt), imputation, classifier, log_softmax ----------------
__global__ __launch_bounds__(256) void k_pred8(
    const float* __restrict__ rowWr, const float* __restrict__ colWc,
    const void* __restrict__ maskp, const int* __restrict__ modep,
    const float* __restrict__ real, const float* __restrict__ Wcls, const float* __restrict__ bcls,
    float* __restrict__ out)
{
    __shared__ float colWc_s[8192];
    __shared__ float rowWr_s[8 * 64];
    __shared__ unsigned char mask_s[8 * 128];
    __shared__ float part[4][80];
    __shared__ float logits_s[80];
    const int t  = threadIdx.x;
    const int r0 = blockIdx.x * 8;
    const int mode = *modep;
    for (int idx = t; idx < 2048; idx += 256)
        *(float4*)&colWc_s[idx * 4] = ld4(colWc + idx * 4);
    for (int idx = t; idx < 128; idx += 256)
        *(float4*)&rowWr_s[idx * 4] = ld4(rowWr + (size_t)r0 * 64 + idx * 4);
    for (int idx = t; idx < 1024; idx += 256){
        const int g = idx >> 7, c = idx & 127;
        const int gi = (r0 + g) * 128 + c;
        bool m;
        if (mode == 2)      m = ((const unsigned char*)maskp)[gi] != 0;
        else if (mode == 0) m = ((const int*)maskp)[gi] != 0;
        else                m = ((const float*)maskp)[gi] != 0.f;
        mask_s[idx] = m ? 1 : 0;
    }
    __syncthreads();

    float acc[8][10];
    #pragma unroll
    for (int g = 0; g < 8; g++)
        #pragma unroll
        for (int c = 0; c < 10; c++) acc[g][c] = 0.f;
    float* pred = out + RROWS * NCLS;

    #pragma unroll 1
    for (int i = 0; i < 8; i++){
        const int e4   = i * 256 + t;
        const int base = e4 * 4;
        const int c = base >> 6;
        const int j = base & 63;
        float4 cw = ld4(&colWc_s[c * 64 + j]);
        float w40[40];
        #pragma unroll
        for (int u = 0; u < 10; u++){
            float4 wv = ld4(Wcls + (size_t)base * 10 + u * 4);
            w40[u*4+0] = wv.x; w40[u*4+1] = wv.y; w40[u*4+2] = wv.z; w40[u*4+3] = wv.w;
        }
        #pragma unroll
        for (int g = 0; g < 8; g++){
            const int rr = r0 + g;
            float4 rwv = ld4(&rowWr_s[g * 64 + j]);
            float4 p;
            p.x = lrelu(rwv.x + cw.x); p.y = lrelu(rwv.y + cw.y);
            p.z = lrelu(rwv.z + cw.z); p.w = lrelu(rwv.w + cw.w);
            ntst4(pred + (size_t)rr * 8192 + base, p);
            float4 im = p;
            if (mask_s[g * 128 + c]) im = ntld4(real + (size_t)rr * 8192 + base);
            #pragma unroll
            for (int cls = 0; cls < 10; cls++){
                acc[g][cls] += im.x * w40[cls]      + im.y * w40[10 + cls]
                             + im.z * w40[20 + cls] + im.w * w40[30 + cls];
            }
        }
    }
    #pragma unroll
    for (int g = 0; g < 8; g++)
        #pragma unroll
        for (int cls = 0; cls < 10; cls++){
            float v = acc[g][cls];
            for (int off = 32; off; off >>= 1) v += __shfl_down(v, off, 64);
            acc[g][cls] = v;
        }
    const int wid = t >> 6, lane = t & 63;
    if (lane == 0){
        #pragma unroll
        for (int g = 0; g < 8; g++)
            #pragma unroll
            for (int cls = 0; cls < 10; cls++) part[wid][g * 10 + cls] = acc[g][cls];
    }
    __syncthreads();
    if (t < 80) logits_s[t] = part[0][t] + part[1][t] + part[2][t] + part[3][t] + bcls[t % 10];
    __syncthreads();
    if (t < 8){
        float m = -1e30f;
        #pragma unroll
        for (int cls = 0; cls < 10; cls++) m = fmaxf(m, logits_s[t * 10 + cls]);
        float se = 0.f;
        #pragma unroll
        for (int cls = 0; cls < 10; cls++) se += expf(logits_s[t * 10 + cls] - m);
        float ls = logf(se) + m;
        #pragma unroll
        for (int cls = 0; cls < 10; cls++) out[(r0 + t) * 10 + cls] = logits_s[t * 10 + cls] - ls;
    }
}

extern "C" void kernel_launch(void* const* d_in, const int* in_sizes, int n_in,
                              void* d_out, int out_size, void* d_ws, size_t ws_size,
                              hipStream_t stream)
{
    const float* x      = (const float*)d_in[0];
    const float* e      = (const float*)d_in[1];
    const int*   src    = (const int*)d_in[2];
    const int*   dst    = (const int*)d_in[3];
    const int*   row_idx= (const int*)d_in[4];
    const int*   col_idx= (const int*)d_in[5];
    const float* real   = (const float*)d_in[6];
    const void*  mask   = d_in[7];
    const float* W1e    = (const float*)d_in[8];
    const float* b1e    = (const float*)d_in[9];
    const float* W1n    = (const float*)d_in[10];
    const float* b1n    = (const float*)d_in[11];
    const float* W2e    = (const float*)d_in[12];
    const float* b2e    = (const float*)d_in[13];
    const float* W2n    = (const float*)d_in[14];
    const float* b2n    = (const float*)d_in[15];
    const float* pe     = (const float*)d_in[16];
    const float* Wq     = (const float*)d_in[17];
    const float* Wk     = (const float*)d_in[18];
    const float* Wv     = (const float*)d_in[19];
    const float* Wref   = (const float*)d_in[20];
    const float* bref   = (const float*)d_in[21];
    const float* Wr     = (const float*)d_in[22];
    const float* Wc     = (const float*)d_in[23];
    const float* bep    = (const float*)d_in[24];
    const float* Wcls   = (const float*)d_in[25];
    const float* bcls   = (const float*)d_in[26];

    float* ws = (float*)d_ws;
    size_t off = 0;
    float* h1sum = ws + off; off += (size_t)NNODES * EHID;
    float* h2sum = ws + off; off += (size_t)NNODES * EOUTD;
    int*   cnt_i = (int*)(ws + off); off += NNODES;
    const size_t zero_floats = off;
    float* cntf  = ws + off; off += NNODES;
    int*   cursor= (int*)(ws + off); off += NNODES;
    int*   srcs  = (int*)(ws + off); off += NEDGES;
    int*   dsts  = (int*)(ws + off); off += NEDGES;
    int*   eidx  = (int*)(ws + off); off += NEDGES;
    float* x1    = ws + off; off += (size_t)NNODES * NHID;
    float* x2    = ws + off; off += (size_t)NNODES * NOUTD;
    unsigned short* xb    = (unsigned short*)(ws + off); off += (size_t)NNODES * NIN  / 2;
    unsigned short* x1b   = (unsigned short*)(ws + off); off += (size_t)NNODES * NHID / 2;
    unsigned short* W1tT  = (unsigned short*)(ws + off); off += 128 * 128 / 2;
    unsigned short* W1bT  = (unsigned short*)(ws + off); off += 128 * 64 / 2;
    unsigned short* W2tT  = (unsigned short*)(ws + off); off += 64 * 256 / 2;
    unsigned short* W2bT  = (unsigned short*)(ws + off); off += 64 * 128 / 2;
    unsigned short* W1nTb = (unsigned short*)(ws + off); off += 256 * 256 / 2;
    unsigned short* W2nTb = (unsigned short*)(ws + off); off += 256 * 320 / 2;
    unsigned short* P1b   = (unsigned short*)(ws + off); off += (size_t)NNODES * 128 / 2;
    unsigned short* P2b   = (unsigned short*)(ws + off); off += (size_t)NNODES * 64 / 2;
    float* qb    = ws + off; off += 128 * 256;
    float* kb    = ws + off; off += 128 * 256;
    float* vb    = ws + off; off += 128 * 256;
    float* distb = ws + off; off += 128 * 128;
    float* colWc = ws + off; off += 128 * 64;
    float* rowWrb= ws + off; off += (size_t)RROWS * EOUTD;
    int*   modep = (int*)(ws + off); off += 4;
    int*   blocksum = (int*)(ws + off); off += 128;
    int*   blockoff = (int*)(ws + off); off += 128;
    // Q bf16 (sorted, 480000x64x2B = 61MB). ws if it fits, else borrow pred
    // region of d_out (Q fully consumed by k_edge2_lite before k_pred8 writes).
    unsigned short* Qb;
    size_t need = (off + (size_t)NEDGES * 32) * sizeof(float);
    if (ws_size >= need) Qb = (unsigned short*)(ws + off);
    else                 Qb = (unsigned short*)((float*)d_out + (size_t)RROWS * NCLS);

    (void)hipMemsetAsync(d_ws, 0, zero_floats * sizeof(float), stream);
    k_prep<<<PREP_TOTAL, 256, 0, stream>>>(x, xb, W1e, W1tT, W1bT, W2e, W2tT, W2bT,
                                           W1n, W1nTb, W2n, W2nTb, dst, cnt_i,
                                           (const unsigned int*)mask, modep);
    k_pfx1<<<NB_PFX, 256, 0, stream>>>(cnt_i, blocksum);
    k_pfx2<<<1, 128, 0, stream>>>(blocksum, blockoff);
    k_pfx3<<<NB_PFX, 256, 0, stream>>>(cnt_i, blockoff, cursor, cntf);
    k_scatter<<<(NEDGES + 255) / 256, 256, 0, stream>>>(dst, cursor, eidx);
    k_sgather<<<(NEDGES + 255) / 256, 256, 0, stream>>>(src, dst, eidx, srcs, dsts);
    k_gemm_b16<128, 128><<<(NNODES + 63) / 64, 256, 0, stream>>>(xb, W1tT, P1b, NNODES);
    k_edge1_fused<<<NEDGES / 64, 256, 0, stream>>>(e, srcs, dsts, eidx, W1bT, b1e, P1b, W2bT, Qb, h1sum);
    k_node_mfma<NIN, EHID, true><<<(NNODES + 31) / 32, 256, 0, stream>>>(xb, h1sum, cntf, W1nTb, b1n, x1, x1b, NNODES);
    k_gemm_b16<256, 64><<<(NNODES + 63) / 64, 256, 0, stream>>>(x1b, W2tT, P2b, NNODES);
    k_edge2_lite<<<NEDGES / 256, 256, 0, stream>>>(P2b, Qb, srcs, dsts, b2e, h2sum);
    k_node_mfma<NHID, EOUTD, false><<<(NNODES + 31) / 32, 256, 0, stream>>>(x1b, h2sum, cntf, W2nTb, b2n, x2, (unsigned short*)nullptr, NNODES);
    k_attn_qkv<<<128, 256, 0, stream>>>(x1, col_idx, pe, Wq, Wk, Wv, qb, kb, vb);
    k_attn_dist<<<128, 128, 0, stream>>>(qb, kb, distb);
    k_attn_out<<<128, 256, 0, stream>>>(distb, vb, Wref, bref, Wc, bep, colWc);
    k_rowwr<<<RROWS / 16, 256, 0, stream>>>(x2, row_idx, Wr, rowWrb);
    k_pred8<<<RROWS / 8, 256, 0, stream>>>(rowWrb, colWc, mask, modep, real, Wcls, bcls, (float*)d_out);
}

// Round 8
// 611.295 us; speedup vs baseline: 3.9121x; 1.0135x over previous
//
#include <hip/hip_runtime.h>
#include <hip/hip_bf16.h>
#include <math.h>

#define NNODES 30000
#define NEDGES 480000
#define RROWS  8192
#define NCOLS  128
#define NIN    128
#define EIN    64
#define NHID   256
#define EHID   128
#define NOUTD  256
#define EOUTD  64
#define NCLS   10
#define NB_PFX 118   // ceil(30000/256)

typedef __attribute__((ext_vector_type(8))) unsigned short ushort8;
typedef __attribute__((ext_vector_type(8))) short bhalf8;
typedef __attribute__((ext_vector_type(4))) float floatx4;

__device__ __forceinline__ float lrelu(float v){ return v > 0.f ? v : 0.01f * v; }
__device__ __forceinline__ float4 ld4(const float* p){ return *(const float4*)p; }
__device__ __forceinline__ float4 ntld4(const float* p){
    floatx4 v = __builtin_nontemporal_load((const floatx4*)p);
    return make_float4(v.x, v.y, v.z, v.w);
}
__device__ __forceinline__ void ntst4(float* p, float4 v){
    floatx4 n = {v.x, v.y, v.z, v.w};
    __builtin_nontemporal_store(n, (floatx4*)p);
}
__device__ __forceinline__ void ntst8u(unsigned short* p, ushort8 v){
    __builtin_nontemporal_store(v, (ushort8*)p);
}
__device__ __forceinline__ unsigned short f2b(float f){
    unsigned int u = __builtin_bit_cast(unsigned int, f);
    u += 0x7fffu + ((u >> 16) & 1u);
    return (unsigned short)(u >> 16);
}
__device__ __forceinline__ float b2f(unsigned short b){
    unsigned int u = ((unsigned int)b) << 16;
    return __builtin_bit_cast(float, u);
}

// ---------------- fused prep: cvt_bf16(x) + 6 weight transposes + dst-hist + mask-detect ----------------
#define PREP_CVT_N   1875                       // 480000/256
#define PREP_W1T_B   (PREP_CVT_N)               // 64 blocks
#define PREP_W1B_B   (PREP_W1T_B + 64)          // 32
#define PREP_W2T_B   (PREP_W1B_B + 32)          // 64
#define PREP_W2B_B   (PREP_W2T_B + 64)          // 32
#define PREP_W1N_B   (PREP_W2B_B + 32)          // 256
#define PREP_W2N_B   (PREP_W1N_B + 256)         // 320
#define PREP_HIST_B  (PREP_W2N_B + 320)         // 1875
#define PREP_DET_B   (PREP_HIST_B + 1875)       // 1
#define PREP_TOTAL   (PREP_DET_B + 1)

__device__ __forceinline__ void wT_region(const float* __restrict__ W, unsigned short* __restrict__ Wt,
                                          int KOFF, int KSUB, int N, int idx){
    if (idx >= N * KSUB) return;
    int n = idx / KSUB, k = idx % KSUB;
    Wt[idx] = f2b(W[(size_t)(KOFF + k) * N + n]);
}

__global__ __launch_bounds__(256) void k_prep(
    const float* __restrict__ x, unsigned short* __restrict__ xb,
    const float* __restrict__ W1e, unsigned short* __restrict__ W1tT, unsigned short* __restrict__ W1bT,
    const float* __restrict__ W2e, unsigned short* __restrict__ W2tT, unsigned short* __restrict__ W2bT,
    const float* __restrict__ W1n, unsigned short* __restrict__ W1nTb,
    const float* __restrict__ W2n, unsigned short* __restrict__ W2nTb,
    const int* __restrict__ dst, int* __restrict__ cnt_i,
    const unsigned int* __restrict__ mask, int* __restrict__ mode)
{
    const int bid = blockIdx.x, t = threadIdx.x;
    if (bid < PREP_CVT_N){
        int i = bid * 256 + t;   // < 480000
        float4 a = ntld4(x + (size_t)i * 8), b = ntld4(x + (size_t)i * 8 + 4);
        ushort8 o = {f2b(a.x), f2b(a.y), f2b(a.z), f2b(a.w), f2b(b.x), f2b(b.y), f2b(b.z), f2b(b.w)};
        *(ushort8*)(xb + (size_t)i * 8) = o;
    } else if (bid < PREP_W1B_B){
        wT_region(W1e, W1tT, 0, 128, 128, (bid - PREP_W1T_B) * 256 + t);
    } else if (bid < PREP_W2T_B){
        wT_region(W1e, W1bT, 128, 64, 128, (bid - PREP_W1B_B) * 256 + t);
    } else if (bid < PREP_W2B_B){
        wT_region(W2e, W2tT, 0, 256, 64, (bid - PREP_W2T_B) * 256 + t);
    } else if (bid < PREP_W1N_B){
        wT_region(W2e, W2bT, 256, 128, 64, (bid - PREP_W2B_B) * 256 + t);
    } else if (bid < PREP_W2N_B){
        wT_region(W1n, W1nTb, 0, 256, 256, (bid - PREP_W1N_B) * 256 + t);
    } else if (bid < PREP_HIST_B){
        wT_region(W2n, W2nTb, 0, 320, 256, (bid - PREP_W2N_B) * 256 + t);
    } else if (bid < PREP_DET_B){
        int i = (bid - PREP_HIST_B) * 256 + t;
        if (i < NEDGES) atomicAdd(&cnt_i[dst[i]], 1);
    } else if (t == 0){
        bool allI32 = true, allF32 = true;
        for (int i = 0; i < 64; i++){
            unsigned int v = mask[i];
            if (!(v == 0u || v == 1u)) allI32 = false;
            if (!(v == 0u || v == 0x3F800000u)) allF32 = false;
        }
        *mode = allI32 ? 0 : (allF32 ? 1 : 2);
    }
}

// ---------------- 3-stage exclusive prefix over 30000 bins ----------------
__global__ __launch_bounds__(256) void k_pfx1(const int* __restrict__ cnt_i, int* __restrict__ blocksum){
    __shared__ int red[256];
    const int t = threadIdx.x;
    const int i = blockIdx.x * 256 + t;
    red[t] = (i < NNODES) ? cnt_i[i] : 0;
    __syncthreads();
    for (int o = 128; o; o >>= 1){ if (t < o) red[t] += red[t + o]; __syncthreads(); }
    if (t == 0) blocksum[blockIdx.x] = red[0];
}
__global__ __launch_bounds__(128) void k_pfx2(const int* __restrict__ blocksum, int* __restrict__ blockoff){
    __shared__ int s[128];
    const int t = threadIdx.x;
    int v = (t < NB_PFX) ? blocksum[t] : 0;
    s[t] = v;
    __syncthreads();
    for (int o = 1; o < 128; o <<= 1){
        int add = (t >= o) ? s[t - o] : 0;
        __syncthreads();
        s[t] += add;
        __syncthreads();
    }
    if (t < NB_PFX) blockoff[t] = s[t] - v;   // exclusive
}
__global__ __launch_bounds__(256) void k_pfx3(const int* __restrict__ cnt_i, const int* __restrict__ blockoff,
                                              int* __restrict__ cursor, float* __restrict__ cntf){
    __shared__ int s[256];
    const int t = threadIdx.x;
    const int i = blockIdx.x * 256 + t;
    int v = (i < NNODES) ? cnt_i[i] : 0;
    s[t] = v;
    __syncthreads();
    for (int o = 1; o < 256; o <<= 1){
        int add = (t >= o) ? s[t - o] : 0;
        __syncthreads();
        s[t] += add;
        __syncthreads();
    }
    if (i < NNODES){
        cursor[i] = s[t] - v + blockoff[blockIdx.x];
        cntf[i] = (float)v;
    }
}

// ---------------- scatter: sorted position -> original edge index ----------------
__global__ void k_scatter(const int* __restrict__ dst, int* __restrict__ cursor, int* __restrict__ eidx){
    int i = blockIdx.x * 256 + threadIdx.x;
    if (i >= NEDGES) return;
    int pos = atomicAdd(&cursor[dst[i]], 1);
    eidx[pos] = i;
}
// ---------------- gather sorted src/dst (coalesced writes) ----------------
__global__ void k_sgather(const int* __restrict__ src, const int* __restrict__ dst,
                          const int* __restrict__ eidx,
                          int* __restrict__ srcs, int* __restrict__ dsts){
    int p = blockIdx.x * 256 + threadIdx.x;
    if (p >= NEDGES) return;
    int i = eidx[p];
    srcs[p] = src[i];
    dsts[p] = dst[i];
}

// ---------------- small GEMM: out_bf16[M,N] = Ab[M,K] @ Wt[N,K] ----------------
template<int K, int N>
__global__ __launch_bounds__(256) void k_gemm_b16(
    const unsigned short* __restrict__ Ab, const unsigned short* __restrict__ Wt,
    unsigned short* __restrict__ outb, int M)
{
    __shared__ unsigned short At[64][K + 8];
    const int t = threadIdx.x;
    const int r0 = blockIdx.x * 64;
    {
        const int r = t >> 2, q = t & 3;
        const int row = r0 + r;
        const bool valid = row < M;
        const unsigned short* a = Ab + (size_t)(valid ? row : 0) * K;
        for (int kk = q * (K / 4); kk < (q + 1) * (K / 4); kk += 8){
            ushort8 u;
            if (valid) u = *(const ushort8*)(a + kk);
            else       u = (ushort8){0,0,0,0,0,0,0,0};
            *(ushort8*)&At[r][kk] = u;
        }
    }
    __syncthreads();
    const int lane = t & 63, w = t >> 6;
    const int fr = lane & 15, fq = lane >> 4;
    constexpr int NF = N / 16;
    floatx4 acc[NF] = {};
    #pragma unroll
    for (int ks = 0; ks < K / 32; ks++){
        const int k = ks * 32 + fq * 8;
        bhalf8 a = *(bhalf8*)&At[w * 16 + fr][k];
        #pragma unroll
        for (int n = 0; n < NF; n++){
            bhalf8 b = *(const bhalf8*)(Wt + (size_t)(n * 16 + fr) * K + k);
            acc[n] = __builtin_amdgcn_mfma_f32_16x16x32_bf16(a, b, acc[n], 0, 0, 0);
        }
    }
    #pragma unroll
    for (int n = 0; n < NF; n++){
        const int col = n * 16 + fr;
        #pragma unroll
        for (int rr = 0; rr < 4; rr++){
            const int row = r0 + w * 16 + fq * 4 + rr;
            if (row < M) outb[(size_t)row * N + col] = f2b(acc[n][rr]);
        }
    }
}

// ---------------- fused edge layer 1 (LDS-staged P1 + LDS-staged Q store) ----------------
// phase A: stage e (f32->bf16) into Cb cols [0,64) + stage P1[src] tile into P1s (vectorized L2)
// phase B: acc1 = e_tile @ W1bT
// phase C: e1 = leaky(acc1 + P1s + b1e) -> Cb bf16 (full 128 cols)
// phase D: Q = e1 @ W2bT -> stage into P1s (dead) -> coalesced nt ushort8 stores
// phase E: run-reduced scatter-add of e1 cols to h1sum
__global__ __launch_bounds__(256) void k_edge1_fused(
    const float* __restrict__ e,
    const int* __restrict__ srcs, const int* __restrict__ dsts, const int* __restrict__ eidx,
    const unsigned short* __restrict__ W1bT, const float* __restrict__ b1e,
    const unsigned short* __restrict__ P1b, const unsigned short* __restrict__ W2bT,
    unsigned short* __restrict__ Qb, float* __restrict__ hsum)
{
    __shared__ unsigned short Cb[64][136];    // 17.4 KB
    __shared__ unsigned short P1s[64][136];   // 17.4 KB (P1 tile; reused as Q staging)
    __shared__ int dstS[64];
    const int t = threadIdx.x;
    const int p0 = blockIdx.x * 64;
    const int r = t >> 2, q = t & 3;
    // phase A
    {
        const int p = p0 + r;
        if (q == 0) dstS[r] = dsts[p];
        const int srow = srcs[p];
        const unsigned short* pp = P1b + (size_t)srow * 128 + q * 32;
        *(ushort8*)&P1s[r][q * 32]      = *(const ushort8*)pp;
        *(ushort8*)&P1s[r][q * 32 + 8]  = *(const ushort8*)(pp + 8);
        *(ushort8*)&P1s[r][q * 32 + 16] = *(const ushort8*)(pp + 16);
        *(ushort8*)&P1s[r][q * 32 + 24] = *(const ushort8*)(pp + 24);
        const int ei = eidx[p];
        const float* ep = e + (size_t)ei * 64 + q * 16;
        float4 f0 = ntld4(ep), f1 = ntld4(ep + 4), f2 = ntld4(ep + 8), f3 = ntld4(ep + 12);
        ushort8 u0 = {f2b(f0.x), f2b(f0.y), f2b(f0.z), f2b(f0.w), f2b(f1.x), f2b(f1.y), f2b(f1.z), f2b(f1.w)};
        ushort8 u1 = {f2b(f2.x), f2b(f2.y), f2b(f2.z), f2b(f2.w), f2b(f3.x), f2b(f3.y), f2b(f3.z), f2b(f3.w)};
        *(ushort8*)&Cb[r][q * 16]     = u0;
        *(ushort8*)&Cb[r][q * 16 + 8] = u1;
    }
    __syncthreads();
    const int lane = t & 63, w = t >> 6;
    const int wm = w >> 1, wn = w & 1;
    const int fr = lane & 15, fq = lane >> 4;
    // phase B
    floatx4 acc1[2][4] = {};
    #pragma unroll
    for (int ks = 0; ks < 2; ks++){
        const int k = ks * 32 + fq * 8;
        bhalf8 a0 = *(bhalf8*)&Cb[wm * 32 + fr][k];
        bhalf8 a1 = *(bhalf8*)&Cb[wm * 32 + 16 + fr][k];
        #pragma unroll
        for (int n = 0; n < 4; n++){
            const int col = wn * 64 + n * 16 + fr;
            bhalf8 b = *(const bhalf8*)(W1bT + (size_t)col * 64 + k);
            acc1[0][n] = __builtin_amdgcn_mfma_f32_16x16x32_bf16(a0, b, acc1[0][n], 0, 0, 0);
            acc1[1][n] = __builtin_amdgcn_mfma_f32_16x16x32_bf16(a1, b, acc1[1][n], 0, 0, 0);
        }
    }
    __syncthreads();   // e-stage reads done; overwrite Cb with e1
    // phase C
    #pragma unroll
    for (int m = 0; m < 2; m++){
        #pragma unroll
        for (int n = 0; n < 4; n++){
            const int col = wn * 64 + n * 16 + fr;
            const float bv = b1e[col];
            #pragma unroll
            for (int rr = 0; rr < 4; rr++){
                const int row = wm * 32 + m * 16 + fq * 4 + rr;
                const float pv = b2f(P1s[row][col]);
                Cb[row][col] = f2b(lrelu(acc1[m][n][rr] + pv + bv));
            }
        }
    }
    __syncthreads();   // e1 complete; P1s reads done
    // phase D: Q = e1 @ W2bT, stage into P1s
    {
        floatx4 acc2[4] = {};
        #pragma unroll
        for (int ks = 0; ks < 4; ks++){
            const int k = ks * 32 + fq * 8;
            bhalf8 a = *(bhalf8*)&Cb[w * 16 + fr][k];
            #pragma unroll
            for (int n = 0; n < 4; n++){
                bhalf8 b = *(const bhalf8*)(W2bT + (size_t)(n * 16 + fr) * 128 + k);
                acc2[n] = __builtin_amdgcn_mfma_f32_16x16x32_bf16(a, b, acc2[n], 0, 0, 0);
            }
        }
        #pragma unroll
        for (int n = 0; n < 4; n++){
            const int col = n * 16 + fr;
            #pragma unroll
            for (int rr = 0; rr < 4; rr++){
                const int row = w * 16 + fq * 4 + rr;
                P1s[row][col] = f2b(acc2[n][rr]);
            }
        }
    }
    __syncthreads();
    // coalesced Q store: 32B per thread, full 128B lines per 4 threads
    {
        unsigned short* op = Qb + (size_t)(p0 + r) * 64 + q * 16;
        ntst8u(op,     *(ushort8*)&P1s[r][q * 16]);
        ntst8u(op + 8, *(ushort8*)&P1s[r][q * 16 + 8]);
    }
    // phase E: run-reduced scatter-add of e1 to h1sum
    {
        const int col = t & 127, half = t >> 7;
        const int rbase = half * 32;
        float s = 0.f;
        int prev = dstS[rbase];
        #pragma unroll 4
        for (int rr = 0; rr < 32; rr++){
            const int rw2 = rbase + rr;
            const int d = dstS[rw2];
            if (d != prev){
                atomicAdd(&hsum[(size_t)prev * EHID + col], s);
                s = 0.f; prev = d;
            }
            s += b2f(Cb[rw2][col]);
        }
        atomicAdd(&hsum[(size_t)prev * EHID + col], s);
    }
}

// ---------------- edge layer 2 (lite): e2 = leaky(P2[src] + Q + b2e), run-reduced scatter ----------------
__global__ __launch_bounds__(256) void k_edge2_lite(
    const unsigned short* __restrict__ P2b, const unsigned short* __restrict__ Qb,
    const int* __restrict__ srcs, const int* __restrict__ dsts,
    const float* __restrict__ b2e, float* __restrict__ hsum)
{
    const int t = threadIdx.x;
    const int lane = t & 63, w = t >> 6;
    const int p0 = blockIdx.x * 256 + w * 64;
    const float bias = b2e[lane];
    float s = 0.f;
    int prev = dsts[p0];
    #pragma unroll 4
    for (int i = 0; i < 64; i++){
        const int p = p0 + i;
        const int d = dsts[p];
        if (d != prev){
            atomicAdd(&hsum[(size_t)prev * EOUTD + lane], s);
            s = 0.f; prev = d;
        }
        const float q  = b2f(__builtin_nontemporal_load(&Qb[(size_t)p * 64 + lane]));
        const float pv = b2f(P2b[(size_t)srcs[p] * 64 + lane]);
        s += lrelu(pv + q + bias);
    }
    atomicAdd(&hsum[(size_t)prev * EOUTD + lane], s);
}

// ---------------- node update (MFMA, 32-row tiles): out = leaky([A1, hsum/cnt] @ W + b) ----------------
template<int K1, int K2, bool WRITE_BF16>
__global__ __launch_bounds__(256) void k_node_mfma(
    const unsigned short* __restrict__ A1b, const float* __restrict__ hsum,
    const float* __restrict__ cntf,
    const unsigned short* __restrict__ Wt, const float* __restrict__ bias,
    float* __restrict__ outf, unsigned short* __restrict__ outb, int M)
{
    constexpr int K = K1 + K2;
    __shared__ unsigned short At[32][K + 8];
    const int t = threadIdx.x;
    const int r0 = blockIdx.x * 32;
    {
        const int r = t >> 3, q = t & 7;
        const int row = r0 + r;
        const bool valid = row < M;
        float rinv = 0.f;
        const unsigned short* a1 = A1b;
        const float* a2 = hsum;
        if (valid){
            rinv = 1.f / fmaxf(cntf[row], 1.f);
            a1 = A1b  + (size_t)row * K1;
            a2 = hsum + (size_t)row * K2;
        }
        for (int kk = q * (K / 8); kk < (q + 1) * (K / 8); kk += 8){
            ushort8 u;
            if (!valid){
                u = (ushort8){0,0,0,0,0,0,0,0};
            } else if (kk < K1){
                u = *(const ushort8*)(a1 + kk);
            } else {
                float4 f0 = ld4(a2 + (kk - K1)), f1 = ld4(a2 + (kk - K1) + 4);
                u = (ushort8){f2b(f0.x*rinv), f2b(f0.y*rinv), f2b(f0.z*rinv), f2b(f0.w*rinv),
                              f2b(f1.x*rinv), f2b(f1.y*rinv), f2b(f1.z*rinv), f2b(f1.w*rinv)};
            }
            *(ushort8*)&At[r][kk] = u;
        }
    }
    __syncthreads();
    const int lane = t & 63, w = t >> 6;
    const int wm = w >> 1, wn = w & 1;
    const int fr = lane & 15, fq = lane >> 4;
    floatx4 acc[8] = {};
    #pragma unroll
    for (int ks = 0; ks < K / 32; ks++){
        const int k = ks * 32 + fq * 8;
        bhalf8 a = *(bhalf8*)&At[wm * 16 + fr][k];
        #pragma unroll
        for (int n = 0; n < 8; n++){
            const int col = wn * 128 + n * 16 + fr;
            bhalf8 b = *(const bhalf8*)(Wt + (size_t)col * K + k);
            acc[n] = __builtin_amdgcn_mfma_f32_16x16x32_bf16(a, b, acc[n], 0, 0, 0);
        }
    }
    #pragma unroll
    for (int n = 0; n < 8; n++){
        const int col = wn * 128 + n * 16 + fr;
        const float bv = bias[col];
        #pragma unroll
        for (int rr = 0; rr < 4; rr++){
            const int row = r0 + wm * 16 + fq * 4 + rr;
            if (row < M){
                float o = lrelu(acc[n][rr] + bv);
                outf[(size_t)row * 256 + col] = o;
                if (WRITE_BF16) outb[(size_t)row * 256 + col] = f2b(o);
            }
        }
    }
}

// ---------------- attention: q,k,v ----------------
__global__ __launch_bounds__(256) void k_attn_qkv(
    const float* __restrict__ x1, const int* __restrict__ col_idx,
    const float* __restrict__ pe,
    const float* __restrict__ Wq, const float* __restrict__ Wk, const float* __restrict__ Wv,
    float* __restrict__ qo, float* __restrict__ ko, float* __restrict__ vo)
{
    __shared__ float c[256];
    const int i = blockIdx.x, t = threadIdx.x;
    const int col = col_idx[i];
    c[t] = x1[(size_t)col * 256 + t] + pe[i * 256 + t];
    __syncthreads();
    float aq = 0.f, ak = 0.f, av = 0.f;
    #pragma unroll 4
    for (int kk = 0; kk < 256; kk++){
        float cv = c[kk];
        aq += cv * Wq[kk * 256 + t];
        ak += cv * Wk[kk * 256 + t];
        av += cv * Wv[kk * 256 + t];
    }
    qo[i * 256 + t] = aq; ko[i * 256 + t] = ak; vo[i * 256 + t] = av;
}

// ---------------- attention: dist = softmax(q @ k^T / 16) ----------------
__global__ __launch_bounds__(128) void k_attn_dist(
    const float* __restrict__ q, const float* __restrict__ k, float* __restrict__ dist)
{
    __shared__ float qr[256];
    __shared__ float red[128];
    const int i = blockIdx.x, t = threadIdx.x;
    qr[t] = q[i * 256 + t]; qr[t + 128] = q[i * 256 + t + 128];
    __syncthreads();
    float s = 0.f;
    #pragma unroll 4
    for (int kk = 0; kk < 256; kk++) s += qr[kk] * k[t * 256 + kk];
    s *= 0.0625f;
    red[t] = s; __syncthreads();
    for (int off = 64; off; off >>= 1){ if (t < off) red[t] = fmaxf(red[t], red[t + off]); __syncthreads(); }
    float m = red[0]; __syncthreads();
    float ex = expf(s - m);
    red[t] = ex; __syncthreads();
    for (int off = 64; off; off >>= 1){ if (t < off) red[t] += red[t + off]; __syncthreads(); }
    dist[i * 128 + t] = ex / red[0];
}

// ---------------- attention tail ----------------
__global__ __launch_bounds__(256) void k_attn_out(
    const float* __restrict__ dist, const float* __restrict__ v,
    const float* __restrict__ Wref, const float* __restrict__ bref,
    const float* __restrict__ Wc, const float* __restrict__ bep,
    float* __restrict__ colWc)
{
    __shared__ float dr[128];
    __shared__ float c2[256];
    __shared__ float nc[256];
    const int i = blockIdx.x, t = threadIdx.x;
    if (t < 128) dr[t] = dist[i * 128 + t];
    __syncthreads();
    float s = 0.f;
    #pragma unroll 4
    for (int j = 0; j < 128; j++) s += dr[j] * v[j * 256 + t];
    c2[t] = 2.f * s;
    __syncthreads();
    float a = 0.f;
    #pragma unroll 4
    for (int kk = 0; kk < 256; kk++) a += c2[kk] * Wref[kk * 256 + t];
    a += bref[t];
    nc[t] = 1.f / (1.f + expf(-a));
    __syncthreads();
    if (t < 64){
        float o = 0.f;
        #pragma unroll 4
        for (int kk = 0; kk < 256; kk++) o += nc[kk] * Wc[kk * 64 + t];
        colWc[i * 64 + t] = o + bep[t];
    }
}

// ---------------- rowWr = x2[row_idx] @ Wr ----------------
__global__ __launch_bounds__(256) void k_rowwr(
    const float* __restrict__ x2, const int* __restrict__ row_idx,
    const float* __restrict__ Wr, float* __restrict__ rw)
{
    __shared__ float A[16][260];
    const int t = threadIdx.x;
    const int r0 = blockIdx.x * 16;
    const int rl = t >> 4, cg = t & 15;
    const int ridx = row_idx[r0 + rl];
    const float* ar = x2 + (size_t)ridx * 256;
    for (int i = cg; i < 64; i += 16) *(float4*)(&A[rl][i * 4]) = ld4(ar + i * 4);
    __syncthreads();
    float acc[4] = {0.f, 0.f, 0.f, 0.f};
    #pragma unroll 4
    for (int kk = 0; kk < 256; kk++){
        float4 w = ld4(Wr + (size_t)kk * 64 + cg * 4);
        float a = A[rl][kk];
        acc[0] += a * w.x; acc[1] += a * w.y; acc[2] += a * w.z; acc[3] += a * w.w;
    }
    *(float4*)(rw + (size_t)(r0 + rl) * 64 + cg * 4) = make_float4(acc[0], acc[1], acc[2], acc[3]);
}

// ---------------- fused: pred -> d_out (nt), imputation, classifier, log_softmax ----------------
__global__ __launch_bounds__(256) void k_pred8(
    const float* __restrict__ rowWr, const float* __restrict__ colWc,
    const void* __restrict__ maskp, const int* __restrict__ modep,
    const float* __restrict__ real, const float* __restrict__ Wcls, const float* __restrict__ bcls,
    float* __restrict__ out)
{
    __shared__ float colWc_s[8192];
    __shared__ float rowWr_s[8 * 64];
    __shared__ unsigned char mask_s[8 * 128];
    __shared__ float part[4][80];
    __shared__ float logits_s[80];
    const int t  = threadIdx.x;
    const int r0 = blockIdx.x * 8;
    const int mode = *modep;
    for (int idx = t; idx < 2048; idx += 256)
        *(float4*)&colWc_s[idx * 4] = ld4(colWc + idx * 4);
    for (int idx = t; idx < 128; idx += 256)
        *(float4*)&rowWr_s[idx * 4] = ld4(rowWr + (size_t)r0 * 64 + idx * 4);
    for (int idx = t; idx < 1024; idx += 256){
        const int g = idx >> 7, c = idx & 127;
        const int gi = (r0 + g) * 128 + c;
        bool m;
        if (mode == 2)      m = ((const unsigned char*)maskp)[gi] != 0;
        else if (mode == 0) m = ((const int*)maskp)[gi] != 0;
        else                m = ((const float*)maskp)[gi] != 0.f;
        mask_s[idx] = m ? 1 : 0;
    }
    __syncthreads();

    float acc[8][10];
    #pragma unroll
    for (int g = 0; g < 8; g++)
        #pragma unroll
        for (int c = 0; c < 10; c++) acc[g][c] = 0.f;
    float* pred = out + RROWS * NCLS;

    #pragma unroll 1
    for (int i = 0; i < 8; i++){
        const int e4   = i * 256 + t;
        const int base = e4 * 4;
        const int c = base >> 6;
        const int j = base & 63;
        float4 cw = ld4(&colWc_s[c * 64 + j]);
        float w40[40];
        #pragma unroll
        for (int u = 0; u < 10; u++){
            float4 wv = ld4(Wcls + (size_t)base * 10 + u * 4);
            w40[u*4+0] = wv.x; w40[u*4+1] = wv.y; w40[u*4+2] = wv.z; w40[u*4+3] = wv.w;
        }
        #pragma unroll
        for (int g = 0; g < 8; g++){
            const int rr = r0 + g;
            float4 rwv = ld4(&rowWr_s[g * 64 + j]);
            float4 p;
            p.x = lrelu(rwv.x + cw.x); p.y = lrelu(rwv.y + cw.y);
            p.z = lrelu(rwv.z + cw.z); p.w = lrelu(rwv.w + cw.w);
            ntst4(pred + (size_t)rr * 8192 + base, p);
            float4 im = p;
            if (mask_s[g * 128 + c]) im = ntld4(real + (size_t)rr * 8192 + base);
            #pragma unroll
            for (int cls = 0; cls < 10; cls++){
                acc[g][cls] += im.x * w40[cls]      + im.y * w40[10 + cls]
                             + im.z * w40[20 + cls] + im.w * w40[30 + cls];
            }
        }
    }
    #pragma unroll
    for (int g = 0; g < 8; g++)
        #pragma unroll
        for (int cls = 0; cls < 10; cls++){
            float v = acc[g][cls];
            for (int off = 32; off; off >>= 1) v += __shfl_down(v, off, 64);
            acc[g][cls] = v;
        }
    const int wid = t >> 6, lane = t & 63;
    if (lane == 0){
        #pragma unroll
        for (int g = 0; g < 8; g++)
            #pragma unroll
            for (int cls = 0; cls < 10; cls++) part[wid][g * 10 + cls] = acc[g][cls];
    }
    __syncthreads();
    if (t < 80) logits_s[t] = part[0][t] + part[1][t] + part[2][t] + part[3][t] + bcls[t % 10];
    __syncthreads();
    if (t < 8){
        float m = -1e30f;
        #pragma unroll
        for (int cls = 0; cls < 10; cls++) m = fmaxf(m, logits_s[t * 10 + cls]);
        float se = 0.f;
        #pragma unroll
        for (int cls = 0; cls < 10; cls++) se += expf(logits_s[t * 10 + cls] - m);
        float ls = logf(se) + m;
        #pragma unroll
        for (int cls = 0; cls < 10; cls++) out[(r0 + t) * 10 + cls] = logits_s[t * 10 + cls] - ls;
    }
}

extern "C" void kernel_launch(void* const* d_in, const int* in_sizes, int n_in,
                              void* d_out, int out_size, void* d_ws, size_t ws_size,
                              hipStream_t stream)
{
    const float* x      = (const float*)d_in[0];
    const float* e      = (const float*)d_in[1];
    const int*   src    = (const int*)d_in[2];
    const int*   dst    = (const int*)d_in[3];
    const int*   row_idx= (const int*)d_in[4];
    const int*   col_idx= (const int*)d_in[5];
    const float* real   = (const float*)d_in[6];
    const void*  mask   = d_in[7];
    const float* W1e    = (const float*)d_in[8];
    const float* b1e    = (const float*)d_in[9];
    const float* W1n    = (const float*)d_in[10];
    const float* b1n    = (const float*)d_in[11];
    const float* W2e    = (const float*)d_in[12];
    const float* b2e    = (const float*)d_in[13];
    const float* W2n    = (const float*)d_in[14];
    const float* b2n    = (const float*)d_in[15];
    const float* pe     = (const float*)d_in[16];
    const float* Wq     = (const float*)d_in[17];
    const float* Wk     = (const float*)d_in[18];
    const float* Wv     = (const float*)d_in[19];
    const float* Wref   = (const float*)d_in[20];
    const float* bref   = (const float*)d_in[21];
    const float* Wr     = (const float*)d_in[22];
    const float* Wc     = (const float*)d_in[23];
    const float* bep    = (const float*)d_in[24];
    const float* Wcls   = (const float*)d_in[25];
    const float* bcls   = (const float*)d_in[26];

    float* ws = (float*)d_ws;
    size_t off = 0;
    float* h1sum = ws + off; off += (size_t)NNODES * EHID;
    float* h2sum = ws + off; off += (size_t)NNODES * EOUTD;
    int*   cnt_i = (int*)(ws + off); off += NNODES;
    const size_t zero_floats = off;
    float* cntf  = ws + off; off += NNODES;
    int*   cursor= (int*)(ws + off); off += NNODES;
    int*   srcs  = (int*)(ws + off); off += NEDGES;
    int*   dsts  = (int*)(ws + off); off += NEDGES;
    int*   eidx  = (int*)(ws + off); off += NEDGES;
    float* x1    = ws + off; off += (size_t)NNODES * NHID;
    float* x2    = ws + off; off += (size_t)NNODES * NOUTD;
    unsigned short* xb    = (unsigned short*)(ws + off); off += (size_t)NNODES * NIN  / 2;
    unsigned short* x1b   = (unsigned short*)(ws + off); off += (size_t)NNODES * NHID / 2;
    unsigned short* W1tT  = (unsigned short*)(ws + off); off += 128 * 128 / 2;
    unsigned short* W1bT  = (unsigned short*)(ws + off); off += 128 * 64 / 2;
    unsigned short* W2tT  = (unsigned short*)(ws + off); off += 64 * 256 / 2;
    unsigned short* W2bT  = (unsigned short*)(ws + off); off += 64 * 128 / 2;
    unsigned short* W1nTb = (unsigned short*)(ws + off); off += 256 * 256 / 2;
    unsigned short* W2nTb = (unsigned short*)(ws + off); off += 256 * 320 / 2;
    unsigned short* P1b   = (unsigned short*)(ws + off); off += (size_t)NNODES * 128 / 2;
    unsigned short* P2b   = (unsigned short*)(ws + off); off += (size_t)NNODES * 64 / 2;
    float* qb    = ws + off; off += 128 * 256;
    float* kb    = ws + off; off += 128 * 256;
    float* vb    = ws + off; off += 128 * 256;
    float* distb = ws + off; off += 128 * 128;
    float* colWc = ws + off; off += 128 * 64;
    float* rowWrb= ws + off; off += (size_t)RROWS * EOUTD;
    int*   modep = (int*)(ws + off); off += 4;
    int*   blocksum = (int*)(ws + off); off += 128;
    int*   blockoff = (int*)(ws + off); off += 128;
    // Q bf16 (sorted, 480000x64x2B = 61MB). ws if it fits, else borrow pred
    // region of d_out (Q fully consumed by k_edge2_lite before k_pred8 writes).
    unsigned short* Qb;
    size_t need = (off + (size_t)NEDGES * 32) * sizeof(float);
    if (ws_size >= need) Qb = (unsigned short*)(ws + off);
    else                 Qb = (unsigned short*)((float*)d_out + (size_t)RROWS * NCLS);

    (void)hipMemsetAsync(d_ws, 0, zero_floats * sizeof(float), stream);
    k_prep<<<PREP_TOTAL, 256, 0, stream>>>(x, xb, W1e, W1tT, W1bT, W2e, W2tT, W2bT,
                                           W1n, W1nTb, W2n, W2nTb, dst, cnt_i,
                                           (const unsigned int*)mask, modep);
    k_pfx1<<<NB_PFX, 256, 0, stream>>>(cnt_i, blocksum);
    k_pfx2<<<1, 128, 0, stream>>>(blocksum, blockoff);
    k_pfx3<<<NB_PFX, 256, 0, stream>>>(cnt_i, blockoff, cursor, cntf);
    k_scatter<<<(NEDGES + 255) / 256, 256, 0, stream>>>(dst, cursor, eidx);
    k_sgather<<<(NEDGES + 255) / 256, 256, 0, stream>>>(src, dst, eidx, srcs, dsts);
    k_gemm_b16<128, 128><<<(NNODES + 63) / 64, 256, 0, stream>>>(xb, W1tT, P1b, NNODES);
    k_edge1_fused<<<NEDGES / 64, 256, 0, stream>>>(e, srcs, dsts, eidx, W1bT, b1e, P1b, W2bT, Qb, h1sum);
    k_node_mfma<NIN, EHID, true><<<(NNODES + 31) / 32, 256, 0, stream>>>(xb, h1sum, cntf, W1nTb, b1n, x1, x1b, NNODES);
    k_gemm_b16<256, 64><<<(NNODES + 63) / 64, 256, 0, stream>>>(x1b, W2tT, P2b, NNODES);
    k_edge2_lite<<<NEDGES / 256, 256, 0, stream>>>(P2b, Qb, srcs, dsts, b2e, h2sum);
    k_node_mfma<NHID, EOUTD, false><<<(NNODES + 31) / 32, 256, 0, stream>>>(x1b, h2sum, cntf, W2nTb, b2n, x2, (unsigned short*)nullptr, NNODES);
    k_attn_qkv<<<128, 256, 0, stream>>>(x1, col_idx, pe, Wq, Wk, Wv, qb, kb, vb);
    k_attn_dist<<<128, 128, 0, stream>>>(qb, kb, distb);
    k_attn_out<<<128, 256, 0, stream>>>(distb, vb, Wref, bref, Wc, bep, colWc);
    k_rowwr<<<RROWS / 16, 256, 0, stream>>>(x2, row_idx, Wr, rowWrb);
    k_pred8<<<RROWS / 8, 256, 0, stream>>>(rowWrb, colWc, mask, modep, real, Wcls, bcls, (float*)d_out);
}